// Round 11
// baseline (1998.550 us; speedup 1.0000x reference)
//
#include <hip/hip_runtime.h>
#include <cmath>
#include <cstring>
#include <cstdint>
#include <vector>

#define TPB 256
static constexpr int kLMAX = 32;
static constexpr int kNMN  = 43680;   // sum_{l<32} (2l+1)^2
static constexpr int kNMN2 = 22352;   // sum_{l<32} (l+1)(2l+1)  (m>=0 rows only)
static constexpr int kNM   = 1024;    // sum_{l<32} (2l+1)
static constexpr int kNQ2  = 5848;    // sum_{l<32} (l+1)*ceil((2l+1)/4)
static constexpr int kB    = 2;
static constexpr int kF0   = 3, kF1 = 60, kF2 = 36;
static constexpr int kCube = 262144;  // 64^3
static constexpr int kFCH  = 24;      // plane chunk (divides 120 and 72)
static constexpr int kCH2  = (kNMN2 + 255) / 256;   // 88 lmn2-chunks of 256

__host__ __device__ inline int off3i(int l) { return l * (4 * l * l - 1) / 3; }

// ---------------------------------------------------------------------------
// Host-side constant tables (~3.0 MB seeds; d_b = F_{b&7} * G_{b>>3}).
// Hermitian dead-code note: synA (mu<=32) only reads zs rows with m>=0, so
// the zs/G/fh chain is computed ONLY for mi>=l (lmn2/lmq tables below), and
// fh3/fft2 only produce the mu in [0,31] half of the spectrum.
// ---------------------------------------------------------------------------
static void h_matmul(const std::vector<double>& A, const std::vector<double>& B,
                     std::vector<double>& C, int n) {
    C.assign((size_t)n * n, 0.0);
    for (int i = 0; i < n; i++)
        for (int k = 0; k < n; k++) {
            double a = A[(size_t)i * n + k];
            if (a == 0.0) continue;
            const double* bp = &B[(size_t)k * n];
            double* cp = &C[(size_t)i * n];
            for (int j = 0; j < n; j++) cp[j] += a * bp[j];
        }
}

struct HostTables {
    std::vector<float> blob;
    size_t o_twf, o_twi, o_w, o_lmnl, o_lml, o_lmn2, o_lmq, o_off4, o_etab;
    size_t bytes;
    HostTables() {
        size_t n = 0;
        o_twf = n;  n += 128;
        o_twi = n;  n += 128;
        o_w = n;    n += 64;
        o_lmnl = n; n += kNMN;
        o_lml = n;  n += kNM;
        o_lmn2 = n; n += kNMN2;
        o_lmq = n;  n += kNQ2;
        o_off4 = n; n += 32;
        o_etab = n; n += (size_t)16 * kNMN;    // [F_0..F_7, G_0..G_7] per l
        blob.assign(n, 0.0f);
        bytes = n * 4;

        for (int k = 0; k < 64; k++) {
            double th = -2.0 * M_PI * k / 64.0;
            blob[o_twf + 2 * k]     = (float)cos(th);
            blob[o_twf + 2 * k + 1] = (float)sin(th);
            blob[o_twi + 2 * k]     = (float)cos(th);
            blob[o_twi + 2 * k + 1] = (float)(-sin(th));
        }
        for (int j = 0; j < 64; j++) {
            double s = 0;
            for (int k = 0; k < 32; k++)
                s += sin((2.0 * j + 1) * (2.0 * k + 1) * M_PI / 128.0) / (2.0 * k + 1);
            blob[o_w + j] = (float)(2.0 / 32.0 * sin(M_PI * (2.0 * j + 1) / 128.0) * s);
        }
        // lmn2: compact index of (l, mi>=l, ni) -> original lmn offset.
        {
            int qi = 0;
            for (int l = 0; l < kLMAX; l++) {
                int R = 2 * l + 1, o3 = off3i(l);
                for (int mi = l; mi < R; mi++)
                    for (int ni = 0; ni < R; ni++) {
                        int32_t v = o3 + mi * R + ni;
                        memcpy(&blob[o_lmn2 + qi], &v, 4);
                        qi++;
                    }
            }
        }
        // q -> (l, mi>=l, n0) table for n4-blocked k_G4, and padded-deT offsets.
        {
            int qi = 0, acc4 = 0;
            for (int l = 0; l < kLMAX; l++) {
                int R = 2 * l + 1, Rp = (R + 3) & ~3, C = Rp >> 2;
                int32_t o4 = acc4;
                memcpy(&blob[o_off4 + l], &o4, 4);
                for (int m = l; m < R; m++)
                    for (int c = 0; c < C; c++) {
                        int32_t pk = l | (m << 5) | ((4 * c) << 11);
                        memcpy(&blob[o_lmq + qi], &pk, 4);
                        qi++;
                    }
                acc4 += R * Rp;
            }
        }
        std::vector<double> A, Eh, E0, E08, F, G, term, tmp;
        for (int l = 0; l < kLMAX; l++) {
            int R = 2 * l + 1, o3 = off3i(l);
            A.assign((size_t)R * R, 0.0);
            for (int i = 0; i + 1 < R; i++) {
                double m = (double)i - l;
                double c = sqrt((double)l * (l + 1) - m * (m + 1));
                A[(size_t)(i + 1) * R + i] = -(M_PI / 128.0) * c * 0.5;
                A[(size_t)i * R + (i + 1)] =  (M_PI / 128.0) * c * 0.5;
            }
            Eh.assign((size_t)R * R, 0.0);
            for (int i = 0; i < R; i++) Eh[(size_t)i * R + i] = 1.0;
            term = Eh;
            for (int k = 1; k <= 30; k++) {
                h_matmul(term, A, tmp, R);
                for (auto& v : tmp) v /= k;
                term = tmp;
                for (size_t i = 0; i < (size_t)R * R; i++) Eh[i] += term[i];
            }
            h_matmul(Eh, Eh, E0, R);
            h_matmul(E0, E0, tmp, R);
            h_matmul(tmp, tmp, E08, R);
            h_matmul(E08, E08, tmp, R); E08 = tmp;  // E0^8
            F = Eh;
            for (int lo = 0; lo < 8; lo++) {
                for (int r = 0; r < R * R; r++)
                    blob[o_etab + (size_t)lo * kNMN + o3 + r] = (float)F[r];
                if (lo < 7) { h_matmul(F, E0, tmp, R); F = tmp; }
            }
            G.assign((size_t)R * R, 0.0);
            for (int i = 0; i < R; i++) G[(size_t)i * R + i] = 1.0;
            for (int hi = 0; hi < 8; hi++) {
                for (int r = 0; r < R * R; r++)
                    blob[o_etab + (size_t)(8 + hi) * kNMN + o3 + r] = (float)G[r];
                if (hi < 7) { h_matmul(G, E08, tmp, R); G = tmp; }
            }
            int32_t li = l;
            for (int r = 0; r < R * R; r++) memcpy(&blob[o_lmnl + o3 + r], &li, 4);
            for (int m = 0; m < R; m++)    memcpy(&blob[o_lml + (size_t)l * l + m], &li, 4);
        }
    }
};
static HostTables g_tab;

// ---------------------------------------------------------------------------
__global__ __launch_bounds__(TPB) void k_gendqA(const float* __restrict__ etab,
                                                float* __restrict__ dtmp) {
    __shared__ float Fm[3969];
    __shared__ float Gm[63 * 64];
    int l = blockIdx.x >> 6, b = blockIdx.x & 63;
    int lo = b & 7, hi = b >> 3;
    int R = 2 * l + 1, RR = R * R, o3 = off3i(l);
    int tid = threadIdx.x;
    const float* Fsrc = etab + (size_t)lo * kNMN + o3;
    const float* Gsrc = etab + (size_t)(8 + hi) * kNMN + o3;
    for (int i = tid; i < RR; i += TPB) Fm[i] = Fsrc[i];
    for (int i = tid; i < R * 64; i += TPB) {
        int k = i >> 6, c = i & 63;
        Gm[i] = (c < R) ? Gsrc[k * R + c] : 0.f;
    }
    __syncthreads();
    int Gc = (R + 15) >> 4;
    if (tid < R * Gc) {
        int row = tid / Gc, g = tid - row * Gc;
        float4 A0 = make_float4(0,0,0,0), A1 = A0, A2 = A0, A3 = A0;
        const float* fr = Fm + row * R;
        for (int k = 0; k < R; k++) {
            float a = fr[k];
            const float4* gp = (const float4*)(Gm + (k << 6) + (g << 4));
            float4 q0 = gp[0], q1 = gp[1], q2 = gp[2], q3 = gp[3];
            A0.x += a * q0.x; A0.y += a * q0.y; A0.z += a * q0.z; A0.w += a * q0.w;
            A1.x += a * q1.x; A1.y += a * q1.y; A1.z += a * q1.z; A1.w += a * q1.w;
            A2.x += a * q2.x; A2.y += a * q2.y; A2.z += a * q2.z; A2.w += a * q2.w;
            A3.x += a * q3.x; A3.y += a * q3.y; A3.z += a * q3.z; A3.w += a * q3.w;
        }
        float v[16] = {A0.x,A0.y,A0.z,A0.w, A1.x,A1.y,A1.z,A1.w,
                       A2.x,A2.y,A2.z,A2.w, A3.x,A3.y,A3.z,A3.w};
        float* dst = dtmp + (size_t)o3 * 64 + (size_t)b * RR + row * R;
        int c0 = g << 4;
        #pragma unroll
        for (int e = 0; e < 16; e++)
            if (c0 + e < R) dst[c0 + e] = v[e];
    }
}

__global__ __launch_bounds__(TPB) void k_scat(const float* __restrict__ dtmp,
                                              const float* __restrict__ w,
                                              float* __restrict__ dqz,
                                              float* __restrict__ dqtw) {
    __shared__ float S[64 * 65];
    int l = blockIdx.x / 63, tile = blockIdx.x % 63;
    int R = 2 * l + 1, RR = R * R, o3 = off3i(l);
    int i0 = tile * 64;
    if (i0 >= RR) return;
    int tid = threadIdx.x;
    const float* src = dtmp + (size_t)o3 * 64;
    #pragma unroll
    for (int s = 0; s < 16; s++) {
        int idx = tid + s * TPB;
        int b = idx >> 6, ii = idx & 63;
        int i = i0 + ii;
        S[ii * 65 + b] = (i < RR) ? src[(size_t)b * RR + i] : 0.f;
    }
    __syncthreads();
    float Rf = (float)R;
    #pragma unroll
    for (int s = 0; s < 16; s++) {
        int idx = tid + s * TPB;
        int ii = idx >> 6, b = idx & 63;
        int i = i0 + ii;
        if (i < RR) {
            float v = S[ii * 65 + b];
            dqtw[((size_t)o3 + i) * 64 + b] = w[b] * v;
            int mi = i / R, ni = i - mi * R;
            int nu = (ni - l) & 63;
            dqz[((size_t)(l * l + mi) * 64 + nu) * 64 + b] = Rf * v;
        }
    }
}

// Builds padded-row deTp: deTp[off4(l) + k*Rp + n] = dehalf[o3 + n*R + k],
// Rp = ceil(R/4)*4. Pad entries stay zero (memset upstream).
__global__ void k_transde_p(const float* __restrict__ dehalf, float* __restrict__ deTp,
                            const int* __restrict__ lmn_l, const int* __restrict__ off4) {
    int t = blockIdx.x * TPB + threadIdx.x;
    if (t >= kNMN) return;
    int l = lmn_l[t], o3 = off3i(l), r = t - o3, R = 2 * l + 1;
    int Rp = (R + 3) & ~3;
    int n = r / R, k = r - n * R;
    deTp[off4[l] + k * Rp + n] = dehalf[t];
}

__global__ void k_khat(const float* __restrict__ kern, float2* __restrict__ khat,
                       const float2* __restrict__ twf, int total, float scale) {
    int t = blockIdx.x * TPB + threadIdx.x;
    if (t >= total) return;
    int nu = t & 63, fo = t >> 6;
    const float* row = kern + (size_t)fo * 64;
    float re = 0, im = 0;
    for (int p = 0; p < 64; p++) {
        float2 w = twf[(p * nu) & 63];
        float v = row[p];
        re += v * w.x; im += v * w.y;
    }
    khat[t] = make_float2(re * scale, im * scale);
}

__global__ void k_fft1(const float* __restrict__ x, float2* __restrict__ xf1,
                       const float2* __restrict__ twf) {
    int t = blockIdx.x * TPB + threadIdx.x;
    if (t >= kB * kF0 * 64 * 64) return;
    int mu = t & 63, row = t >> 6;
    const float* p = x + (size_t)row * 64;
    float re = 0, im = 0;
    for (int a = 0; a < 64; a++) {
        float2 w = twf[(a * mu) & 63];
        float v = p[a];
        re += v * w.x; im += v * w.y;
    }
    xf1[t] = make_float2(re, im);
}

__global__ void k_fh1(const float2* __restrict__ xf1, const float* __restrict__ dqtw,
                      const int* __restrict__ lm_l, float2* __restrict__ fh1) {
    int t = blockIdx.x * TPB + threadIdx.x;
    if (t >= kNM * kB * kF0) return;
    int lm = t / 6, rem = t % 6, z = rem / 3, f = rem % 3;
    int l = lm_l[lm], m = lm - l * l, R = 2 * l + 1, o3 = off3i(l);
    int mu = (m - l) & 63;
    const float4* wq = (const float4*)(dqtw + (size_t)o3 * 64 + (size_t)(m * R + l) * 64);
    const float2* xr = xf1 + (size_t)((z * 3 + f) * 64) * 64 + mu;
    float re0 = 0, im0 = 0, re1 = 0, im1 = 0;
    #pragma unroll
    for (int b4 = 0; b4 < 16; b4++) {
        float4 w4 = wq[b4];
        float2 v0 = xr[(4 * b4 + 0) * 64];
        float2 v1 = xr[(4 * b4 + 1) * 64];
        float2 v2 = xr[(4 * b4 + 2) * 64];
        float2 v3 = xr[(4 * b4 + 3) * 64];
        re0 += w4.x * v0.x + w4.y * v1.x; im0 += w4.x * v0.y + w4.y * v1.y;
        re1 += w4.z * v2.x + w4.w * v3.x; im1 += w4.z * v2.y + w4.w * v3.y;
    }
    const float C2 = 1.0f / 128.0f;
    fh1[t] = make_float2((re0 + re1) * C2, (im0 + im1) * C2);
}

// Layer-1 zs restricted to lmn2 (mi>=l): synA never reads m<0 rows.
__global__ void k_zs1(const float2* __restrict__ fh1, const float2* __restrict__ khat,
                      const float* __restrict__ dehalf, const int* __restrict__ lmn_l,
                      const int* __restrict__ lmn2, float2* __restrict__ zs) {
    int nOg = kF1 / 6;                       // 10
    int t = blockIdx.x * TPB + threadIdx.x;  // og*NMN2 + i2
    if (t >= nOg * kNMN2) return;
    int i2 = t % kNMN2, og = t / kNMN2;
    int lmn = lmn2[i2];
    int l = lmn_l[lmn], o3 = off3i(l), r = lmn - o3, R = 2 * l + 1;
    int m = r / R, n = r - m * R;
    int nu = (n - l) & 63;
    float de1 = dehalf[o3 + n * R + l];
    int o0 = og * 6;
    const float2* fp = fh1 + (size_t)(l * l + m) * 6;
    const float2* kp = khat + (size_t)o0 * 64 + nu;
    float2 c0[6], c1[6];
    #pragma unroll
    for (int i = 0; i < 6; i++) {
        c0[i] = make_float2(0.f, 0.f);
        c1[i] = make_float2(0.f, 0.f);
    }
    #pragma unroll
    for (int f = 0; f < kF0; f++) {
        float2 a0 = fp[f];       // z = 0
        float2 a1 = fp[3 + f];   // z = 1
        const float2* kf = kp + (size_t)f * kF1 * 64;
        #pragma unroll
        for (int i = 0; i < 6; i++) {
            float2 b = kf[(size_t)i * 64];   // conj applied below
            c0[i].x += a0.x * b.x + a0.y * b.y;
            c0[i].y += a0.y * b.x - a0.x * b.y;
            c1[i].x += a1.x * b.x + a1.y * b.y;
            c1[i].y += a1.y * b.x - a1.x * b.y;
        }
    }
    float2* zp0 = zs + (size_t)o0 * kNMN + lmn;
    float2* zp1 = zs + ((size_t)kF1 + o0) * kNMN + lmn;
    #pragma unroll
    for (int i = 0; i < 6; i++) {
        zp0[(size_t)i * kNMN] = make_float2(c0[i].x * de1, c0[i].y * de1);
        zp1[(size_t)i * kNMN] = make_float2(c1[i].x * de1, c1[i].y * de1);
    }
}

// 2D forward DFT (radix-8 x2) with fused BN+ReLU; float4 staging.
// HERMITIAN DCE (output): k_fh3 reads only mu in [0,31] -> pass-2 computes
// only u<4. HERMITIAN (input): rows are REAL, so pass-1 output satisfies
// F[64-nu] = conj(F[nu]); pass-1 stage-2 computes nu<=32 and mirrors 33..63
// in LDS (intra-wave, same lockstep reliance as the existing cross-lane
// stage-1 -> stage-2 reads).
__global__ __launch_bounds__(TPB) void k_fft2(const float* __restrict__ y,
                                              float2* __restrict__ xf,
                                              const float2* __restrict__ twf_g,
                                              const float* __restrict__ stats,
                                              const float* __restrict__ gamma,
                                              const float* __restrict__ beta,
                                              int zf0) {
    __shared__ float sIn[64 * 65];
    __shared__ float2 sMid[64 * 66];
    __shared__ float2 tw[64];
    int blk = blockIdx.x, tid = threadIdx.x;
    if (tid < 64) tw[tid] = twf_g[tid];
    int o = (zf0 + (blk >> 6)) % kF1;
    const float inv = 1.0f / 524288.0f;
    float mean = stats[o * 2] * inv;
    float var = stats[o * 2 + 1] * inv - mean * mean;
    float rstd = rsqrtf(var + 1e-5f);
    float ga = gamma[o], be = beta[o];
    const float4* src4 = (const float4*)(y + (size_t)blk * 4096);
    for (int i = tid; i < 1024; i += TPB) {
        float4 v4 = src4[i];
        int row = i >> 4, col = (i & 15) << 2;
        float* d = sIn + row * 65 + col;
        float a0 = (v4.x - mean) * rstd * ga + be;
        float a1 = (v4.y - mean) * rstd * ga + be;
        float a2 = (v4.z - mean) * rstd * ga + be;
        float a3 = (v4.w - mean) * rstd * ga + be;
        d[0] = a0 > 0.f ? a0 : 0.f;
        d[1] = a1 > 0.f ? a1 : 0.f;
        d[2] = a2 > 0.f ? a2 : 0.f;
        d[3] = a3 > 0.f ? a3 : 0.f;
    }
    __syncthreads();
    float2 w8[8];
    #pragma unroll
    for (int k = 0; k < 8; k++) w8[k] = tw[k * 8];
    int r2 = tid >> 2, q = tid & 3;
    {   // dim-1: g -> nu, REAL input
        const float* rowp = sIn + r2 * 65;
        float2* mrow = sMid + r2 * 66;
        #pragma unroll
        for (int half = 0; half < 2; half++) {
            int s = q + 4 * half;
            float f[8];
            #pragma unroll
            for (int p = 0; p < 8; p++) f[p] = rowp[8 * p + s];
            float2 ws = tw[s];
            float2 t = make_float2(1.f, 0.f);
            #pragma unroll
            for (int v = 0; v < 8; v++) {
                float re = 0, im = 0;
                #pragma unroll
                for (int p = 0; p < 8; p++) {
                    float2 w = w8[(v * p) & 7];
                    re += f[p] * w.x; im += f[p] * w.y;
                }
                mrow[v * 8 + s] = make_float2(re * t.x - im * t.y, re * t.y + im * t.x);
                float tx = t.x * ws.x - t.y * ws.y;
                t.y = t.x * ws.y + t.y * ws.x; t.x = tx;
            }
        }
        float2 a[2][8];
        #pragma unroll
        for (int half = 0; half < 2; half++) {
            int v = q + 4 * half;
            #pragma unroll
            for (int s = 0; s < 8; s++) a[half][s] = mrow[v * 8 + s];
        }
        #pragma unroll
        for (int half = 0; half < 2; half++) {
            int v = q + 4 * half;
            #pragma unroll
            for (int u = 0; u < 4; u++) {   // nu = 8u+v in [0,31]
                float re = 0, im = 0;
                #pragma unroll
                for (int s = 0; s < 8; s++) {
                    float2 w = w8[(u * s) & 7];
                    re += a[half][s].x * w.x - a[half][s].y * w.y;
                    im += a[half][s].x * w.y + a[half][s].y * w.x;
                }
                mrow[8 * u + v] = make_float2(re, im);
            }
        }
        if (q == 0) {   // nu = 32 (u=4, v=0): only the half=0, v=0 slot
            float re = 0, im = 0;
            #pragma unroll
            for (int s = 0; s < 8; s++) {
                float2 w = w8[(4 * s) & 7];
                re += a[0][s].x * w.x - a[0][s].y * w.y;
                im += a[0][s].x * w.y + a[0][s].y * w.x;
            }
            mrow[32] = make_float2(re, im);
        }
        // mirror nu = 33..63: F[nu] = conj(F[64-nu]) (real input rows).
        // Reads lanes of the same wave (4 threads/row, lockstep).
        for (int nu = 33 + q; nu < 64; nu += 4) {
            float2 vv = mrow[64 - nu];
            mrow[nu] = make_float2(vv.x, -vv.y);
        }
    }
    __syncthreads();
    {   // dim-2: a -> mu per column c; only mu < 32 needed downstream
        int c = r2;
        float2* dst = xf + (size_t)blk * 4096;
        #pragma unroll
        for (int half = 0; half < 2; half++) {
            int s = q + 4 * half;
            float2 f[8];
            #pragma unroll
            for (int p = 0; p < 8; p++) f[p] = sMid[(8 * p + s) * 66 + c];
            float2 ws = tw[s];
            float2 t = make_float2(1.f, 0.f);
            #pragma unroll
            for (int v = 0; v < 8; v++) {
                float re = 0, im = 0;
                #pragma unroll
                for (int p = 0; p < 8; p++) {
                    float2 w = w8[(v * p) & 7];
                    re += f[p].x * w.x - f[p].y * w.y;
                    im += f[p].x * w.y + f[p].y * w.x;
                }
                sMid[(v * 8 + s) * 66 + c] = make_float2(re * t.x - im * t.y,
                                                         re * t.y + im * t.x);
                float tx = t.x * ws.x - t.y * ws.y;
                t.y = t.x * ws.y + t.y * ws.x; t.x = tx;
            }
        }
        float2 a[2][8];
        #pragma unroll
        for (int half = 0; half < 2; half++) {
            int v = q + 4 * half;
            #pragma unroll
            for (int s = 0; s < 8; s++) a[half][s] = sMid[(v * 8 + s) * 66 + c];
        }
        #pragma unroll
        for (int half = 0; half < 2; half++) {
            int v = q + 4 * half;
            #pragma unroll
            for (int u = 0; u < 4; u++) {   // mu = 8u+v in [0,31] only
                float re = 0, im = 0;
                #pragma unroll
                for (int s = 0; s < 8; s++) {
                    float2 w = w8[(u * s) & 7];
                    re += a[half][s].x * w.x - a[half][s].y * w.y;
                    im += a[half][s].x * w.y + a[half][s].y * w.x;
                }
                dst[(8 * u + v) * 64 + c] = make_float2(re, im);
            }
        }
    }
}

// fh3: one block per (mu,nu) column, mu in [0..31] ONLY (m>=0 rows; the m<0
// half of fh is dead code downstream). X and dqtw staged once in LDS.
// XCD swizzle in 256-block chunks: per-XCD xf slice = 4 mu rows ~ 3 MB < L2.
__global__ __launch_bounds__(TPB) void k_fh3(const float2* __restrict__ xf,
                                             const float* __restrict__ dqtw,
                                             float2* __restrict__ fh_out, int nzf) {
    __shared__ float2 sX[24 * 66];   // [zf][b], row stride 66 float2
    __shared__ float  sD[32 * 68];   // [li][b], row stride 68 floats
    int v = blockIdx.x;              // 2048 blocks
    int wg = (v & 7) * 256 + (v >> 3);
    int nu = wg & 63, mu = wg >> 6;  // mu in [0,31] -> mt = mu >= 0
    int mt = mu;
    int nt = (nu <= 31) ? nu : nu - 64;
    int am = mu, an = nt < 0 ? -nt : nt;
    int lmin = am > an ? am : an;
    if (lmin >= kLMAX) return;
    int nl = kLMAX - lmin;
    int tid = threadIdx.x;
    for (int i = tid; i < nzf * 64; i += TPB) {
        int zf = i >> 6, b = i & 63;
        sX[zf * 66 + b] = xf[(size_t)zf * kCube + (size_t)b * 4096 + mu * 64 + nu];
    }
    for (int i = tid; i < nl * 64; i += TPB) {
        int li = i >> 6, b = i & 63;
        int l = lmin + li, R = 2 * l + 1;
        int r = (mt + l) * R + (nt + l);
        sD[li * 68 + b] = dqtw[(size_t)(off3i(l) + r) * 64 + b];
    }
    __syncthreads();
    const float C3 = 1.0f / 8192.0f;
    int items = nzf * nl;
    for (int item = tid; item < items; item += TPB) {
        int zf = item / nl, li = item - zf * nl;
        const float4* D4 = (const float4*)(sD + li * 68);
        const float4* X4 = (const float4*)(sX + zf * 66);
        float re0 = 0, im0 = 0, re1 = 0, im1 = 0;
        #pragma unroll
        for (int b4 = 0; b4 < 16; b4++) {
            float4 d   = D4[b4];
            float4 x01 = X4[2 * b4];
            float4 x23 = X4[2 * b4 + 1];
            re0 += d.x * x01.x; im0 += d.x * x01.y;
            re0 += d.y * x01.z; im0 += d.y * x01.w;
            re1 += d.z * x23.x; im1 += d.z * x23.y;
            re1 += d.w * x23.z; im1 += d.w * x23.w;
        }
        int l = lmin + li, R = 2 * l + 1;
        int r = (mt + l) * R + (nt + l);
        fh_out[(size_t)zf * kNMN + off3i(l) + r] =
            make_float2((re0 + re1) * C3, (im0 + im1) * C3);
    }
}

// G (n4-blocked, mi>=l rows only): thread computes 4 consecutive n outputs.
// Per k: 1 float2 fh broadcast + 1 aligned float4 deTp row-load -> 16 lane-FMA.
__global__ void k_G4(const float2* __restrict__ fh, const float* __restrict__ deTp,
                     const int* __restrict__ lmq, const int* __restrict__ off4,
                     float2* __restrict__ G, int total) {
    int t = blockIdx.x * TPB + threadIdx.x;
    if (t >= total) return;
    int q = t % kNQ2, zf = t / kNQ2;
    int pk = lmq[q];
    int l = pk & 31, m = (pk >> 5) & 63, n0 = pk >> 11;
    int R = 2 * l + 1, o3 = off3i(l);
    int C4 = ((R + 3) & ~3) >> 2;            // Rp/4
    const float2* fr = fh + (size_t)zf * kNMN + o3 + m * R;
    const float4* dp = (const float4*)(deTp + off4[l] + n0);
    float4 re = make_float4(0.f, 0.f, 0.f, 0.f);
    float4 im = make_float4(0.f, 0.f, 0.f, 0.f);
    int k = 0;
    for (; k + 1 < R; k += 2) {
        float2 f0 = fr[k], f1 = fr[k + 1];
        float4 d0 = dp[(size_t)k * C4];
        float4 d1 = dp[(size_t)(k + 1) * C4];
        re.x += f0.x * d0.x + f1.x * d1.x; im.x += f0.y * d0.x + f1.y * d1.x;
        re.y += f0.x * d0.y + f1.x * d1.y; im.y += f0.y * d0.y + f1.y * d1.y;
        re.z += f0.x * d0.z + f1.x * d1.z; im.z += f0.y * d0.z + f1.y * d1.z;
        re.w += f0.x * d0.w + f1.x * d1.w; im.w += f0.y * d0.w + f1.y * d1.w;
    }
    {
        float2 f0 = fr[k];
        float4 d0 = dp[(size_t)k * C4];
        re.x += f0.x * d0.x; im.x += f0.y * d0.x;
        re.y += f0.x * d0.y; im.y += f0.y * d0.y;
        re.z += f0.x * d0.z; im.z += f0.y * d0.z;
        re.w += f0.x * d0.w; im.w += f0.y * d0.w;
    }
    float2* gp = G + (size_t)zf * kNMN + o3 + m * R + n0;
    int rem = R - n0;
    gp[0] = make_float2(re.x, im.x);
    if (rem > 1) gp[1] = make_float2(re.y, im.y);
    if (rem > 2) gp[2] = make_float2(re.z, im.z);
    if (rem > 3) gp[3] = make_float2(re.w, im.w);
}

// zs v4: og-tile 3; barrier-free body + og-fastest XCD-grouped decode +
// compile-time FIN/FO + unroll-4 f-loop; lmn2 (mi>=l) restricted.
template<int FIN, int FO>
__global__ __launch_bounds__(TPB) void k_zs_v4(const float2* __restrict__ G,
                                               const float2* __restrict__ khat,
                                               const int* __restrict__ lmn_l,
                                               const int* __restrict__ lmn2,
                                               float2* __restrict__ zs) {
    constexpr int NOG = FO / 3;
    int CHb = gridDim.x >> 3;
    int bid = blockIdx.x;
    int work = (bid & 7) * CHb + (bid >> 3);   // bijective; og-fastest
    if (work >= kCH2 * NOG) return;
    int x = work / NOG, og = work - x * NOG;
    int i2 = x * 256 + threadIdx.x;
    if (i2 >= kNMN2) return;
    int lmn = lmn2[i2];
    int l = lmn_l[lmn], r = lmn - off3i(l), R = 2 * l + 1;
    int n = r % R;
    int nu = (n - l) & 63;
    int o0 = og * 3;
    const float2* gp0 = G + lmn;
    const float2* gp1 = G + (size_t)FIN * kNMN + lmn;
    const float2* kp = khat + (size_t)o0 * 64 + nu;
    float2 c0[3], c1[3];
    #pragma unroll
    for (int i = 0; i < 3; i++) {
        c0[i] = make_float2(0.f, 0.f);
        c1[i] = make_float2(0.f, 0.f);
    }
    #pragma unroll 4
    for (int f = 0; f < FIN; f++) {
        float2 a0 = gp0[(size_t)f * kNMN];
        float2 a1 = gp1[(size_t)f * kNMN];
        const float2* kf = kp + (size_t)f * FO * 64;
        #pragma unroll
        for (int i = 0; i < 3; i++) {
            float2 b = kf[(size_t)i * 64];   // conj applied in the FMA signs
            c0[i].x += a0.x * b.x + a0.y * b.y;
            c0[i].y += a0.y * b.x - a0.x * b.y;
            c1[i].x += a1.x * b.x + a1.y * b.y;
            c1[i].y += a1.y * b.x - a1.x * b.y;
        }
    }
    float2* zp0 = zs + (size_t)o0 * kNMN + lmn;
    float2* zp1 = zs + ((size_t)FO + o0) * kNMN + lmn;
    #pragma unroll
    for (int i = 0; i < 3; i++) {
        zp0[(size_t)i * kNMN] = c0[i];
        zp1[(size_t)i * kNMN] = c1[i];
    }
}

// Synthesis stage A: dense accumulation; LDS z reads via b128.
// HERMITIAN: mu = 0..32 only; rows 33..63 derived in k_synB by conj-mirror.
// XCD-grouped decode: all NP p-blocks of one mu land on the same XCD, so the
// per-mu dqz slice (~(32-mu)*16KB, used by exactly one mu) stays L2-resident
// across its p-blocks instead of being re-fetched from L3 by every XCD.
__global__ __launch_bounds__(TPB) void k_synA(const float2* __restrict__ zs,
                                              const float* __restrict__ dqz,
                                              float2* __restrict__ T, int NP) {
    __shared__ float2 sZ[2 * 32 * 64];
    int CHb = gridDim.x >> 3;
    int work = ((blockIdx.x & 7) * CHb) + (blockIdx.x >> 3);   // bijective
    if (work >= 33 * NP) return;
    int mu = work / NP, p = work - mu * NP;
    int tid = threadIdx.x;
    int mt = (mu <= 31) ? mu : mu - 64;
    int am = mt < 0 ? -mt : mt;
    #pragma unroll
    for (int k = 0; k < 16; k++) {
        int i = tid + k * TPB;
        int nu = i & 63, l = (i >> 6) & 31, zo_i = i >> 11;
        int nt = (nu <= 31) ? nu : nu - 64;
        int an = nt < 0 ? -nt : nt;
        float2 v = make_float2(0.f, 0.f);
        if (l >= am && an <= l)
            v = zs[(size_t)(2 * p + zo_i) * kNMN + off3i(l) +
                   (mt + l) * (2 * l + 1) + nt + l];
        sZ[i] = v;
    }
    __syncthreads();
    int j = tid & 63, s = tid >> 6;
    float2 c0[16], c1[16];
    #pragma unroll
    for (int k = 0; k < 16; k++) {
        c0[k] = make_float2(0.f, 0.f);
        c1[k] = make_float2(0.f, 0.f);
    }
    for (int l = am; l < 32; l++) {
        const float* dp = dqz + ((size_t)(l * l + mt + l) * 64 + s * 16) * 64 + j;
        const float4* z04 = (const float4*)(sZ + (size_t)l * 64 + s * 16);
        const float4* z14 = (const float4*)(sZ + (size_t)(32 + l) * 64 + s * 16);
        #pragma unroll
        for (int h = 0; h < 8; h++) {
            float d0 = dp[(size_t)(2 * h) * 64];
            float d1 = dp[(size_t)(2 * h + 1) * 64];
            float4 za = z04[h];
            float4 zb = z14[h];
            c0[2 * h].x     += d0 * za.x; c0[2 * h].y     += d0 * za.y;
            c0[2 * h + 1].x += d1 * za.z; c0[2 * h + 1].y += d1 * za.w;
            c1[2 * h].x     += d0 * zb.x; c1[2 * h].y     += d0 * zb.y;
            c1[2 * h + 1].x += d1 * zb.z; c1[2 * h + 1].y += d1 * zb.w;
        }
    }
    float2* t0 = T + (((size_t)(2 * p + 0) * 64 + mu) * 64 + j) * 64 + s * 16;
    float2* t1 = T + (((size_t)(2 * p + 1) * 64 + mu) * 64 + j) * 64 + s * 16;
    #pragma unroll
    for (int k = 0; k < 16; k++) t0[k] = c0[k];
    #pragma unroll
    for (int k = 0; k < 16; k++) t1[k] = c1[k];
}

// Synthesis stage B: radix-8 x2 IDFT; real + bias out; fused BN-stats atomics.
// Stages T rows mu=0..32 from memory, rows 33..63 by Hermitian mirror in LDS.
__global__ __launch_bounds__(TPB) void k_synB(const float2* __restrict__ T,
                                              const float2* __restrict__ twi_g,
                                              const float* __restrict__ bias,
                                              float* __restrict__ yout,
                                              float* __restrict__ stats,
                                              int Fo, int zo0) {
    __shared__ float2 sF[64 * 66];
    __shared__ float2 tw[64];
    int blk = blockIdx.x;
    int zo_l = blk >> 6, j = blk & 63;
    int zo_g = zo0 + zo_l;
    int o = zo_g % Fo;
    int tid = threadIdx.x;
    if (tid < 64) tw[tid] = twi_g[tid];
    const float4* src4 = (const float4*)(T + (size_t)zo_l * kCube + (size_t)j * 64);
    for (int i = tid; i < 1056; i += TPB) {      // mu = 0..32 direct
        int mu = i >> 5, half = i & 31;
        float4 v = src4[(size_t)mu * 2048 + half];
        sF[mu * 66 + 2 * half]     = make_float2(v.x, v.y);
        sF[mu * 66 + 2 * half + 1] = make_float2(v.z, v.w);
    }
    __syncthreads();
    for (int i = tid; i < 31 * 64; i += TPB) {   // mu = 33..63 by Hermitian mirror
        int mu = 33 + (i >> 6), nu = i & 63;
        float2 v = sF[(64 - mu) * 66 + ((64 - nu) & 63)];
        sF[mu * 66 + nu] = make_float2(v.x, -v.y);
    }
    __syncthreads();
    float2 w8[8];
    #pragma unroll
    for (int k = 0; k < 8; k++) w8[k] = tw[k * 8];
    int r2 = tid >> 2, q = tid & 3;
    {   // dim-nu, complex in-place radix-8
        float2* mrow = sF + r2 * 66;
        #pragma unroll
        for (int half = 0; half < 2; half++) {
            int s = q + 4 * half;
            float2 f[8];
            #pragma unroll
            for (int p = 0; p < 8; p++) f[p] = mrow[8 * p + s];
            float2 ws = tw[s];
            float2 t = make_float2(1.f, 0.f);
            #pragma unroll
            for (int v = 0; v < 8; v++) {
                float re = 0, im = 0;
                #pragma unroll
                for (int p = 0; p < 8; p++) {
                    float2 w = w8[(v * p) & 7];
                    re += f[p].x * w.x - f[p].y * w.y;
                    im += f[p].x * w.y + f[p].y * w.x;
                }
                mrow[v * 8 + s] = make_float2(re * t.x - im * t.y, re * t.y + im * t.x);
                float tx = t.x * ws.x - t.y * ws.y;
                t.y = t.x * ws.y + t.y * ws.x; t.x = tx;
            }
        }
        float2 a[2][8];
        #pragma unroll
        for (int half = 0; half < 2; half++) {
            int v = q + 4 * half;
            #pragma unroll
            for (int s = 0; s < 8; s++) a[half][s] = mrow[v * 8 + s];
        }
        #pragma unroll
        for (int half = 0; half < 2; half++) {
            int v = q + 4 * half;
            #pragma unroll
            for (int u = 0; u < 8; u++) {
                float re = 0, im = 0;
                #pragma unroll
                for (int s = 0; s < 8; s++) {
                    float2 w = w8[(u * s) & 7];
                    re += a[half][s].x * w.x - a[half][s].y * w.y;
                    im += a[half][s].x * w.y + a[half][s].y * w.x;
                }
                mrow[8 * u + v] = make_float2(re, im);
            }
        }
    }
    __syncthreads();
    float s_acc = 0.f, q_acc = 0.f;
    {   // dim-mu, per column c; real + bias out
        int c = r2;
        float bo = bias[o];
        float* dst = yout + ((size_t)zo_g * 64 + j) * 4096;
        #pragma unroll
        for (int half = 0; half < 2; half++) {
            int s = q + 4 * half;
            float2 f[8];
            #pragma unroll
            for (int p = 0; p < 8; p++) f[p] = sF[(8 * p + s) * 66 + c];
            float2 ws = tw[s];
            float2 t = make_float2(1.f, 0.f);
            #pragma unroll
            for (int v = 0; v < 8; v++) {
                float re = 0, im = 0;
                #pragma unroll
                for (int p = 0; p < 8; p++) {
                    float2 w = w8[(v * p) & 7];
                    re += f[p].x * w.x - f[p].y * w.y;
                    im += f[p].x * w.y + f[p].y * w.x;
                }
                sF[(v * 8 + s) * 66 + c] = make_float2(re * t.x - im * t.y,
                                                       re * t.y + im * t.x);
                float tx = t.x * ws.x - t.y * ws.y;
                t.y = t.x * ws.y + t.y * ws.x; t.x = tx;
            }
        }
        float2 a[2][8];
        #pragma unroll
        for (int half = 0; half < 2; half++) {
            int v = q + 4 * half;
            #pragma unroll
            for (int s = 0; s < 8; s++) a[half][s] = sF[(v * 8 + s) * 66 + c];
        }
        #pragma unroll
        for (int half = 0; half < 2; half++) {
            int v = q + 4 * half;
            #pragma unroll
            for (int u = 0; u < 8; u++) {
                float re = 0;
                #pragma unroll
                for (int s = 0; s < 8; s++) {
                    float2 w = w8[(u * s) & 7];
                    re += a[half][s].x * w.x - a[half][s].y * w.y;
                }
                float val = re + bo;
                dst[(8 * u + v) * 64 + c] = val;
                s_acc += val;
                q_acc += val * val;
            }
        }
    }
    // fused BN stats: block reduce + 2 atomics (replaces k_bn_stats pass)
    __syncthreads();
    float* rs = (float*)sF;
    rs[tid] = s_acc;
    rs[TPB + tid] = q_acc;
    __syncthreads();
    for (int st = TPB / 2; st > 0; st >>= 1) {
        if (tid < st) { rs[tid] += rs[tid + st]; rs[TPB + tid] += rs[TPB + tid + st]; }
        __syncthreads();
    }
    if (tid == 0) {
        atomicAdd(&stats[o * 2], rs[0]);
        atomicAdd(&stats[o * 2 + 1], rs[TPB]);
    }
}

__global__ void k_final(const float* __restrict__ y, const float* __restrict__ stats,
                        const float* __restrict__ gamma, const float* __restrict__ beta,
                        float* __restrict__ out) {
    int t = blockIdx.x * TPB + threadIdx.x;
    if (t >= kB * kF2 * 4096) return;
    int zo = t >> 12, o = zo % kF2;
    const float inv = 1.0f / 524288.0f;
    float mean = stats[o * 2] * inv;
    float var = stats[o * 2 + 1] * inv - mean * mean;
    float rstd = rsqrtf(var + 1e-5f);
    float ga = gamma[o], be = beta[o];
    const float* p = y + (size_t)t * 64;
    float acc = 0;
    for (int g = 0; g < 64; g++) {
        float v = (p[g] - mean) * rstd * ga + be;
        acc += v > 0.f ? v : 0.f;
    }
    out[t] = acc * (1.0f / 64.0f);
}

// ---------------------------------------------------------------------------
extern "C" void kernel_launch(void* const* d_in, const int* in_sizes, int n_in,
                              void* d_out, int out_size, void* d_ws, size_t ws_size,
                              hipStream_t stream) {
    const float* x     = (const float*)d_in[0];
    const float* k1    = (const float*)d_in[1];
    const float* bias1 = (const float*)d_in[2];
    const float* g1    = (const float*)d_in[3];
    const float* be1   = (const float*)d_in[4];
    const float* k2    = (const float*)d_in[5];
    const float* bias2 = (const float*)d_in[6];
    const float* g2    = (const float*)d_in[7];
    const float* be2   = (const float*)d_in[8];
    const float* k3    = (const float*)d_in[9];
    const float* bias3 = (const float*)d_in[10];
    const float* g3    = (const float*)d_in[11];
    const float* be3   = (const float*)d_in[12];

    char* ws = (char*)d_ws;
    size_t off = 0;
    auto alloc = [&](size_t bytes) {
        size_t cur = off;
        off = (off + bytes + 255) & ~(size_t)255;
        return cur;
    };
    size_t o_const = alloc(g_tab.bytes);                       // 3.0 MB
    size_t o_dqz   = alloc((size_t)kNM * 64 * 64 * 4);         // 16.8 MB
    size_t o_dqtw  = alloc((size_t)64 * kNMN * 4);             // 11.2 MB
    size_t o_deTp  = alloc((size_t)4 * 11424 * 4);             // 0.18 MB (padded, full)
    size_t o_khat  = alloc((size_t)kF1 * kF1 * 64 * 8);        // 1.8 MB
    size_t o_xf1   = alloc((size_t)kB * kF0 * 64 * 64 * 8);    // 0.2 MB
    size_t o_fh1   = alloc((size_t)kNM * kB * kF0 * 8);        // 0.05 MB
    size_t o_stats = alloc(2 * 64 * 4);
    size_t o_fh    = alloc((size_t)kB * kF1 * kNMN * 8);       // 42 MB (fh, then zs)
    size_t o_scr   = alloc((size_t)kFCH * kCube * 8);          // 50.3 MB (dtmp/xf/G/T)
    size_t o_cube  = alloc((size_t)kB * kF1 * kCube * 4);      // 126 MB
    if (off > ws_size) return;

    const float* cb = (const float*)(ws + o_const);
    const float2* twf = (const float2*)(cb + g_tab.o_twf);
    const float2* twi = (const float2*)(cb + g_tab.o_twi);
    const float* w_t = cb + g_tab.o_w;
    const float* etab = cb + g_tab.o_etab;
    const float* dehalf = etab + (size_t)(8 + 4) * kNMN;  // G_4 = E0^32 = d(pi/2)
    const int* lmn_l = (const int*)(cb + g_tab.o_lmnl);
    const int* lm_l = (const int*)(cb + g_tab.o_lml);
    const int* lmn2 = (const int*)(cb + g_tab.o_lmn2);
    const int* lmq = (const int*)(cb + g_tab.o_lmq);
    const int* off4 = (const int*)(cb + g_tab.o_off4);

    float* dqz = (float*)(ws + o_dqz);
    float* dqtw = (float*)(ws + o_dqtw);
    float* deTp = (float*)(ws + o_deTp);
    float2* khat = (float2*)(ws + o_khat);
    float2* xf1 = (float2*)(ws + o_xf1);
    float2* fh1 = (float2*)(ws + o_fh1);
    float* stats = (float*)(ws + o_stats);
    float2* fh = (float2*)(ws + o_fh);
    float2* zsb = (float2*)(ws + o_fh);
    float* dtmp = (float*)(ws + o_scr);
    float2* Gb = (float2*)(ws + o_scr);
    float2* xfc = (float2*)(ws + o_scr);
    float2* Tb = (float2*)(ws + o_scr);
    float* cube = (float*)(ws + o_cube);

    hipMemcpyAsync(ws + o_const, g_tab.blob.data(), g_tab.bytes,
                   hipMemcpyHostToDevice, stream);
    hipMemsetAsync(dqz, 0, (size_t)kNM * 64 * 64 * 4, stream);
    hipMemsetAsync(deTp, 0, (size_t)4 * 11424 * 4, stream);
    k_gendqA<<<kLMAX * 64, TPB, 0, stream>>>(etab, dtmp);
    k_scat<<<kLMAX * 63, TPB, 0, stream>>>(dtmp, w_t, dqz, dqtw);
    k_transde_p<<<(kNMN + TPB - 1) / TPB, TPB, 0, stream>>>(dehalf, deTp, lmn_l, off4);

    const float S2S = 1.0f / sqrtf(64.0f * 3.0f * 1024.0f);
    const float SO3S = 1.0f / sqrtf(64.0f * 60.0f);
    auto blks = [](size_t n) { return (int)((n + TPB - 1) / TPB); };

    auto synth = [&](const float* bi, int Fo) {
        hipMemsetAsync(stats, 0, 2 * 64 * 4, stream);
        int planes = kB * Fo;
        for (int zo0 = 0; zo0 < planes; zo0 += kFCH) {
            int nzo = planes - zo0 < kFCH ? planes - zo0 : kFCH;
            int NP = nzo / 2;                       // 12
            int grid = 8 * ((33 * NP + 7) / 8);
            k_synA<<<grid, TPB, 0, stream>>>(
                zsb + (size_t)zo0 * kNMN, dqz, Tb, NP);
            k_synB<<<nzo * 64, TPB, 0, stream>>>(Tb, twi, bi, cube, stats, Fo, zo0);
        }
    };

    // ---- Layer 1: S2 conv -> cube ----
    k_khat<<<blks(kF0 * kF1 * 64), TPB, 0, stream>>>(k1, khat, twf, kF0 * kF1 * 64, S2S);
    k_fft1<<<blks(kB * kF0 * 64 * 64), TPB, 0, stream>>>(x, xf1, twf);
    k_fh1<<<blks(kNM * kB * kF0), TPB, 0, stream>>>(xf1, dqtw, lm_l, fh1);
    k_zs1<<<blks((size_t)(kF1 / 6) * kNMN2), TPB, 0, stream>>>(fh1, khat, dehalf,
                                                               lmn_l, lmn2, zsb);
    synth(bias1, kF1);

    // ---- Layers 2 & 3: SO3 conv; fft2 applies previous layer's BN+ReLU ----
    for (int layer = 2; layer <= 3; layer++) {
        int Fo = (layer == 2) ? kF1 : kF2;
        const float* kk = (layer == 2) ? k2 : k3;
        const float* bi = (layer == 2) ? bias2 : bias3;
        const float* gp = (layer == 2) ? g1 : g2;
        const float* bp = (layer == 2) ? be1 : be2;
        k_khat<<<blks(kF1 * Fo * 64), TPB, 0, stream>>>(kk, khat, twf, kF1 * Fo * 64, SO3S);
        for (int zf0 = 0; zf0 < kB * kF1; zf0 += kFCH) {
            int nzf = kB * kF1 - zf0 < kFCH ? kB * kF1 - zf0 : kFCH;
            k_fft2<<<nzf * 64, TPB, 0, stream>>>(cube + (size_t)zf0 * kCube, xfc,
                                                 twf, stats, gp, bp, zf0);
            k_fh3<<<2048, TPB, 0, stream>>>(xfc, dqtw, fh + (size_t)zf0 * kNMN, nzf);
        }
        {
            int total = kB * kF1 * kNQ2;
            k_G4<<<blks(total), TPB, 0, stream>>>(fh, deTp, lmq, off4, Gb, total);
        }
        if (layer == 2) {
            int nOg = kF1 / 3;
            int CHb = (kCH2 * nOg + 7) / 8;
            k_zs_v4<60, 60><<<8 * CHb, TPB, 0, stream>>>(Gb, khat, lmn_l, lmn2, zsb);
        } else {
            int nOg = kF2 / 3;
            int CHb = (kCH2 * nOg + 7) / 8;
            k_zs_v4<60, 36><<<8 * CHb, TPB, 0, stream>>>(Gb, khat, lmn_l, lmn2, zsb);
        }
        synth(bi, Fo);
        if (layer == 3)
            k_final<<<blks(kB * kF2 * 4096), TPB, 0, stream>>>(cube, stats, g3, be3, (float*)d_out);
    }
}

// Round 12
// 1944.970 us; speedup vs baseline: 1.0275x; 1.0275x over previous
//
#include <hip/hip_runtime.h>
#include <cmath>
#include <cstring>
#include <cstdint>
#include <vector>

#define TPB 256
static constexpr int kLMAX = 32;
static constexpr int kNMN  = 43680;   // sum_{l<32} (2l+1)^2
static constexpr int kNMN2 = 22352;   // sum_{l<32} (l+1)(2l+1)  (m>=0 rows only)
static constexpr int kNM   = 1024;    // sum_{l<32} (2l+1)
static constexpr int kNQ2  = 5848;    // sum_{l<32} (l+1)*ceil((2l+1)/4)
static constexpr int kB    = 2;
static constexpr int kF0   = 3, kF1 = 60, kF2 = 36;
static constexpr int kCube = 262144;  // 64^3
static constexpr int kFCH  = 24;      // plane chunk (divides 120 and 72)
static constexpr int kCH2  = (kNMN2 + 255) / 256;   // 88 lmn2-chunks of 256

__host__ __device__ inline int off3i(int l) { return l * (4 * l * l - 1) / 3; }

// ---------------------------------------------------------------------------
// Host-side constant tables (~3.0 MB seeds; d_b = F_{b&7} * G_{b>>3}).
// Hermitian dead-code note: synA (mu<=32) only reads zs rows with m>=0, so
// the zs/G/fh chain is computed ONLY for mi>=l (lmn2/lmq tables below), and
// fh3/fft2 only produce the mu in [0,31] half of the spectrum.
// ---------------------------------------------------------------------------
static void h_matmul(const std::vector<double>& A, const std::vector<double>& B,
                     std::vector<double>& C, int n) {
    C.assign((size_t)n * n, 0.0);
    for (int i = 0; i < n; i++)
        for (int k = 0; k < n; k++) {
            double a = A[(size_t)i * n + k];
            if (a == 0.0) continue;
            const double* bp = &B[(size_t)k * n];
            double* cp = &C[(size_t)i * n];
            for (int j = 0; j < n; j++) cp[j] += a * bp[j];
        }
}

struct HostTables {
    std::vector<float> blob;
    size_t o_twf, o_twi, o_w, o_lmnl, o_lml, o_lmn2, o_lmq, o_off4, o_etab;
    size_t bytes;
    HostTables() {
        size_t n = 0;
        o_twf = n;  n += 128;
        o_twi = n;  n += 128;
        o_w = n;    n += 64;
        o_lmnl = n; n += kNMN;
        o_lml = n;  n += kNM;
        o_lmn2 = n; n += kNMN2;
        o_lmq = n;  n += kNQ2;
        o_off4 = n; n += 32;
        o_etab = n; n += (size_t)16 * kNMN;    // [F_0..F_7, G_0..G_7] per l
        blob.assign(n, 0.0f);
        bytes = n * 4;

        for (int k = 0; k < 64; k++) {
            double th = -2.0 * M_PI * k / 64.0;
            blob[o_twf + 2 * k]     = (float)cos(th);
            blob[o_twf + 2 * k + 1] = (float)sin(th);
            blob[o_twi + 2 * k]     = (float)cos(th);
            blob[o_twi + 2 * k + 1] = (float)(-sin(th));
        }
        for (int j = 0; j < 64; j++) {
            double s = 0;
            for (int k = 0; k < 32; k++)
                s += sin((2.0 * j + 1) * (2.0 * k + 1) * M_PI / 128.0) / (2.0 * k + 1);
            blob[o_w + j] = (float)(2.0 / 32.0 * sin(M_PI * (2.0 * j + 1) / 128.0) * s);
        }
        // lmn2: compact index of (l, mi>=l, ni) -> original lmn offset.
        {
            int qi = 0;
            for (int l = 0; l < kLMAX; l++) {
                int R = 2 * l + 1, o3 = off3i(l);
                for (int mi = l; mi < R; mi++)
                    for (int ni = 0; ni < R; ni++) {
                        int32_t v = o3 + mi * R + ni;
                        memcpy(&blob[o_lmn2 + qi], &v, 4);
                        qi++;
                    }
            }
        }
        // q -> (l, mi>=l, n0) table for n4-blocked k_G4, and padded-deT offsets.
        {
            int qi = 0, acc4 = 0;
            for (int l = 0; l < kLMAX; l++) {
                int R = 2 * l + 1, Rp = (R + 3) & ~3, C = Rp >> 2;
                int32_t o4 = acc4;
                memcpy(&blob[o_off4 + l], &o4, 4);
                for (int m = l; m < R; m++)
                    for (int c = 0; c < C; c++) {
                        int32_t pk = l | (m << 5) | ((4 * c) << 11);
                        memcpy(&blob[o_lmq + qi], &pk, 4);
                        qi++;
                    }
                acc4 += R * Rp;
            }
        }
        std::vector<double> A, Eh, E0, E08, F, G, term, tmp;
        for (int l = 0; l < kLMAX; l++) {
            int R = 2 * l + 1, o3 = off3i(l);
            A.assign((size_t)R * R, 0.0);
            for (int i = 0; i + 1 < R; i++) {
                double m = (double)i - l;
                double c = sqrt((double)l * (l + 1) - m * (m + 1));
                A[(size_t)(i + 1) * R + i] = -(M_PI / 128.0) * c * 0.5;
                A[(size_t)i * R + (i + 1)] =  (M_PI / 128.0) * c * 0.5;
            }
            Eh.assign((size_t)R * R, 0.0);
            for (int i = 0; i < R; i++) Eh[(size_t)i * R + i] = 1.0;
            term = Eh;
            for (int k = 1; k <= 30; k++) {
                h_matmul(term, A, tmp, R);
                for (auto& v : tmp) v /= k;
                term = tmp;
                for (size_t i = 0; i < (size_t)R * R; i++) Eh[i] += term[i];
            }
            h_matmul(Eh, Eh, E0, R);
            h_matmul(E0, E0, tmp, R);
            h_matmul(tmp, tmp, E08, R);
            h_matmul(E08, E08, tmp, R); E08 = tmp;  // E0^8
            F = Eh;
            for (int lo = 0; lo < 8; lo++) {
                for (int r = 0; r < R * R; r++)
                    blob[o_etab + (size_t)lo * kNMN + o3 + r] = (float)F[r];
                if (lo < 7) { h_matmul(F, E0, tmp, R); F = tmp; }
            }
            G.assign((size_t)R * R, 0.0);
            for (int i = 0; i < R; i++) G[(size_t)i * R + i] = 1.0;
            for (int hi = 0; hi < 8; hi++) {
                for (int r = 0; r < R * R; r++)
                    blob[o_etab + (size_t)(8 + hi) * kNMN + o3 + r] = (float)G[r];
                if (hi < 7) { h_matmul(G, E08, tmp, R); G = tmp; }
            }
            int32_t li = l;
            for (int r = 0; r < R * R; r++) memcpy(&blob[o_lmnl + o3 + r], &li, 4);
            for (int m = 0; m < R; m++)    memcpy(&blob[o_lml + (size_t)l * l + m], &li, 4);
        }
    }
};
static HostTables g_tab;

// ---------------------------------------------------------------------------
__global__ __launch_bounds__(TPB) void k_gendqA(const float* __restrict__ etab,
                                                float* __restrict__ dtmp) {
    __shared__ float Fm[3969];
    __shared__ float Gm[63 * 64];
    int l = blockIdx.x >> 6, b = blockIdx.x & 63;
    int lo = b & 7, hi = b >> 3;
    int R = 2 * l + 1, RR = R * R, o3 = off3i(l);
    int tid = threadIdx.x;
    const float* Fsrc = etab + (size_t)lo * kNMN + o3;
    const float* Gsrc = etab + (size_t)(8 + hi) * kNMN + o3;
    for (int i = tid; i < RR; i += TPB) Fm[i] = Fsrc[i];
    for (int i = tid; i < R * 64; i += TPB) {
        int k = i >> 6, c = i & 63;
        Gm[i] = (c < R) ? Gsrc[k * R + c] : 0.f;
    }
    __syncthreads();
    int Gc = (R + 15) >> 4;
    if (tid < R * Gc) {
        int row = tid / Gc, g = tid - row * Gc;
        float4 A0 = make_float4(0,0,0,0), A1 = A0, A2 = A0, A3 = A0;
        const float* fr = Fm + row * R;
        for (int k = 0; k < R; k++) {
            float a = fr[k];
            const float4* gp = (const float4*)(Gm + (k << 6) + (g << 4));
            float4 q0 = gp[0], q1 = gp[1], q2 = gp[2], q3 = gp[3];
            A0.x += a * q0.x; A0.y += a * q0.y; A0.z += a * q0.z; A0.w += a * q0.w;
            A1.x += a * q1.x; A1.y += a * q1.y; A1.z += a * q1.z; A1.w += a * q1.w;
            A2.x += a * q2.x; A2.y += a * q2.y; A2.z += a * q2.z; A2.w += a * q2.w;
            A3.x += a * q3.x; A3.y += a * q3.y; A3.z += a * q3.z; A3.w += a * q3.w;
        }
        float v[16] = {A0.x,A0.y,A0.z,A0.w, A1.x,A1.y,A1.z,A1.w,
                       A2.x,A2.y,A2.z,A2.w, A3.x,A3.y,A3.z,A3.w};
        float* dst = dtmp + (size_t)o3 * 64 + (size_t)b * RR + row * R;
        int c0 = g << 4;
        #pragma unroll
        for (int e = 0; e < 16; e++)
            if (c0 + e < R) dst[c0 + e] = v[e];
    }
}

__global__ __launch_bounds__(TPB) void k_scat(const float* __restrict__ dtmp,
                                              const float* __restrict__ w,
                                              float* __restrict__ dqz,
                                              float* __restrict__ dqtw) {
    __shared__ float S[64 * 65];
    int l = blockIdx.x / 63, tile = blockIdx.x % 63;
    int R = 2 * l + 1, RR = R * R, o3 = off3i(l);
    int i0 = tile * 64;
    if (i0 >= RR) return;
    int tid = threadIdx.x;
    const float* src = dtmp + (size_t)o3 * 64;
    #pragma unroll
    for (int s = 0; s < 16; s++) {
        int idx = tid + s * TPB;
        int b = idx >> 6, ii = idx & 63;
        int i = i0 + ii;
        S[ii * 65 + b] = (i < RR) ? src[(size_t)b * RR + i] : 0.f;
    }
    __syncthreads();
    float Rf = (float)R;
    #pragma unroll
    for (int s = 0; s < 16; s++) {
        int idx = tid + s * TPB;
        int ii = idx >> 6, b = idx & 63;
        int i = i0 + ii;
        if (i < RR) {
            float v = S[ii * 65 + b];
            dqtw[((size_t)o3 + i) * 64 + b] = w[b] * v;
            int mi = i / R, ni = i - mi * R;
            int nu = (ni - l) & 63;
            dqz[((size_t)(l * l + mi) * 64 + nu) * 64 + b] = Rf * v;
        }
    }
}

// Builds padded-row deTp: deTp[off4(l) + k*Rp + n] = dehalf[o3 + n*R + k],
// Rp = ceil(R/4)*4. Pad entries stay zero (memset upstream).
__global__ void k_transde_p(const float* __restrict__ dehalf, float* __restrict__ deTp,
                            const int* __restrict__ lmn_l, const int* __restrict__ off4) {
    int t = blockIdx.x * TPB + threadIdx.x;
    if (t >= kNMN) return;
    int l = lmn_l[t], o3 = off3i(l), r = t - o3, R = 2 * l + 1;
    int Rp = (R + 3) & ~3;
    int n = r / R, k = r - n * R;
    deTp[off4[l] + k * Rp + n] = dehalf[t];
}

__global__ void k_khat(const float* __restrict__ kern, float2* __restrict__ khat,
                       const float2* __restrict__ twf, int total, float scale) {
    int t = blockIdx.x * TPB + threadIdx.x;
    if (t >= total) return;
    int nu = t & 63, fo = t >> 6;
    const float* row = kern + (size_t)fo * 64;
    float re = 0, im = 0;
    for (int p = 0; p < 64; p++) {
        float2 w = twf[(p * nu) & 63];
        float v = row[p];
        re += v * w.x; im += v * w.y;
    }
    khat[t] = make_float2(re * scale, im * scale);
}

__global__ void k_fft1(const float* __restrict__ x, float2* __restrict__ xf1,
                       const float2* __restrict__ twf) {
    int t = blockIdx.x * TPB + threadIdx.x;
    if (t >= kB * kF0 * 64 * 64) return;
    int mu = t & 63, row = t >> 6;
    const float* p = x + (size_t)row * 64;
    float re = 0, im = 0;
    for (int a = 0; a < 64; a++) {
        float2 w = twf[(a * mu) & 63];
        float v = p[a];
        re += v * w.x; im += v * w.y;
    }
    xf1[t] = make_float2(re, im);
}

__global__ void k_fh1(const float2* __restrict__ xf1, const float* __restrict__ dqtw,
                      const int* __restrict__ lm_l, float2* __restrict__ fh1) {
    int t = blockIdx.x * TPB + threadIdx.x;
    if (t >= kNM * kB * kF0) return;
    int lm = t / 6, rem = t % 6, z = rem / 3, f = rem % 3;
    int l = lm_l[lm], m = lm - l * l, R = 2 * l + 1, o3 = off3i(l);
    int mu = (m - l) & 63;
    const float4* wq = (const float4*)(dqtw + (size_t)o3 * 64 + (size_t)(m * R + l) * 64);
    const float2* xr = xf1 + (size_t)((z * 3 + f) * 64) * 64 + mu;
    float re0 = 0, im0 = 0, re1 = 0, im1 = 0;
    #pragma unroll
    for (int b4 = 0; b4 < 16; b4++) {
        float4 w4 = wq[b4];
        float2 v0 = xr[(4 * b4 + 0) * 64];
        float2 v1 = xr[(4 * b4 + 1) * 64];
        float2 v2 = xr[(4 * b4 + 2) * 64];
        float2 v3 = xr[(4 * b4 + 3) * 64];
        re0 += w4.x * v0.x + w4.y * v1.x; im0 += w4.x * v0.y + w4.y * v1.y;
        re1 += w4.z * v2.x + w4.w * v3.x; im1 += w4.z * v2.y + w4.w * v3.y;
    }
    const float C2 = 1.0f / 128.0f;
    fh1[t] = make_float2((re0 + re1) * C2, (im0 + im1) * C2);
}

// Layer-1 zs restricted to lmn2 (mi>=l): synA never reads m<0 rows.
__global__ void k_zs1(const float2* __restrict__ fh1, const float2* __restrict__ khat,
                      const float* __restrict__ dehalf, const int* __restrict__ lmn_l,
                      const int* __restrict__ lmn2, float2* __restrict__ zs) {
    int nOg = kF1 / 6;                       // 10
    int t = blockIdx.x * TPB + threadIdx.x;  // og*NMN2 + i2
    if (t >= nOg * kNMN2) return;
    int i2 = t % kNMN2, og = t / kNMN2;
    int lmn = lmn2[i2];
    int l = lmn_l[lmn], o3 = off3i(l), r = lmn - o3, R = 2 * l + 1;
    int m = r / R, n = r - m * R;
    int nu = (n - l) & 63;
    float de1 = dehalf[o3 + n * R + l];
    int o0 = og * 6;
    const float2* fp = fh1 + (size_t)(l * l + m) * 6;
    const float2* kp = khat + (size_t)o0 * 64 + nu;
    float2 c0[6], c1[6];
    #pragma unroll
    for (int i = 0; i < 6; i++) {
        c0[i] = make_float2(0.f, 0.f);
        c1[i] = make_float2(0.f, 0.f);
    }
    #pragma unroll
    for (int f = 0; f < kF0; f++) {
        float2 a0 = fp[f];       // z = 0
        float2 a1 = fp[3 + f];   // z = 1
        const float2* kf = kp + (size_t)f * kF1 * 64;
        #pragma unroll
        for (int i = 0; i < 6; i++) {
            float2 b = kf[(size_t)i * 64];   // conj applied below
            c0[i].x += a0.x * b.x + a0.y * b.y;
            c0[i].y += a0.y * b.x - a0.x * b.y;
            c1[i].x += a1.x * b.x + a1.y * b.y;
            c1[i].y += a1.y * b.x - a1.x * b.y;
        }
    }
    float2* zp0 = zs + (size_t)o0 * kNMN + lmn;
    float2* zp1 = zs + ((size_t)kF1 + o0) * kNMN + lmn;
    #pragma unroll
    for (int i = 0; i < 6; i++) {
        zp0[(size_t)i * kNMN] = make_float2(c0[i].x * de1, c0[i].y * de1);
        zp1[(size_t)i * kNMN] = make_float2(c1[i].x * de1, c1[i].y * de1);
    }
}

// 2D forward DFT (radix-8 x2) with fused BN+ReLU; float4 staging.
// HERMITIAN DCE (output): k_fh3 reads only mu in [0,31] -> pass-2 computes
// only u<4. HERMITIAN (input): rows are REAL, so pass-1 output satisfies
// F[64-nu] = conj(F[nu]); pass-1 stage-2 computes nu<=32 and mirrors 33..63
// in LDS (intra-wave lockstep, same reliance as the cross-lane stage reads).
__global__ __launch_bounds__(TPB) void k_fft2(const float* __restrict__ y,
                                              float2* __restrict__ xf,
                                              const float2* __restrict__ twf_g,
                                              const float* __restrict__ stats,
                                              const float* __restrict__ gamma,
                                              const float* __restrict__ beta,
                                              int zf0) {
    __shared__ float sIn[64 * 65];
    __shared__ float2 sMid[64 * 66];
    __shared__ float2 tw[64];
    int blk = blockIdx.x, tid = threadIdx.x;
    if (tid < 64) tw[tid] = twf_g[tid];
    int o = (zf0 + (blk >> 6)) % kF1;
    const float inv = 1.0f / 524288.0f;
    float mean = stats[o * 2] * inv;
    float var = stats[o * 2 + 1] * inv - mean * mean;
    float rstd = rsqrtf(var + 1e-5f);
    float ga = gamma[o], be = beta[o];
    const float4* src4 = (const float4*)(y + (size_t)blk * 4096);
    for (int i = tid; i < 1024; i += TPB) {
        float4 v4 = src4[i];
        int row = i >> 4, col = (i & 15) << 2;
        float* d = sIn + row * 65 + col;
        float a0 = (v4.x - mean) * rstd * ga + be;
        float a1 = (v4.y - mean) * rstd * ga + be;
        float a2 = (v4.z - mean) * rstd * ga + be;
        float a3 = (v4.w - mean) * rstd * ga + be;
        d[0] = a0 > 0.f ? a0 : 0.f;
        d[1] = a1 > 0.f ? a1 : 0.f;
        d[2] = a2 > 0.f ? a2 : 0.f;
        d[3] = a3 > 0.f ? a3 : 0.f;
    }
    __syncthreads();
    float2 w8[8];
    #pragma unroll
    for (int k = 0; k < 8; k++) w8[k] = tw[k * 8];
    int r2 = tid >> 2, q = tid & 3;
    {   // dim-1: g -> nu, REAL input
        const float* rowp = sIn + r2 * 65;
        float2* mrow = sMid + r2 * 66;
        #pragma unroll
        for (int half = 0; half < 2; half++) {
            int s = q + 4 * half;
            float f[8];
            #pragma unroll
            for (int p = 0; p < 8; p++) f[p] = rowp[8 * p + s];
            float2 ws = tw[s];
            float2 t = make_float2(1.f, 0.f);
            #pragma unroll
            for (int v = 0; v < 8; v++) {
                float re = 0, im = 0;
                #pragma unroll
                for (int p = 0; p < 8; p++) {
                    float2 w = w8[(v * p) & 7];
                    re += f[p] * w.x; im += f[p] * w.y;
                }
                mrow[v * 8 + s] = make_float2(re * t.x - im * t.y, re * t.y + im * t.x);
                float tx = t.x * ws.x - t.y * ws.y;
                t.y = t.x * ws.y + t.y * ws.x; t.x = tx;
            }
        }
        float2 a[2][8];
        #pragma unroll
        for (int half = 0; half < 2; half++) {
            int v = q + 4 * half;
            #pragma unroll
            for (int s = 0; s < 8; s++) a[half][s] = mrow[v * 8 + s];
        }
        #pragma unroll
        for (int half = 0; half < 2; half++) {
            int v = q + 4 * half;
            #pragma unroll
            for (int u = 0; u < 4; u++) {   // nu = 8u+v in [0,31]
                float re = 0, im = 0;
                #pragma unroll
                for (int s = 0; s < 8; s++) {
                    float2 w = w8[(u * s) & 7];
                    re += a[half][s].x * w.x - a[half][s].y * w.y;
                    im += a[half][s].x * w.y + a[half][s].y * w.x;
                }
                mrow[8 * u + v] = make_float2(re, im);
            }
        }
        if (q == 0) {   // nu = 32 (u=4, v=0): only the half=0, v=0 slot
            float re = 0, im = 0;
            #pragma unroll
            for (int s = 0; s < 8; s++) {
                float2 w = w8[(4 * s) & 7];
                re += a[0][s].x * w.x - a[0][s].y * w.y;
                im += a[0][s].x * w.y + a[0][s].y * w.x;
            }
            mrow[32] = make_float2(re, im);
        }
        // mirror nu = 33..63: F[nu] = conj(F[64-nu]) (real input rows).
        for (int nu = 33 + q; nu < 64; nu += 4) {
            float2 vv = mrow[64 - nu];
            mrow[nu] = make_float2(vv.x, -vv.y);
        }
    }
    __syncthreads();
    {   // dim-2: a -> mu per column c; only mu < 32 needed downstream
        int c = r2;
        float2* dst = xf + (size_t)blk * 4096;
        #pragma unroll
        for (int half = 0; half < 2; half++) {
            int s = q + 4 * half;
            float2 f[8];
            #pragma unroll
            for (int p = 0; p < 8; p++) f[p] = sMid[(8 * p + s) * 66 + c];
            float2 ws = tw[s];
            float2 t = make_float2(1.f, 0.f);
            #pragma unroll
            for (int v = 0; v < 8; v++) {
                float re = 0, im = 0;
                #pragma unroll
                for (int p = 0; p < 8; p++) {
                    float2 w = w8[(v * p) & 7];
                    re += f[p].x * w.x - f[p].y * w.y;
                    im += f[p].x * w.y + f[p].y * w.x;
                }
                sMid[(v * 8 + s) * 66 + c] = make_float2(re * t.x - im * t.y,
                                                         re * t.y + im * t.x);
                float tx = t.x * ws.x - t.y * ws.y;
                t.y = t.x * ws.y + t.y * ws.x; t.x = tx;
            }
        }
        float2 a[2][8];
        #pragma unroll
        for (int half = 0; half < 2; half++) {
            int v = q + 4 * half;
            #pragma unroll
            for (int s = 0; s < 8; s++) a[half][s] = sMid[(v * 8 + s) * 66 + c];
        }
        #pragma unroll
        for (int half = 0; half < 2; half++) {
            int v = q + 4 * half;
            #pragma unroll
            for (int u = 0; u < 4; u++) {   // mu = 8u+v in [0,31] only
                float re = 0, im = 0;
                #pragma unroll
                for (int s = 0; s < 8; s++) {
                    float2 w = w8[(u * s) & 7];
                    re += a[half][s].x * w.x - a[half][s].y * w.y;
                    im += a[half][s].x * w.y + a[half][s].y * w.x;
                }
                dst[(8 * u + v) * 64 + c] = make_float2(re, im);
            }
        }
    }
}

// fh3: one block per (mu,nu) column, mu in [0..31] ONLY (m>=0 rows; the m<0
// half of fh is dead code downstream). X and dqtw staged once in LDS.
// XCD swizzle in 256-block chunks: per-XCD xf slice = 4 mu rows ~ 3 MB < L2.
__global__ __launch_bounds__(TPB) void k_fh3(const float2* __restrict__ xf,
                                             const float* __restrict__ dqtw,
                                             float2* __restrict__ fh_out, int nzf) {
    __shared__ float2 sX[24 * 66];   // [zf][b], row stride 66 float2
    __shared__ float  sD[32 * 68];   // [li][b], row stride 68 floats
    int v = blockIdx.x;              // 2048 blocks
    int wg = (v & 7) * 256 + (v >> 3);
    int nu = wg & 63, mu = wg >> 6;  // mu in [0,31] -> mt = mu >= 0
    int mt = mu;
    int nt = (nu <= 31) ? nu : nu - 64;
    int am = mu, an = nt < 0 ? -nt : nt;
    int lmin = am > an ? am : an;
    if (lmin >= kLMAX) return;
    int nl = kLMAX - lmin;
    int tid = threadIdx.x;
    for (int i = tid; i < nzf * 64; i += TPB) {
        int zf = i >> 6, b = i & 63;
        sX[zf * 66 + b] = xf[(size_t)zf * kCube + (size_t)b * 4096 + mu * 64 + nu];
    }
    for (int i = tid; i < nl * 64; i += TPB) {
        int li = i >> 6, b = i & 63;
        int l = lmin + li, R = 2 * l + 1;
        int r = (mt + l) * R + (nt + l);
        sD[li * 68 + b] = dqtw[(size_t)(off3i(l) + r) * 64 + b];
    }
    __syncthreads();
    const float C3 = 1.0f / 8192.0f;
    int items = nzf * nl;
    for (int item = tid; item < items; item += TPB) {
        int zf = item / nl, li = item - zf * nl;
        const float4* D4 = (const float4*)(sD + li * 68);
        const float4* X4 = (const float4*)(sX + zf * 66);
        float re0 = 0, im0 = 0, re1 = 0, im1 = 0;
        #pragma unroll
        for (int b4 = 0; b4 < 16; b4++) {
            float4 d   = D4[b4];
            float4 x01 = X4[2 * b4];
            float4 x23 = X4[2 * b4 + 1];
            re0 += d.x * x01.x; im0 += d.x * x01.y;
            re0 += d.y * x01.z; im0 += d.y * x01.w;
            re1 += d.z * x23.x; im1 += d.z * x23.y;
            re1 += d.w * x23.z; im1 += d.w * x23.w;
        }
        int l = lmin + li, R = 2 * l + 1;
        int r = (mt + l) * R + (nt + l);
        fh_out[(size_t)zf * kNMN + off3i(l) + r] =
            make_float2((re0 + re1) * C3, (im0 + im1) * C3);
    }
}

// G (n4-blocked, mi>=l rows only): thread computes 4 consecutive n outputs.
// Per k: 1 float2 fh broadcast + 1 aligned float4 deTp row-load -> 16 lane-FMA.
__global__ void k_G4(const float2* __restrict__ fh, const float* __restrict__ deTp,
                     const int* __restrict__ lmq, const int* __restrict__ off4,
                     float2* __restrict__ G, int total) {
    int t = blockIdx.x * TPB + threadIdx.x;
    if (t >= total) return;
    int q = t % kNQ2, zf = t / kNQ2;
    int pk = lmq[q];
    int l = pk & 31, m = (pk >> 5) & 63, n0 = pk >> 11;
    int R = 2 * l + 1, o3 = off3i(l);
    int C4 = ((R + 3) & ~3) >> 2;            // Rp/4
    const float2* fr = fh + (size_t)zf * kNMN + o3 + m * R;
    const float4* dp = (const float4*)(deTp + off4[l] + n0);
    float4 re = make_float4(0.f, 0.f, 0.f, 0.f);
    float4 im = make_float4(0.f, 0.f, 0.f, 0.f);
    int k = 0;
    for (; k + 1 < R; k += 2) {
        float2 f0 = fr[k], f1 = fr[k + 1];
        float4 d0 = dp[(size_t)k * C4];
        float4 d1 = dp[(size_t)(k + 1) * C4];
        re.x += f0.x * d0.x + f1.x * d1.x; im.x += f0.y * d0.x + f1.y * d1.x;
        re.y += f0.x * d0.y + f1.x * d1.y; im.y += f0.y * d0.y + f1.y * d1.y;
        re.z += f0.x * d0.z + f1.x * d1.z; im.z += f0.y * d0.z + f1.y * d1.z;
        re.w += f0.x * d0.w + f1.x * d1.w; im.w += f0.y * d0.w + f1.y * d1.w;
    }
    {
        float2 f0 = fr[k];
        float4 d0 = dp[(size_t)k * C4];
        re.x += f0.x * d0.x; im.x += f0.y * d0.x;
        re.y += f0.x * d0.y; im.y += f0.y * d0.y;
        re.z += f0.x * d0.z; im.z += f0.y * d0.z;
        re.w += f0.x * d0.w; im.w += f0.y * d0.w;
    }
    float2* gp = G + (size_t)zf * kNMN + o3 + m * R + n0;
    int rem = R - n0;
    gp[0] = make_float2(re.x, im.x);
    if (rem > 1) gp[1] = make_float2(re.y, im.y);
    if (rem > 2) gp[2] = make_float2(re.z, im.z);
    if (rem > 3) gp[3] = make_float2(re.w, im.w);
}

// zs v4: og-tile 3; barrier-free body + og-fastest XCD-grouped decode +
// compile-time FIN/FO + unroll-4 f-loop; lmn2 (mi>=l) restricted.
template<int FIN, int FO>
__global__ __launch_bounds__(TPB) void k_zs_v4(const float2* __restrict__ G,
                                               const float2* __restrict__ khat,
                                               const int* __restrict__ lmn_l,
                                               const int* __restrict__ lmn2,
                                               float2* __restrict__ zs) {
    constexpr int NOG = FO / 3;
    int CHb = gridDim.x >> 3;
    int bid = blockIdx.x;
    int work = (bid & 7) * CHb + (bid >> 3);   // bijective; og-fastest
    if (work >= kCH2 * NOG) return;
    int x = work / NOG, og = work - x * NOG;
    int i2 = x * 256 + threadIdx.x;
    if (i2 >= kNMN2) return;
    int lmn = lmn2[i2];
    int l = lmn_l[lmn], r = lmn - off3i(l), R = 2 * l + 1;
    int n = r % R;
    int nu = (n - l) & 63;
    int o0 = og * 3;
    const float2* gp0 = G + lmn;
    const float2* gp1 = G + (size_t)FIN * kNMN + lmn;
    const float2* kp = khat + (size_t)o0 * 64 + nu;
    float2 c0[3], c1[3];
    #pragma unroll
    for (int i = 0; i < 3; i++) {
        c0[i] = make_float2(0.f, 0.f);
        c1[i] = make_float2(0.f, 0.f);
    }
    #pragma unroll 4
    for (int f = 0; f < FIN; f++) {
        float2 a0 = gp0[(size_t)f * kNMN];
        float2 a1 = gp1[(size_t)f * kNMN];
        const float2* kf = kp + (size_t)f * FO * 64;
        #pragma unroll
        for (int i = 0; i < 3; i++) {
            float2 b = kf[(size_t)i * 64];   // conj applied in the FMA signs
            c0[i].x += a0.x * b.x + a0.y * b.y;
            c0[i].y += a0.y * b.x - a0.x * b.y;
            c1[i].x += a1.x * b.x + a1.y * b.y;
            c1[i].y += a1.y * b.x - a1.x * b.y;
        }
    }
    float2* zp0 = zs + (size_t)o0 * kNMN + lmn;
    float2* zp1 = zs + ((size_t)FO + o0) * kNMN + lmn;
    #pragma unroll
    for (int i = 0; i < 3; i++) {
        zp0[(size_t)i * kNMN] = c0[i];
        zp1[(size_t)i * kNMN] = c1[i];
    }
}

// Synthesis stage A: dense accumulation; LDS z reads via b128.
// HERMITIAN: launched with gridDim.x = 33 (mu = 0..32); rows 33..63 are
// derived in k_synB via T[-mu,-nu] = conj(T[mu,nu]) (real-output symmetry).
__global__ __launch_bounds__(TPB) void k_synA(const float2* __restrict__ zs,
                                              const float* __restrict__ dqz,
                                              float2* __restrict__ T) {
    __shared__ float2 sZ[2 * 32 * 64];
    int mu = blockIdx.x, p = blockIdx.y;
    int tid = threadIdx.x;
    int mt = (mu <= 31) ? mu : mu - 64;
    int am = mt < 0 ? -mt : mt;
    #pragma unroll
    for (int k = 0; k < 16; k++) {
        int i = tid + k * TPB;
        int nu = i & 63, l = (i >> 6) & 31, zo_i = i >> 11;
        int nt = (nu <= 31) ? nu : nu - 64;
        int an = nt < 0 ? -nt : nt;
        float2 v = make_float2(0.f, 0.f);
        if (l >= am && an <= l)
            v = zs[(size_t)(2 * p + zo_i) * kNMN + off3i(l) +
                   (mt + l) * (2 * l + 1) + nt + l];
        sZ[i] = v;
    }
    __syncthreads();
    int j = tid & 63, s = tid >> 6;
    float2 c0[16], c1[16];
    #pragma unroll
    for (int k = 0; k < 16; k++) {
        c0[k] = make_float2(0.f, 0.f);
        c1[k] = make_float2(0.f, 0.f);
    }
    for (int l = am; l < 32; l++) {
        const float* dp = dqz + ((size_t)(l * l + mt + l) * 64 + s * 16) * 64 + j;
        const float4* z04 = (const float4*)(sZ + (size_t)l * 64 + s * 16);
        const float4* z14 = (const float4*)(sZ + (size_t)(32 + l) * 64 + s * 16);
        #pragma unroll
        for (int h = 0; h < 8; h++) {
            float d0 = dp[(size_t)(2 * h) * 64];
            float d1 = dp[(size_t)(2 * h + 1) * 64];
            float4 za = z04[h];
            float4 zb = z14[h];
            c0[2 * h].x     += d0 * za.x; c0[2 * h].y     += d0 * za.y;
            c0[2 * h + 1].x += d1 * za.z; c0[2 * h + 1].y += d1 * za.w;
            c1[2 * h].x     += d0 * zb.x; c1[2 * h].y     += d0 * zb.y;
            c1[2 * h + 1].x += d1 * zb.z; c1[2 * h + 1].y += d1 * zb.w;
        }
    }
    float2* t0 = T + (((size_t)(2 * p + 0) * 64 + mu) * 64 + j) * 64 + s * 16;
    float2* t1 = T + (((size_t)(2 * p + 1) * 64 + mu) * 64 + j) * 64 + s * 16;
    #pragma unroll
    for (int k = 0; k < 16; k++) t0[k] = c0[k];
    #pragma unroll
    for (int k = 0; k < 16; k++) t1[k] = c1[k];
}

// Synthesis stage B: radix-8 x2 IDFT; real + bias out; fused BN-stats atomics.
// Stages T rows mu=0..32; pass-1 (dim-nu) runs ONLY on those 33 rows with
// 8 threads/row (halved per-thread work); rows 33..63 are then derived by
// h[mu][g] = conj(h[64-mu][g]) (T-row conj-mirror symmetry commutes with the
// nu-IDFT). Pass-2 unchanged.
__global__ __launch_bounds__(TPB) void k_synB(const float2* __restrict__ T,
                                              const float2* __restrict__ twi_g,
                                              const float* __restrict__ bias,
                                              float* __restrict__ yout,
                                              float* __restrict__ stats,
                                              int Fo, int zo0) {
    __shared__ float2 sF[64 * 66];
    __shared__ float2 tw[64];
    int blk = blockIdx.x;
    int zo_l = blk >> 6, j = blk & 63;
    int zo_g = zo0 + zo_l;
    int o = zo_g % Fo;
    int tid = threadIdx.x;
    if (tid < 64) tw[tid] = twi_g[tid];
    const float4* src4 = (const float4*)(T + (size_t)zo_l * kCube + (size_t)j * 64);
    for (int i = tid; i < 1056; i += TPB) {      // mu = 0..32 direct
        int mu = i >> 5, half = i & 31;
        float4 v = src4[(size_t)mu * 2048 + half];
        sF[mu * 66 + 2 * half]     = make_float2(v.x, v.y);
        sF[mu * 66 + 2 * half + 1] = make_float2(v.z, v.w);
    }
    __syncthreads();
    float2 w8[8];
    #pragma unroll
    for (int k = 0; k < 8; k++) w8[k] = tw[k * 8];
    {   // pass 1 (dim-nu): rows 0..31 with 8 threads/row; row 32 on lanes 0..7
        int r8 = tid >> 3, q8 = tid & 7;
        float2* mrow = sF + r8 * 66;
        float2* mrow32 = sF + 32 * 66;
        {
            int s = q8;
            float2 f[8];
            #pragma unroll
            for (int p = 0; p < 8; p++) f[p] = mrow[8 * p + s];
            float2 ws = tw[s];
            float2 t = make_float2(1.f, 0.f);
            #pragma unroll
            for (int v = 0; v < 8; v++) {
                float re = 0, im = 0;
                #pragma unroll
                for (int p = 0; p < 8; p++) {
                    float2 w = w8[(v * p) & 7];
                    re += f[p].x * w.x - f[p].y * w.y;
                    im += f[p].x * w.y + f[p].y * w.x;
                }
                mrow[v * 8 + s] = make_float2(re * t.x - im * t.y, re * t.y + im * t.x);
                float tx = t.x * ws.x - t.y * ws.y;
                t.y = t.x * ws.y + t.y * ws.x; t.x = tx;
            }
        }
        if (tid < 8) {   // row 32 stage 1 (wave 0 lanes 0..7, lockstep)
            int s = tid;
            float2 f[8];
            #pragma unroll
            for (int p = 0; p < 8; p++) f[p] = mrow32[8 * p + s];
            float2 ws = tw[s];
            float2 t = make_float2(1.f, 0.f);
            #pragma unroll
            for (int v = 0; v < 8; v++) {
                float re = 0, im = 0;
                #pragma unroll
                for (int p = 0; p < 8; p++) {
                    float2 w = w8[(v * p) & 7];
                    re += f[p].x * w.x - f[p].y * w.y;
                    im += f[p].x * w.y + f[p].y * w.x;
                }
                mrow32[v * 8 + s] = make_float2(re * t.x - im * t.y, re * t.y + im * t.x);
                float tx = t.x * ws.x - t.y * ws.y;
                t.y = t.x * ws.y + t.y * ws.x; t.x = tx;
            }
        }
        {
            int v = q8;
            float2 a[8];
            #pragma unroll
            for (int s = 0; s < 8; s++) a[s] = mrow[v * 8 + s];
            #pragma unroll
            for (int u = 0; u < 8; u++) {
                float re = 0, im = 0;
                #pragma unroll
                for (int s = 0; s < 8; s++) {
                    float2 w = w8[(u * s) & 7];
                    re += a[s].x * w.x - a[s].y * w.y;
                    im += a[s].x * w.y + a[s].y * w.x;
                }
                mrow[8 * u + v] = make_float2(re, im);
            }
        }
        if (tid < 8) {   // row 32 stage 2
            int v = tid;
            float2 a[8];
            #pragma unroll
            for (int s = 0; s < 8; s++) a[s] = mrow32[v * 8 + s];
            #pragma unroll
            for (int u = 0; u < 8; u++) {
                float re = 0, im = 0;
                #pragma unroll
                for (int s = 0; s < 8; s++) {
                    float2 w = w8[(u * s) & 7];
                    re += a[s].x * w.x - a[s].y * w.y;
                    im += a[s].x * w.y + a[s].y * w.x;
                }
                mrow32[8 * u + v] = make_float2(re, im);
            }
        }
    }
    __syncthreads();
    for (int i = tid; i < 31 * 64; i += TPB) {   // rows 33..63: conj mirror in g
        int mu = 33 + (i >> 6), g = i & 63;
        float2 v = sF[(64 - mu) * 66 + g];
        sF[mu * 66 + g] = make_float2(v.x, -v.y);
    }
    __syncthreads();
    float s_acc = 0.f, q_acc = 0.f;
    int r2 = tid >> 2, q = tid & 3;
    {   // dim-mu, per column c; real + bias out
        int c = r2;
        float bo = bias[o];
        float* dst = yout + ((size_t)zo_g * 64 + j) * 4096;
        #pragma unroll
        for (int half = 0; half < 2; half++) {
            int s = q + 4 * half;
            float2 f[8];
            #pragma unroll
            for (int p = 0; p < 8; p++) f[p] = sF[(8 * p + s) * 66 + c];
            float2 ws = tw[s];
            float2 t = make_float2(1.f, 0.f);
            #pragma unroll
            for (int v = 0; v < 8; v++) {
                float re = 0, im = 0;
                #pragma unroll
                for (int p = 0; p < 8; p++) {
                    float2 w = w8[(v * p) & 7];
                    re += f[p].x * w.x - f[p].y * w.y;
                    im += f[p].x * w.y + f[p].y * w.x;
                }
                sF[(v * 8 + s) * 66 + c] = make_float2(re * t.x - im * t.y,
                                                       re * t.y + im * t.x);
                float tx = t.x * ws.x - t.y * ws.y;
                t.y = t.x * ws.y + t.y * ws.x; t.x = tx;
            }
        }
        float2 a[2][8];
        #pragma unroll
        for (int half = 0; half < 2; half++) {
            int v = q + 4 * half;
            #pragma unroll
            for (int s = 0; s < 8; s++) a[half][s] = sF[(v * 8 + s) * 66 + c];
        }
        #pragma unroll
        for (int half = 0; half < 2; half++) {
            int v = q + 4 * half;
            #pragma unroll
            for (int u = 0; u < 8; u++) {
                float re = 0;
                #pragma unroll
                for (int s = 0; s < 8; s++) {
                    float2 w = w8[(u * s) & 7];
                    re += a[half][s].x * w.x - a[half][s].y * w.y;
                }
                float val = re + bo;
                dst[(8 * u + v) * 64 + c] = val;
                s_acc += val;
                q_acc += val * val;
            }
        }
    }
    // fused BN stats: block reduce + 2 atomics (replaces k_bn_stats pass)
    __syncthreads();
    float* rs = (float*)sF;
    rs[tid] = s_acc;
    rs[TPB + tid] = q_acc;
    __syncthreads();
    for (int st = TPB / 2; st > 0; st >>= 1) {
        if (tid < st) { rs[tid] += rs[tid + st]; rs[TPB + tid] += rs[TPB + tid + st]; }
        __syncthreads();
    }
    if (tid == 0) {
        atomicAdd(&stats[o * 2], rs[0]);
        atomicAdd(&stats[o * 2 + 1], rs[TPB]);
    }
}

__global__ void k_final(const float* __restrict__ y, const float* __restrict__ stats,
                        const float* __restrict__ gamma, const float* __restrict__ beta,
                        float* __restrict__ out) {
    int t = blockIdx.x * TPB + threadIdx.x;
    if (t >= kB * kF2 * 4096) return;
    int zo = t >> 12, o = zo % kF2;
    const float inv = 1.0f / 524288.0f;
    float mean = stats[o * 2] * inv;
    float var = stats[o * 2 + 1] * inv - mean * mean;
    float rstd = rsqrtf(var + 1e-5f);
    float ga = gamma[o], be = beta[o];
    const float* p = y + (size_t)t * 64;
    float acc = 0;
    for (int g = 0; g < 64; g++) {
        float v = (p[g] - mean) * rstd * ga + be;
        acc += v > 0.f ? v : 0.f;
    }
    out[t] = acc * (1.0f / 64.0f);
}

// ---------------------------------------------------------------------------
extern "C" void kernel_launch(void* const* d_in, const int* in_sizes, int n_in,
                              void* d_out, int out_size, void* d_ws, size_t ws_size,
                              hipStream_t stream) {
    const float* x     = (const float*)d_in[0];
    const float* k1    = (const float*)d_in[1];
    const float* bias1 = (const float*)d_in[2];
    const float* g1    = (const float*)d_in[3];
    const float* be1   = (const float*)d_in[4];
    const float* k2    = (const float*)d_in[5];
    const float* bias2 = (const float*)d_in[6];
    const float* g2    = (const float*)d_in[7];
    const float* be2   = (const float*)d_in[8];
    const float* k3    = (const float*)d_in[9];
    const float* bias3 = (const float*)d_in[10];
    const float* g3    = (const float*)d_in[11];
    const float* be3   = (const float*)d_in[12];

    char* ws = (char*)d_ws;
    size_t off = 0;
    auto alloc = [&](size_t bytes) {
        size_t cur = off;
        off = (off + bytes + 255) & ~(size_t)255;
        return cur;
    };
    size_t o_const = alloc(g_tab.bytes);                       // 3.0 MB
    size_t o_dqz   = alloc((size_t)kNM * 64 * 64 * 4);         // 16.8 MB
    size_t o_dqtw  = alloc((size_t)64 * kNMN * 4);             // 11.2 MB
    size_t o_deTp  = alloc((size_t)4 * 11424 * 4);             // 0.18 MB (padded, full)
    size_t o_khat  = alloc((size_t)kF1 * kF1 * 64 * 8);        // 1.8 MB
    size_t o_xf1   = alloc((size_t)kB * kF0 * 64 * 64 * 8);    // 0.2 MB
    size_t o_fh1   = alloc((size_t)kNM * kB * kF0 * 8);        // 0.05 MB
    size_t o_stats = alloc(2 * 64 * 4);
    size_t o_fh    = alloc((size_t)kB * kF1 * kNMN * 8);       // 42 MB (fh, then zs)
    size_t o_scr   = alloc((size_t)kFCH * kCube * 8);          // 50.3 MB (dtmp/xf/G/T)
    size_t o_cube  = alloc((size_t)kB * kF1 * kCube * 4);      // 126 MB
    if (off > ws_size) return;

    const float* cb = (const float*)(ws + o_const);
    const float2* twf = (const float2*)(cb + g_tab.o_twf);
    const float2* twi = (const float2*)(cb + g_tab.o_twi);
    const float* w_t = cb + g_tab.o_w;
    const float* etab = cb + g_tab.o_etab;
    const float* dehalf = etab + (size_t)(8 + 4) * kNMN;  // G_4 = E0^32 = d(pi/2)
    const int* lmn_l = (const int*)(cb + g_tab.o_lmnl);
    const int* lm_l = (const int*)(cb + g_tab.o_lml);
    const int* lmn2 = (const int*)(cb + g_tab.o_lmn2);
    const int* lmq = (const int*)(cb + g_tab.o_lmq);
    const int* off4 = (const int*)(cb + g_tab.o_off4);

    float* dqz = (float*)(ws + o_dqz);
    float* dqtw = (float*)(ws + o_dqtw);
    float* deTp = (float*)(ws + o_deTp);
    float2* khat = (float2*)(ws + o_khat);
    float2* xf1 = (float2*)(ws + o_xf1);
    float2* fh1 = (float2*)(ws + o_fh1);
    float* stats = (float*)(ws + o_stats);
    float2* fh = (float2*)(ws + o_fh);
    float2* zsb = (float2*)(ws + o_fh);
    float* dtmp = (float*)(ws + o_scr);
    float2* Gb = (float2*)(ws + o_scr);
    float2* xfc = (float2*)(ws + o_scr);
    float2* Tb = (float2*)(ws + o_scr);
    float* cube = (float*)(ws + o_cube);

    hipMemcpyAsync(ws + o_const, g_tab.blob.data(), g_tab.bytes,
                   hipMemcpyHostToDevice, stream);
    hipMemsetAsync(dqz, 0, (size_t)kNM * 64 * 64 * 4, stream);
    hipMemsetAsync(deTp, 0, (size_t)4 * 11424 * 4, stream);
    k_gendqA<<<kLMAX * 64, TPB, 0, stream>>>(etab, dtmp);
    k_scat<<<kLMAX * 63, TPB, 0, stream>>>(dtmp, w_t, dqz, dqtw);
    k_transde_p<<<(kNMN + TPB - 1) / TPB, TPB, 0, stream>>>(dehalf, deTp, lmn_l, off4);

    const float S2S = 1.0f / sqrtf(64.0f * 3.0f * 1024.0f);
    const float SO3S = 1.0f / sqrtf(64.0f * 60.0f);
    auto blks = [](size_t n) { return (int)((n + TPB - 1) / TPB); };

    auto synth = [&](const float* bi, int Fo) {
        hipMemsetAsync(stats, 0, 2 * 64 * 4, stream);
        int planes = kB * Fo;
        for (int zo0 = 0; zo0 < planes; zo0 += kFCH) {
            int nzo = planes - zo0 < kFCH ? planes - zo0 : kFCH;
            k_synA<<<dim3(33, nzo / 2), TPB, 0, stream>>>(
                zsb + (size_t)zo0 * kNMN, dqz, Tb);
            k_synB<<<nzo * 64, TPB, 0, stream>>>(Tb, twi, bi, cube, stats, Fo, zo0);
        }
    };

    // ---- Layer 1: S2 conv -> cube ----
    k_khat<<<blks(kF0 * kF1 * 64), TPB, 0, stream>>>(k1, khat, twf, kF0 * kF1 * 64, S2S);
    k_fft1<<<blks(kB * kF0 * 64 * 64), TPB, 0, stream>>>(x, xf1, twf);
    k_fh1<<<blks(kNM * kB * kF0), TPB, 0, stream>>>(xf1, dqtw, lm_l, fh1);
    k_zs1<<<blks((size_t)(kF1 / 6) * kNMN2), TPB, 0, stream>>>(fh1, khat, dehalf,
                                                               lmn_l, lmn2, zsb);
    synth(bias1, kF1);

    // ---- Layers 2 & 3: SO3 conv; fft2 applies previous layer's BN+ReLU ----
    for (int layer = 2; layer <= 3; layer++) {
        int Fo = (layer == 2) ? kF1 : kF2;
        const float* kk = (layer == 2) ? k2 : k3;
        const float* bi = (layer == 2) ? bias2 : bias3;
        const float* gp = (layer == 2) ? g1 : g2;
        const float* bp = (layer == 2) ? be1 : be2;
        k_khat<<<blks(kF1 * Fo * 64), TPB, 0, stream>>>(kk, khat, twf, kF1 * Fo * 64, SO3S);
        for (int zf0 = 0; zf0 < kB * kF1; zf0 += kFCH) {
            int nzf = kB * kF1 - zf0 < kFCH ? kB * kF1 - zf0 : kFCH;
            k_fft2<<<nzf * 64, TPB, 0, stream>>>(cube + (size_t)zf0 * kCube, xfc,
                                                 twf, stats, gp, bp, zf0);
            k_fh3<<<2048, TPB, 0, stream>>>(xfc, dqtw, fh + (size_t)zf0 * kNMN, nzf);
        }
        {
            int total = kB * kF1 * kNQ2;
            k_G4<<<blks(total), TPB, 0, stream>>>(fh, deTp, lmq, off4, Gb, total);
        }
        if (layer == 2) {
            int nOg = kF1 / 3;
            int CHb = (kCH2 * nOg + 7) / 8;
            k_zs_v4<60, 60><<<8 * CHb, TPB, 0, stream>>>(Gb, khat, lmn_l, lmn2, zsb);
        } else {
            int nOg = kF2 / 3;
            int CHb = (kCH2 * nOg + 7) / 8;
            k_zs_v4<60, 36><<<8 * CHb, TPB, 0, stream>>>(Gb, khat, lmn_l, lmn2, zsb);
        }
        synth(bi, Fo);
        if (layer == 3)
            k_final<<<blks(kB * kF2 * 4096), TPB, 0, stream>>>(cube, stats, g3, be3, (float*)d_out);
    }
}

// Round 13
// 1869.821 us; speedup vs baseline: 1.0688x; 1.0402x over previous
//
#include <hip/hip_runtime.h>
#include <cmath>
#include <cstring>
#include <cstdint>
#include <vector>

#define TPB 256
static constexpr int kLMAX = 32;
static constexpr int kNMN  = 43680;   // sum_{l<32} (2l+1)^2
static constexpr int kNMN2 = 22352;   // sum_{l<32} (l+1)(2l+1)  (m>=0 rows only)
static constexpr int kNM   = 1024;    // sum_{l<32} (2l+1)
static constexpr int kNQ2  = 5848;    // sum_{l<32} (l+1)*ceil((2l+1)/4)
static constexpr int kB    = 2;
static constexpr int kF0   = 3, kF1 = 60, kF2 = 36;
static constexpr int kCube = 262144;  // 64^3
static constexpr int kFCH  = 24;      // plane chunk (divides 120 and 72)
static constexpr int kCH2  = (kNMN2 + 255) / 256;   // 88 lmn2-chunks of 256

__host__ __device__ inline int off3i(int l) { return l * (4 * l * l - 1) / 3; }

// ---------------------------------------------------------------------------
// Host-side constant tables (~3.0 MB seeds; d_b = F_{b&7} * G_{b>>3}).
// Hermitian dead-code note: synA (mu<=32) only reads zs rows with m>=0, so
// the zs/G/fh chain is computed ONLY for mi>=l (lmn2/lmq tables below), and
// fh3/fft2 only produce the mu in [0,31] half of the spectrum.
// ---------------------------------------------------------------------------
static void h_matmul(const std::vector<double>& A, const std::vector<double>& B,
                     std::vector<double>& C, int n) {
    C.assign((size_t)n * n, 0.0);
    for (int i = 0; i < n; i++)
        for (int k = 0; k < n; k++) {
            double a = A[(size_t)i * n + k];
            if (a == 0.0) continue;
            const double* bp = &B[(size_t)k * n];
            double* cp = &C[(size_t)i * n];
            for (int j = 0; j < n; j++) cp[j] += a * bp[j];
        }
}

struct HostTables {
    std::vector<float> blob;
    size_t o_twf, o_twi, o_w, o_lmnl, o_lml, o_lmn2, o_lmq, o_off4, o_etab;
    size_t bytes;
    HostTables() {
        size_t n = 0;
        o_twf = n;  n += 128;
        o_twi = n;  n += 128;
        o_w = n;    n += 64;
        o_lmnl = n; n += kNMN;
        o_lml = n;  n += kNM;
        o_lmn2 = n; n += kNMN2;
        o_lmq = n;  n += kNQ2;
        o_off4 = n; n += 32;
        o_etab = n; n += (size_t)16 * kNMN;    // [F_0..F_7, G_0..G_7] per l
        blob.assign(n, 0.0f);
        bytes = n * 4;

        for (int k = 0; k < 64; k++) {
            double th = -2.0 * M_PI * k / 64.0;
            blob[o_twf + 2 * k]     = (float)cos(th);
            blob[o_twf + 2 * k + 1] = (float)sin(th);
            blob[o_twi + 2 * k]     = (float)cos(th);
            blob[o_twi + 2 * k + 1] = (float)(-sin(th));
        }
        for (int j = 0; j < 64; j++) {
            double s = 0;
            for (int k = 0; k < 32; k++)
                s += sin((2.0 * j + 1) * (2.0 * k + 1) * M_PI / 128.0) / (2.0 * k + 1);
            blob[o_w + j] = (float)(2.0 / 32.0 * sin(M_PI * (2.0 * j + 1) / 128.0) * s);
        }
        // lmn2: compact index of (l, mi>=l, ni) -> original lmn offset.
        {
            int qi = 0;
            for (int l = 0; l < kLMAX; l++) {
                int R = 2 * l + 1, o3 = off3i(l);
                for (int mi = l; mi < R; mi++)
                    for (int ni = 0; ni < R; ni++) {
                        int32_t v = o3 + mi * R + ni;
                        memcpy(&blob[o_lmn2 + qi], &v, 4);
                        qi++;
                    }
            }
        }
        // q -> (l, mi>=l, n0) table for n4-blocked k_G4, and padded-deT offsets.
        {
            int qi = 0, acc4 = 0;
            for (int l = 0; l < kLMAX; l++) {
                int R = 2 * l + 1, Rp = (R + 3) & ~3, C = Rp >> 2;
                int32_t o4 = acc4;
                memcpy(&blob[o_off4 + l], &o4, 4);
                for (int m = l; m < R; m++)
                    for (int c = 0; c < C; c++) {
                        int32_t pk = l | (m << 5) | ((4 * c) << 11);
                        memcpy(&blob[o_lmq + qi], &pk, 4);
                        qi++;
                    }
                acc4 += R * Rp;
            }
        }
        std::vector<double> A, Eh, E0, E08, F, G, term, tmp;
        for (int l = 0; l < kLMAX; l++) {
            int R = 2 * l + 1, o3 = off3i(l);
            A.assign((size_t)R * R, 0.0);
            for (int i = 0; i + 1 < R; i++) {
                double m = (double)i - l;
                double c = sqrt((double)l * (l + 1) - m * (m + 1));
                A[(size_t)(i + 1) * R + i] = -(M_PI / 128.0) * c * 0.5;
                A[(size_t)i * R + (i + 1)] =  (M_PI / 128.0) * c * 0.5;
            }
            Eh.assign((size_t)R * R, 0.0);
            for (int i = 0; i < R; i++) Eh[(size_t)i * R + i] = 1.0;
            term = Eh;
            for (int k = 1; k <= 30; k++) {
                h_matmul(term, A, tmp, R);
                for (auto& v : tmp) v /= k;
                term = tmp;
                for (size_t i = 0; i < (size_t)R * R; i++) Eh[i] += term[i];
            }
            h_matmul(Eh, Eh, E0, R);
            h_matmul(E0, E0, tmp, R);
            h_matmul(tmp, tmp, E08, R);
            h_matmul(E08, E08, tmp, R); E08 = tmp;  // E0^8
            F = Eh;
            for (int lo = 0; lo < 8; lo++) {
                for (int r = 0; r < R * R; r++)
                    blob[o_etab + (size_t)lo * kNMN + o3 + r] = (float)F[r];
                if (lo < 7) { h_matmul(F, E0, tmp, R); F = tmp; }
            }
            G.assign((size_t)R * R, 0.0);
            for (int i = 0; i < R; i++) G[(size_t)i * R + i] = 1.0;
            for (int hi = 0; hi < 8; hi++) {
                for (int r = 0; r < R * R; r++)
                    blob[o_etab + (size_t)(8 + hi) * kNMN + o3 + r] = (float)G[r];
                if (hi < 7) { h_matmul(G, E08, tmp, R); G = tmp; }
            }
            int32_t li = l;
            for (int r = 0; r < R * R; r++) memcpy(&blob[o_lmnl + o3 + r], &li, 4);
            for (int m = 0; m < R; m++)    memcpy(&blob[o_lml + (size_t)l * l + m], &li, 4);
        }
    }
};
static HostTables g_tab;

// ---------------------------------------------------------------------------
__global__ __launch_bounds__(TPB) void k_gendqA(const float* __restrict__ etab,
                                                float* __restrict__ dtmp) {
    __shared__ float Fm[3969];
    __shared__ float Gm[63 * 64];
    int l = blockIdx.x >> 6, b = blockIdx.x & 63;
    int lo = b & 7, hi = b >> 3;
    int R = 2 * l + 1, RR = R * R, o3 = off3i(l);
    int tid = threadIdx.x;
    const float* Fsrc = etab + (size_t)lo * kNMN + o3;
    const float* Gsrc = etab + (size_t)(8 + hi) * kNMN + o3;
    for (int i = tid; i < RR; i += TPB) Fm[i] = Fsrc[i];
    for (int i = tid; i < R * 64; i += TPB) {
        int k = i >> 6, c = i & 63;
        Gm[i] = (c < R) ? Gsrc[k * R + c] : 0.f;
    }
    __syncthreads();
    int Gc = (R + 15) >> 4;
    if (tid < R * Gc) {
        int row = tid / Gc, g = tid - row * Gc;
        float4 A0 = make_float4(0,0,0,0), A1 = A0, A2 = A0, A3 = A0;
        const float* fr = Fm + row * R;
        for (int k = 0; k < R; k++) {
            float a = fr[k];
            const float4* gp = (const float4*)(Gm + (k << 6) + (g << 4));
            float4 q0 = gp[0], q1 = gp[1], q2 = gp[2], q3 = gp[3];
            A0.x += a * q0.x; A0.y += a * q0.y; A0.z += a * q0.z; A0.w += a * q0.w;
            A1.x += a * q1.x; A1.y += a * q1.y; A1.z += a * q1.z; A1.w += a * q1.w;
            A2.x += a * q2.x; A2.y += a * q2.y; A2.z += a * q2.z; A2.w += a * q2.w;
            A3.x += a * q3.x; A3.y += a * q3.y; A3.z += a * q3.z; A3.w += a * q3.w;
        }
        float v[16] = {A0.x,A0.y,A0.z,A0.w, A1.x,A1.y,A1.z,A1.w,
                       A2.x,A2.y,A2.z,A2.w, A3.x,A3.y,A3.z,A3.w};
        float* dst = dtmp + (size_t)o3 * 64 + (size_t)b * RR + row * R;
        int c0 = g << 4;
        #pragma unroll
        for (int e = 0; e < 16; e++)
            if (c0 + e < R) dst[c0 + e] = v[e];
    }
}

__global__ __launch_bounds__(TPB) void k_scat(const float* __restrict__ dtmp,
                                              const float* __restrict__ w,
                                              float* __restrict__ dqz,
                                              float* __restrict__ dqtw) {
    __shared__ float S[64 * 65];
    int l = blockIdx.x / 63, tile = blockIdx.x % 63;
    int R = 2 * l + 1, RR = R * R, o3 = off3i(l);
    int i0 = tile * 64;
    if (i0 >= RR) return;
    int tid = threadIdx.x;
    const float* src = dtmp + (size_t)o3 * 64;
    #pragma unroll
    for (int s = 0; s < 16; s++) {
        int idx = tid + s * TPB;
        int b = idx >> 6, ii = idx & 63;
        int i = i0 + ii;
        S[ii * 65 + b] = (i < RR) ? src[(size_t)b * RR + i] : 0.f;
    }
    __syncthreads();
    float Rf = (float)R;
    #pragma unroll
    for (int s = 0; s < 16; s++) {
        int idx = tid + s * TPB;
        int ii = idx >> 6, b = idx & 63;
        int i = i0 + ii;
        if (i < RR) {
            float v = S[ii * 65 + b];
            dqtw[((size_t)o3 + i) * 64 + b] = w[b] * v;
            int mi = i / R, ni = i - mi * R;
            int nu = (ni - l) & 63;
            dqz[((size_t)(l * l + mi) * 64 + nu) * 64 + b] = Rf * v;
        }
    }
}

// Builds padded-row deTp: deTp[off4(l) + k*Rp + n] = dehalf[o3 + n*R + k],
// Rp = ceil(R/4)*4. Pad entries stay zero (memset upstream).
__global__ void k_transde_p(const float* __restrict__ dehalf, float* __restrict__ deTp,
                            const int* __restrict__ lmn_l, const int* __restrict__ off4) {
    int t = blockIdx.x * TPB + threadIdx.x;
    if (t >= kNMN) return;
    int l = lmn_l[t], o3 = off3i(l), r = t - o3, R = 2 * l + 1;
    int Rp = (R + 3) & ~3;
    int n = r / R, k = r - n * R;
    deTp[off4[l] + k * Rp + n] = dehalf[t];
}

__global__ void k_khat(const float* __restrict__ kern, float2* __restrict__ khat,
                       const float2* __restrict__ twf, int total, float scale) {
    int t = blockIdx.x * TPB + threadIdx.x;
    if (t >= total) return;
    int nu = t & 63, fo = t >> 6;
    const float* row = kern + (size_t)fo * 64;
    float re = 0, im = 0;
    for (int p = 0; p < 64; p++) {
        float2 w = twf[(p * nu) & 63];
        float v = row[p];
        re += v * w.x; im += v * w.y;
    }
    khat[t] = make_float2(re * scale, im * scale);
}

__global__ void k_fft1(const float* __restrict__ x, float2* __restrict__ xf1,
                       const float2* __restrict__ twf) {
    int t = blockIdx.x * TPB + threadIdx.x;
    if (t >= kB * kF0 * 64 * 64) return;
    int mu = t & 63, row = t >> 6;
    const float* p = x + (size_t)row * 64;
    float re = 0, im = 0;
    for (int a = 0; a < 64; a++) {
        float2 w = twf[(a * mu) & 63];
        float v = p[a];
        re += v * w.x; im += v * w.y;
    }
    xf1[t] = make_float2(re, im);
}

__global__ void k_fh1(const float2* __restrict__ xf1, const float* __restrict__ dqtw,
                      const int* __restrict__ lm_l, float2* __restrict__ fh1) {
    int t = blockIdx.x * TPB + threadIdx.x;
    if (t >= kNM * kB * kF0) return;
    int lm = t / 6, rem = t % 6, z = rem / 3, f = rem % 3;
    int l = lm_l[lm], m = lm - l * l, R = 2 * l + 1, o3 = off3i(l);
    int mu = (m - l) & 63;
    const float4* wq = (const float4*)(dqtw + (size_t)o3 * 64 + (size_t)(m * R + l) * 64);
    const float2* xr = xf1 + (size_t)((z * 3 + f) * 64) * 64 + mu;
    float re0 = 0, im0 = 0, re1 = 0, im1 = 0;
    #pragma unroll
    for (int b4 = 0; b4 < 16; b4++) {
        float4 w4 = wq[b4];
        float2 v0 = xr[(4 * b4 + 0) * 64];
        float2 v1 = xr[(4 * b4 + 1) * 64];
        float2 v2 = xr[(4 * b4 + 2) * 64];
        float2 v3 = xr[(4 * b4 + 3) * 64];
        re0 += w4.x * v0.x + w4.y * v1.x; im0 += w4.x * v0.y + w4.y * v1.y;
        re1 += w4.z * v2.x + w4.w * v3.x; im1 += w4.z * v2.y + w4.w * v3.y;
    }
    const float C2 = 1.0f / 128.0f;
    fh1[t] = make_float2((re0 + re1) * C2, (im0 + im1) * C2);
}

// Layer-1 zs restricted to lmn2 (mi>=l): synA never reads m<0 rows.
__global__ void k_zs1(const float2* __restrict__ fh1, const float2* __restrict__ khat,
                      const float* __restrict__ dehalf, const int* __restrict__ lmn_l,
                      const int* __restrict__ lmn2, float2* __restrict__ zs) {
    int nOg = kF1 / 6;                       // 10
    int t = blockIdx.x * TPB + threadIdx.x;  // og*NMN2 + i2
    if (t >= nOg * kNMN2) return;
    int i2 = t % kNMN2, og = t / kNMN2;
    int lmn = lmn2[i2];
    int l = lmn_l[lmn], o3 = off3i(l), r = lmn - o3, R = 2 * l + 1;
    int m = r / R, n = r - m * R;
    int nu = (n - l) & 63;
    float de1 = dehalf[o3 + n * R + l];
    int o0 = og * 6;
    const float2* fp = fh1 + (size_t)(l * l + m) * 6;
    const float2* kp = khat + (size_t)o0 * 64 + nu;
    float2 c0[6], c1[6];
    #pragma unroll
    for (int i = 0; i < 6; i++) {
        c0[i] = make_float2(0.f, 0.f);
        c1[i] = make_float2(0.f, 0.f);
    }
    #pragma unroll
    for (int f = 0; f < kF0; f++) {
        float2 a0 = fp[f];       // z = 0
        float2 a1 = fp[3 + f];   // z = 1
        const float2* kf = kp + (size_t)f * kF1 * 64;
        #pragma unroll
        for (int i = 0; i < 6; i++) {
            float2 b = kf[(size_t)i * 64];   // conj applied below
            c0[i].x += a0.x * b.x + a0.y * b.y;
            c0[i].y += a0.y * b.x - a0.x * b.y;
            c1[i].x += a1.x * b.x + a1.y * b.y;
            c1[i].y += a1.y * b.x - a1.x * b.y;
        }
    }
    float2* zp0 = zs + (size_t)o0 * kNMN + lmn;
    float2* zp1 = zs + ((size_t)kF1 + o0) * kNMN + lmn;
    #pragma unroll
    for (int i = 0; i < 6; i++) {
        zp0[(size_t)i * kNMN] = make_float2(c0[i].x * de1, c0[i].y * de1);
        zp1[(size_t)i * kNMN] = make_float2(c1[i].x * de1, c1[i].y * de1);
    }
}

// 2D forward DFT (radix-8 x2) with fused BN+ReLU; float4 staging.
// HERMITIAN DCE (output): k_fh3 reads only mu in [0,31] -> pass-2 computes
// only u<4. HERMITIAN (input): rows are REAL, so pass-1 output satisfies
// F[64-nu] = conj(F[nu]); pass-1 stage-2 computes nu<=32 and mirrors 33..63
// in LDS (intra-wave lockstep, same reliance as the cross-lane stage reads).
__global__ __launch_bounds__(TPB) void k_fft2(const float* __restrict__ y,
                                              float2* __restrict__ xf,
                                              const float2* __restrict__ twf_g,
                                              const float* __restrict__ stats,
                                              const float* __restrict__ gamma,
                                              const float* __restrict__ beta,
                                              int zf0) {
    __shared__ float sIn[64 * 65];
    __shared__ float2 sMid[64 * 66];
    __shared__ float2 tw[64];
    int blk = blockIdx.x, tid = threadIdx.x;
    if (tid < 64) tw[tid] = twf_g[tid];
    int o = (zf0 + (blk >> 6)) % kF1;
    const float inv = 1.0f / 524288.0f;
    float mean = stats[o * 2] * inv;
    float var = stats[o * 2 + 1] * inv - mean * mean;
    float rstd = rsqrtf(var + 1e-5f);
    float ga = gamma[o], be = beta[o];
    const float4* src4 = (const float4*)(y + (size_t)blk * 4096);
    for (int i = tid; i < 1024; i += TPB) {
        float4 v4 = src4[i];
        int row = i >> 4, col = (i & 15) << 2;
        float* d = sIn + row * 65 + col;
        float a0 = (v4.x - mean) * rstd * ga + be;
        float a1 = (v4.y - mean) * rstd * ga + be;
        float a2 = (v4.z - mean) * rstd * ga + be;
        float a3 = (v4.w - mean) * rstd * ga + be;
        d[0] = a0 > 0.f ? a0 : 0.f;
        d[1] = a1 > 0.f ? a1 : 0.f;
        d[2] = a2 > 0.f ? a2 : 0.f;
        d[3] = a3 > 0.f ? a3 : 0.f;
    }
    __syncthreads();
    float2 w8[8];
    #pragma unroll
    for (int k = 0; k < 8; k++) w8[k] = tw[k * 8];
    int r2 = tid >> 2, q = tid & 3;
    {   // dim-1: g -> nu, REAL input
        const float* rowp = sIn + r2 * 65;
        float2* mrow = sMid + r2 * 66;
        #pragma unroll
        for (int half = 0; half < 2; half++) {
            int s = q + 4 * half;
            float f[8];
            #pragma unroll
            for (int p = 0; p < 8; p++) f[p] = rowp[8 * p + s];
            float2 ws = tw[s];
            float2 t = make_float2(1.f, 0.f);
            #pragma unroll
            for (int v = 0; v < 8; v++) {
                float re = 0, im = 0;
                #pragma unroll
                for (int p = 0; p < 8; p++) {
                    float2 w = w8[(v * p) & 7];
                    re += f[p] * w.x; im += f[p] * w.y;
                }
                mrow[v * 8 + s] = make_float2(re * t.x - im * t.y, re * t.y + im * t.x);
                float tx = t.x * ws.x - t.y * ws.y;
                t.y = t.x * ws.y + t.y * ws.x; t.x = tx;
            }
        }
        float2 a[2][8];
        #pragma unroll
        for (int half = 0; half < 2; half++) {
            int v = q + 4 * half;
            #pragma unroll
            for (int s = 0; s < 8; s++) a[half][s] = mrow[v * 8 + s];
        }
        #pragma unroll
        for (int half = 0; half < 2; half++) {
            int v = q + 4 * half;
            #pragma unroll
            for (int u = 0; u < 4; u++) {   // nu = 8u+v in [0,31]
                float re = 0, im = 0;
                #pragma unroll
                for (int s = 0; s < 8; s++) {
                    float2 w = w8[(u * s) & 7];
                    re += a[half][s].x * w.x - a[half][s].y * w.y;
                    im += a[half][s].x * w.y + a[half][s].y * w.x;
                }
                mrow[8 * u + v] = make_float2(re, im);
            }
        }
        if (q == 0) {   // nu = 32 (u=4, v=0): only the half=0, v=0 slot
            float re = 0, im = 0;
            #pragma unroll
            for (int s = 0; s < 8; s++) {
                float2 w = w8[(4 * s) & 7];
                re += a[0][s].x * w.x - a[0][s].y * w.y;
                im += a[0][s].x * w.y + a[0][s].y * w.x;
            }
            mrow[32] = make_float2(re, im);
        }
        // mirror nu = 33..63: F[nu] = conj(F[64-nu]) (real input rows).
        for (int nu = 33 + q; nu < 64; nu += 4) {
            float2 vv = mrow[64 - nu];
            mrow[nu] = make_float2(vv.x, -vv.y);
        }
    }
    __syncthreads();
    {   // dim-2: a -> mu per column c; only mu < 32 needed downstream
        int c = r2;
        float2* dst = xf + (size_t)blk * 4096;
        #pragma unroll
        for (int half = 0; half < 2; half++) {
            int s = q + 4 * half;
            float2 f[8];
            #pragma unroll
            for (int p = 0; p < 8; p++) f[p] = sMid[(8 * p + s) * 66 + c];
            float2 ws = tw[s];
            float2 t = make_float2(1.f, 0.f);
            #pragma unroll
            for (int v = 0; v < 8; v++) {
                float re = 0, im = 0;
                #pragma unroll
                for (int p = 0; p < 8; p++) {
                    float2 w = w8[(v * p) & 7];
                    re += f[p].x * w.x - f[p].y * w.y;
                    im += f[p].x * w.y + f[p].y * w.x;
                }
                sMid[(v * 8 + s) * 66 + c] = make_float2(re * t.x - im * t.y,
                                                         re * t.y + im * t.x);
                float tx = t.x * ws.x - t.y * ws.y;
                t.y = t.x * ws.y + t.y * ws.x; t.x = tx;
            }
        }
        float2 a[2][8];
        #pragma unroll
        for (int half = 0; half < 2; half++) {
            int v = q + 4 * half;
            #pragma unroll
            for (int s = 0; s < 8; s++) a[half][s] = sMid[(v * 8 + s) * 66 + c];
        }
        #pragma unroll
        for (int half = 0; half < 2; half++) {
            int v = q + 4 * half;
            #pragma unroll
            for (int u = 0; u < 4; u++) {   // mu = 8u+v in [0,31] only
                float re = 0, im = 0;
                #pragma unroll
                for (int s = 0; s < 8; s++) {
                    float2 w = w8[(u * s) & 7];
                    re += a[half][s].x * w.x - a[half][s].y * w.y;
                    im += a[half][s].x * w.y + a[half][s].y * w.x;
                }
                dst[(8 * u + v) * 64 + c] = make_float2(re, im);
            }
        }
    }
}

// fh3: one block per (mu,nu) column, mu in [0..31] ONLY (m>=0 rows; the m<0
// half of fh is dead code downstream). X and dqtw staged once in LDS.
// XCD swizzle in 256-block chunks: per-XCD xf slice = 4 mu rows ~ 3 MB < L2.
__global__ __launch_bounds__(TPB) void k_fh3(const float2* __restrict__ xf,
                                             const float* __restrict__ dqtw,
                                             float2* __restrict__ fh_out, int nzf) {
    __shared__ float2 sX[24 * 66];   // [zf][b], row stride 66 float2
    __shared__ float  sD[32 * 68];   // [li][b], row stride 68 floats
    int v = blockIdx.x;              // 2048 blocks
    int wg = (v & 7) * 256 + (v >> 3);
    int nu = wg & 63, mu = wg >> 6;  // mu in [0,31] -> mt = mu >= 0
    int mt = mu;
    int nt = (nu <= 31) ? nu : nu - 64;
    int am = mu, an = nt < 0 ? -nt : nt;
    int lmin = am > an ? am : an;
    if (lmin >= kLMAX) return;
    int nl = kLMAX - lmin;
    int tid = threadIdx.x;
    for (int i = tid; i < nzf * 64; i += TPB) {
        int zf = i >> 6, b = i & 63;
        sX[zf * 66 + b] = xf[(size_t)zf * kCube + (size_t)b * 4096 + mu * 64 + nu];
    }
    for (int i = tid; i < nl * 64; i += TPB) {
        int li = i >> 6, b = i & 63;
        int l = lmin + li, R = 2 * l + 1;
        int r = (mt + l) * R + (nt + l);
        sD[li * 68 + b] = dqtw[(size_t)(off3i(l) + r) * 64 + b];
    }
    __syncthreads();
    const float C3 = 1.0f / 8192.0f;
    int items = nzf * nl;
    for (int item = tid; item < items; item += TPB) {
        int zf = item / nl, li = item - zf * nl;
        const float4* D4 = (const float4*)(sD + li * 68);
        const float4* X4 = (const float4*)(sX + zf * 66);
        float re0 = 0, im0 = 0, re1 = 0, im1 = 0;
        #pragma unroll
        for (int b4 = 0; b4 < 16; b4++) {
            float4 d   = D4[b4];
            float4 x01 = X4[2 * b4];
            float4 x23 = X4[2 * b4 + 1];
            re0 += d.x * x01.x; im0 += d.x * x01.y;
            re0 += d.y * x01.z; im0 += d.y * x01.w;
            re1 += d.z * x23.x; im1 += d.z * x23.y;
            re1 += d.w * x23.z; im1 += d.w * x23.w;
        }
        int l = lmin + li, R = 2 * l + 1;
        int r = (mt + l) * R + (nt + l);
        fh_out[(size_t)zf * kNMN + off3i(l) + r] =
            make_float2((re0 + re1) * C3, (im0 + im1) * C3);
    }
}

// G (n4-blocked, mi>=l rows only): thread computes 4 consecutive n outputs.
// Per k: 1 float2 fh broadcast + 1 aligned float4 deTp row-load -> 16 lane-FMA.
__global__ void k_G4(const float2* __restrict__ fh, const float* __restrict__ deTp,
                     const int* __restrict__ lmq, const int* __restrict__ off4,
                     float2* __restrict__ G, int total) {
    int t = blockIdx.x * TPB + threadIdx.x;
    if (t >= total) return;
    int q = t % kNQ2, zf = t / kNQ2;
    int pk = lmq[q];
    int l = pk & 31, m = (pk >> 5) & 63, n0 = pk >> 11;
    int R = 2 * l + 1, o3 = off3i(l);
    int C4 = ((R + 3) & ~3) >> 2;            // Rp/4
    const float2* fr = fh + (size_t)zf * kNMN + o3 + m * R;
    const float4* dp = (const float4*)(deTp + off4[l] + n0);
    float4 re = make_float4(0.f, 0.f, 0.f, 0.f);
    float4 im = make_float4(0.f, 0.f, 0.f, 0.f);
    int k = 0;
    for (; k + 1 < R; k += 2) {
        float2 f0 = fr[k], f1 = fr[k + 1];
        float4 d0 = dp[(size_t)k * C4];
        float4 d1 = dp[(size_t)(k + 1) * C4];
        re.x += f0.x * d0.x + f1.x * d1.x; im.x += f0.y * d0.x + f1.y * d1.x;
        re.y += f0.x * d0.y + f1.x * d1.y; im.y += f0.y * d0.y + f1.y * d1.y;
        re.z += f0.x * d0.z + f1.x * d1.z; im.z += f0.y * d0.z + f1.y * d1.z;
        re.w += f0.x * d0.w + f1.x * d1.w; im.w += f0.y * d0.w + f1.y * d1.w;
    }
    {
        float2 f0 = fr[k];
        float4 d0 = dp[(size_t)k * C4];
        re.x += f0.x * d0.x; im.x += f0.y * d0.x;
        re.y += f0.x * d0.y; im.y += f0.y * d0.y;
        re.z += f0.x * d0.z; im.z += f0.y * d0.z;
        re.w += f0.x * d0.w; im.w += f0.y * d0.w;
    }
    float2* gp = G + (size_t)zf * kNMN + o3 + m * R + n0;
    int rem = R - n0;
    gp[0] = make_float2(re.x, im.x);
    if (rem > 1) gp[1] = make_float2(re.y, im.y);
    if (rem > 2) gp[2] = make_float2(re.z, im.z);
    if (rem > 3) gp[3] = make_float2(re.w, im.w);
}

// zs v4: og-tile 3; barrier-free body + og-fastest XCD-grouped decode +
// compile-time FIN/FO + unroll-4 f-loop; lmn2 (mi>=l) restricted.
template<int FIN, int FO>
__global__ __launch_bounds__(TPB) void k_zs_v4(const float2* __restrict__ G,
                                               const float2* __restrict__ khat,
                                               const int* __restrict__ lmn_l,
                                               const int* __restrict__ lmn2,
                                               float2* __restrict__ zs) {
    constexpr int NOG = FO / 3;
    int CHb = gridDim.x >> 3;
    int bid = blockIdx.x;
    int work = (bid & 7) * CHb + (bid >> 3);   // bijective; og-fastest
    if (work >= kCH2 * NOG) return;
    int x = work / NOG, og = work - x * NOG;
    int i2 = x * 256 + threadIdx.x;
    if (i2 >= kNMN2) return;
    int lmn = lmn2[i2];
    int l = lmn_l[lmn], r = lmn - off3i(l), R = 2 * l + 1;
    int n = r % R;
    int nu = (n - l) & 63;
    int o0 = og * 3;
    const float2* gp0 = G + lmn;
    const float2* gp1 = G + (size_t)FIN * kNMN + lmn;
    const float2* kp = khat + (size_t)o0 * 64 + nu;
    float2 c0[3], c1[3];
    #pragma unroll
    for (int i = 0; i < 3; i++) {
        c0[i] = make_float2(0.f, 0.f);
        c1[i] = make_float2(0.f, 0.f);
    }
    #pragma unroll 4
    for (int f = 0; f < FIN; f++) {
        float2 a0 = gp0[(size_t)f * kNMN];
        float2 a1 = gp1[(size_t)f * kNMN];
        const float2* kf = kp + (size_t)f * FO * 64;
        #pragma unroll
        for (int i = 0; i < 3; i++) {
            float2 b = kf[(size_t)i * 64];   // conj applied in the FMA signs
            c0[i].x += a0.x * b.x + a0.y * b.y;
            c0[i].y += a0.y * b.x - a0.x * b.y;
            c1[i].x += a1.x * b.x + a1.y * b.y;
            c1[i].y += a1.y * b.x - a1.x * b.y;
        }
    }
    float2* zp0 = zs + (size_t)o0 * kNMN + lmn;
    float2* zp1 = zs + ((size_t)FO + o0) * kNMN + lmn;
    #pragma unroll
    for (int i = 0; i < 3; i++) {
        zp0[(size_t)i * kNMN] = c0[i];
        zp1[(size_t)i * kNMN] = c1[i];
    }
}

// Synthesis stage A (1-plane blocks): grid = (33 mu) x (nzo planes); each
// block accumulates ONE zo plane. vs the 2-plane version: 2x blocks (~3/CU),
// half the LDS (16KB -> ~9 blocks/CU resident), half the per-block latency
// chain (the mu=0 critical path), same per-output FMA order -> bitwise-same T.
// HERMITIAN: mu = 0..32 only; rows 33..63 derived in k_synB by conj-mirror.
__global__ __launch_bounds__(TPB) void k_synA(const float2* __restrict__ zs,
                                              const float* __restrict__ dqz,
                                              float2* __restrict__ T) {
    __shared__ float2 sZ[32 * 64];
    int mu = blockIdx.x, zo = blockIdx.y;
    int tid = threadIdx.x;
    int mt = (mu <= 31) ? mu : mu - 64;
    int am = mt < 0 ? -mt : mt;
    #pragma unroll
    for (int k = 0; k < 8; k++) {
        int i = tid + k * TPB;
        int nu = i & 63, l = i >> 6;
        int nt = (nu <= 31) ? nu : nu - 64;
        int an = nt < 0 ? -nt : nt;
        float2 v = make_float2(0.f, 0.f);
        if (l >= am && an <= l)
            v = zs[(size_t)zo * kNMN + off3i(l) +
                   (mt + l) * (2 * l + 1) + nt + l];
        sZ[i] = v;
    }
    __syncthreads();
    int j = tid & 63, s = tid >> 6;
    float2 c0[16];
    #pragma unroll
    for (int k = 0; k < 16; k++) c0[k] = make_float2(0.f, 0.f);
    for (int l = am; l < 32; l++) {
        const float* dp = dqz + ((size_t)(l * l + mt + l) * 64 + s * 16) * 64 + j;
        const float4* z04 = (const float4*)(sZ + (size_t)l * 64 + s * 16);
        #pragma unroll
        for (int h = 0; h < 8; h++) {
            float d0 = dp[(size_t)(2 * h) * 64];
            float d1 = dp[(size_t)(2 * h + 1) * 64];
            float4 za = z04[h];
            c0[2 * h].x     += d0 * za.x; c0[2 * h].y     += d0 * za.y;
            c0[2 * h + 1].x += d1 * za.z; c0[2 * h + 1].y += d1 * za.w;
        }
    }
    float2* t0 = T + (((size_t)zo * 64 + mu) * 64 + j) * 64 + s * 16;
    #pragma unroll
    for (int k = 0; k < 16; k++) t0[k] = c0[k];
}

// Synthesis stage B: radix-8 x2 IDFT; real + bias out; fused BN-stats atomics.
// Stages T rows mu=0..32; pass-1 (dim-nu) runs ONLY on those 33 rows with
// 8 threads/row (halved per-thread work); rows 33..63 are then derived by
// h[mu][g] = conj(h[64-mu][g]) (T-row conj-mirror symmetry commutes with the
// nu-IDFT). Pass-2 unchanged.
__global__ __launch_bounds__(TPB) void k_synB(const float2* __restrict__ T,
                                              const float2* __restrict__ twi_g,
                                              const float* __restrict__ bias,
                                              float* __restrict__ yout,
                                              float* __restrict__ stats,
                                              int Fo, int zo0) {
    __shared__ float2 sF[64 * 66];
    __shared__ float2 tw[64];
    int blk = blockIdx.x;
    int zo_l = blk >> 6, j = blk & 63;
    int zo_g = zo0 + zo_l;
    int o = zo_g % Fo;
    int tid = threadIdx.x;
    if (tid < 64) tw[tid] = twi_g[tid];
    const float4* src4 = (const float4*)(T + (size_t)zo_l * kCube + (size_t)j * 64);
    for (int i = tid; i < 1056; i += TPB) {      // mu = 0..32 direct
        int mu = i >> 5, half = i & 31;
        float4 v = src4[(size_t)mu * 2048 + half];
        sF[mu * 66 + 2 * half]     = make_float2(v.x, v.y);
        sF[mu * 66 + 2 * half + 1] = make_float2(v.z, v.w);
    }
    __syncthreads();
    float2 w8[8];
    #pragma unroll
    for (int k = 0; k < 8; k++) w8[k] = tw[k * 8];
    {   // pass 1 (dim-nu): rows 0..31 with 8 threads/row; row 32 on lanes 0..7
        int r8 = tid >> 3, q8 = tid & 7;
        float2* mrow = sF + r8 * 66;
        float2* mrow32 = sF + 32 * 66;
        {
            int s = q8;
            float2 f[8];
            #pragma unroll
            for (int p = 0; p < 8; p++) f[p] = mrow[8 * p + s];
            float2 ws = tw[s];
            float2 t = make_float2(1.f, 0.f);
            #pragma unroll
            for (int v = 0; v < 8; v++) {
                float re = 0, im = 0;
                #pragma unroll
                for (int p = 0; p < 8; p++) {
                    float2 w = w8[(v * p) & 7];
                    re += f[p].x * w.x - f[p].y * w.y;
                    im += f[p].x * w.y + f[p].y * w.x;
                }
                mrow[v * 8 + s] = make_float2(re * t.x - im * t.y, re * t.y + im * t.x);
                float tx = t.x * ws.x - t.y * ws.y;
                t.y = t.x * ws.y + t.y * ws.x; t.x = tx;
            }
        }
        if (tid < 8) {   // row 32 stage 1 (wave 0 lanes 0..7, lockstep)
            int s = tid;
            float2 f[8];
            #pragma unroll
            for (int p = 0; p < 8; p++) f[p] = mrow32[8 * p + s];
            float2 ws = tw[s];
            float2 t = make_float2(1.f, 0.f);
            #pragma unroll
            for (int v = 0; v < 8; v++) {
                float re = 0, im = 0;
                #pragma unroll
                for (int p = 0; p < 8; p++) {
                    float2 w = w8[(v * p) & 7];
                    re += f[p].x * w.x - f[p].y * w.y;
                    im += f[p].x * w.y + f[p].y * w.x;
                }
                mrow32[v * 8 + s] = make_float2(re * t.x - im * t.y, re * t.y + im * t.x);
                float tx = t.x * ws.x - t.y * ws.y;
                t.y = t.x * ws.y + t.y * ws.x; t.x = tx;
            }
        }
        {
            int v = q8;
            float2 a[8];
            #pragma unroll
            for (int s = 0; s < 8; s++) a[s] = mrow[v * 8 + s];
            #pragma unroll
            for (int u = 0; u < 8; u++) {
                float re = 0, im = 0;
                #pragma unroll
                for (int s = 0; s < 8; s++) {
                    float2 w = w8[(u * s) & 7];
                    re += a[s].x * w.x - a[s].y * w.y;
                    im += a[s].x * w.y + a[s].y * w.x;
                }
                mrow[8 * u + v] = make_float2(re, im);
            }
        }
        if (tid < 8) {   // row 32 stage 2
            int v = tid;
            float2 a[8];
            #pragma unroll
            for (int s = 0; s < 8; s++) a[s] = mrow32[v * 8 + s];
            #pragma unroll
            for (int u = 0; u < 8; u++) {
                float re = 0, im = 0;
                #pragma unroll
                for (int s = 0; s < 8; s++) {
                    float2 w = w8[(u * s) & 7];
                    re += a[s].x * w.x - a[s].y * w.y;
                    im += a[s].x * w.y + a[s].y * w.x;
                }
                mrow32[8 * u + v] = make_float2(re, im);
            }
        }
    }
    __syncthreads();
    for (int i = tid; i < 31 * 64; i += TPB) {   // rows 33..63: conj mirror in g
        int mu = 33 + (i >> 6), g = i & 63;
        float2 v = sF[(64 - mu) * 66 + g];
        sF[mu * 66 + g] = make_float2(v.x, -v.y);
    }
    __syncthreads();
    float s_acc = 0.f, q_acc = 0.f;
    int r2 = tid >> 2, q = tid & 3;
    {   // dim-mu, per column c; real + bias out
        int c = r2;
        float bo = bias[o];
        float* dst = yout + ((size_t)zo_g * 64 + j) * 4096;
        #pragma unroll
        for (int half = 0; half < 2; half++) {
            int s = q + 4 * half;
            float2 f[8];
            #pragma unroll
            for (int p = 0; p < 8; p++) f[p] = sF[(8 * p + s) * 66 + c];
            float2 ws = tw[s];
            float2 t = make_float2(1.f, 0.f);
            #pragma unroll
            for (int v = 0; v < 8; v++) {
                float re = 0, im = 0;
                #pragma unroll
                for (int p = 0; p < 8; p++) {
                    float2 w = w8[(v * p) & 7];
                    re += f[p].x * w.x - f[p].y * w.y;
                    im += f[p].x * w.y + f[p].y * w.x;
                }
                sF[(v * 8 + s) * 66 + c] = make_float2(re * t.x - im * t.y,
                                                       re * t.y + im * t.x);
                float tx = t.x * ws.x - t.y * ws.y;
                t.y = t.x * ws.y + t.y * ws.x; t.x = tx;
            }
        }
        float2 a[2][8];
        #pragma unroll
        for (int half = 0; half < 2; half++) {
            int v = q + 4 * half;
            #pragma unroll
            for (int s = 0; s < 8; s++) a[half][s] = sF[(v * 8 + s) * 66 + c];
        }
        #pragma unroll
        for (int half = 0; half < 2; half++) {
            int v = q + 4 * half;
            #pragma unroll
            for (int u = 0; u < 8; u++) {
                float re = 0;
                #pragma unroll
                for (int s = 0; s < 8; s++) {
                    float2 w = w8[(u * s) & 7];
                    re += a[half][s].x * w.x - a[half][s].y * w.y;
                }
                float val = re + bo;
                dst[(8 * u + v) * 64 + c] = val;
                s_acc += val;
                q_acc += val * val;
            }
        }
    }
    // fused BN stats: block reduce + 2 atomics (replaces k_bn_stats pass)
    __syncthreads();
    float* rs = (float*)sF;
    rs[tid] = s_acc;
    rs[TPB + tid] = q_acc;
    __syncthreads();
    for (int st = TPB / 2; st > 0; st >>= 1) {
        if (tid < st) { rs[tid] += rs[tid + st]; rs[TPB + tid] += rs[TPB + tid + st]; }
        __syncthreads();
    }
    if (tid == 0) {
        atomicAdd(&stats[o * 2], rs[0]);
        atomicAdd(&stats[o * 2 + 1], rs[TPB]);
    }
}

__global__ void k_final(const float* __restrict__ y, const float* __restrict__ stats,
                        const float* __restrict__ gamma, const float* __restrict__ beta,
                        float* __restrict__ out) {
    int t = blockIdx.x * TPB + threadIdx.x;
    if (t >= kB * kF2 * 4096) return;
    int zo = t >> 12, o = zo % kF2;
    const float inv = 1.0f / 524288.0f;
    float mean = stats[o * 2] * inv;
    float var = stats[o * 2 + 1] * inv - mean * mean;
    float rstd = rsqrtf(var + 1e-5f);
    float ga = gamma[o], be = beta[o];
    const float* p = y + (size_t)t * 64;
    float acc = 0;
    for (int g = 0; g < 64; g++) {
        float v = (p[g] - mean) * rstd * ga + be;
        acc += v > 0.f ? v : 0.f;
    }
    out[t] = acc * (1.0f / 64.0f);
}

// ---------------------------------------------------------------------------
extern "C" void kernel_launch(void* const* d_in, const int* in_sizes, int n_in,
                              void* d_out, int out_size, void* d_ws, size_t ws_size,
                              hipStream_t stream) {
    const float* x     = (const float*)d_in[0];
    const float* k1    = (const float*)d_in[1];
    const float* bias1 = (const float*)d_in[2];
    const float* g1    = (const float*)d_in[3];
    const float* be1   = (const float*)d_in[4];
    const float* k2    = (const float*)d_in[5];
    const float* bias2 = (const float*)d_in[6];
    const float* g2    = (const float*)d_in[7];
    const float* be2   = (const float*)d_in[8];
    const float* k3    = (const float*)d_in[9];
    const float* bias3 = (const float*)d_in[10];
    const float* g3    = (const float*)d_in[11];
    const float* be3   = (const float*)d_in[12];

    char* ws = (char*)d_ws;
    size_t off = 0;
    auto alloc = [&](size_t bytes) {
        size_t cur = off;
        off = (off + bytes + 255) & ~(size_t)255;
        return cur;
    };
    size_t o_const = alloc(g_tab.bytes);                       // 3.0 MB
    size_t o_dqz   = alloc((size_t)kNM * 64 * 64 * 4);         // 16.8 MB
    size_t o_dqtw  = alloc((size_t)64 * kNMN * 4);             // 11.2 MB
    size_t o_deTp  = alloc((size_t)4 * 11424 * 4);             // 0.18 MB (padded, full)
    size_t o_khat  = alloc((size_t)kF1 * kF1 * 64 * 8);        // 1.8 MB
    size_t o_xf1   = alloc((size_t)kB * kF0 * 64 * 64 * 8);    // 0.2 MB
    size_t o_fh1   = alloc((size_t)kNM * kB * kF0 * 8);        // 0.05 MB
    size_t o_stats = alloc(2 * 64 * 4);
    size_t o_fh    = alloc((size_t)kB * kF1 * kNMN * 8);       // 42 MB (fh, then zs)
    size_t o_scr   = alloc((size_t)kFCH * kCube * 8);          // 50.3 MB (dtmp/xf/G/T)
    size_t o_cube  = alloc((size_t)kB * kF1 * kCube * 4);      // 126 MB
    if (off > ws_size) return;

    const float* cb = (const float*)(ws + o_const);
    const float2* twf = (const float2*)(cb + g_tab.o_twf);
    const float2* twi = (const float2*)(cb + g_tab.o_twi);
    const float* w_t = cb + g_tab.o_w;
    const float* etab = cb + g_tab.o_etab;
    const float* dehalf = etab + (size_t)(8 + 4) * kNMN;  // G_4 = E0^32 = d(pi/2)
    const int* lmn_l = (const int*)(cb + g_tab.o_lmnl);
    const int* lm_l = (const int*)(cb + g_tab.o_lml);
    const int* lmn2 = (const int*)(cb + g_tab.o_lmn2);
    const int* lmq = (const int*)(cb + g_tab.o_lmq);
    const int* off4 = (const int*)(cb + g_tab.o_off4);

    float* dqz = (float*)(ws + o_dqz);
    float* dqtw = (float*)(ws + o_dqtw);
    float* deTp = (float*)(ws + o_deTp);
    float2* khat = (float2*)(ws + o_khat);
    float2* xf1 = (float2*)(ws + o_xf1);
    float2* fh1 = (float2*)(ws + o_fh1);
    float* stats = (float*)(ws + o_stats);
    float2* fh = (float2*)(ws + o_fh);
    float2* zsb = (float2*)(ws + o_fh);
    float* dtmp = (float*)(ws + o_scr);
    float2* Gb = (float2*)(ws + o_scr);
    float2* xfc = (float2*)(ws + o_scr);
    float2* Tb = (float2*)(ws + o_scr);
    float* cube = (float*)(ws + o_cube);

    hipMemcpyAsync(ws + o_const, g_tab.blob.data(), g_tab.bytes,
                   hipMemcpyHostToDevice, stream);
    hipMemsetAsync(dqz, 0, (size_t)kNM * 64 * 64 * 4, stream);
    hipMemsetAsync(deTp, 0, (size_t)4 * 11424 * 4, stream);
    k_gendqA<<<kLMAX * 64, TPB, 0, stream>>>(etab, dtmp);
    k_scat<<<kLMAX * 63, TPB, 0, stream>>>(dtmp, w_t, dqz, dqtw);
    k_transde_p<<<(kNMN + TPB - 1) / TPB, TPB, 0, stream>>>(dehalf, deTp, lmn_l, off4);

    const float S2S = 1.0f / sqrtf(64.0f * 3.0f * 1024.0f);
    const float SO3S = 1.0f / sqrtf(64.0f * 60.0f);
    auto blks = [](size_t n) { return (int)((n + TPB - 1) / TPB); };

    auto synth = [&](const float* bi, int Fo) {
        hipMemsetAsync(stats, 0, 2 * 64 * 4, stream);
        int planes = kB * Fo;
        for (int zo0 = 0; zo0 < planes; zo0 += kFCH) {
            int nzo = planes - zo0 < kFCH ? planes - zo0 : kFCH;
            k_synA<<<dim3(33, nzo), TPB, 0, stream>>>(
                zsb + (size_t)zo0 * kNMN, dqz, Tb);
            k_synB<<<nzo * 64, TPB, 0, stream>>>(Tb, twi, bi, cube, stats, Fo, zo0);
        }
    };

    // ---- Layer 1: S2 conv -> cube ----
    k_khat<<<blks(kF0 * kF1 * 64), TPB, 0, stream>>>(k1, khat, twf, kF0 * kF1 * 64, S2S);
    k_fft1<<<blks(kB * kF0 * 64 * 64), TPB, 0, stream>>>(x, xf1, twf);
    k_fh1<<<blks(kNM * kB * kF0), TPB, 0, stream>>>(xf1, dqtw, lm_l, fh1);
    k_zs1<<<blks((size_t)(kF1 / 6) * kNMN2), TPB, 0, stream>>>(fh1, khat, dehalf,
                                                               lmn_l, lmn2, zsb);
    synth(bias1, kF1);

    // ---- Layers 2 & 3: SO3 conv; fft2 applies previous layer's BN+ReLU ----
    for (int layer = 2; layer <= 3; layer++) {
        int Fo = (layer == 2) ? kF1 : kF2;
        const float* kk = (layer == 2) ? k2 : k3;
        const float* bi = (layer == 2) ? bias2 : bias3;
        const float* gp = (layer == 2) ? g1 : g2;
        const float* bp = (layer == 2) ? be1 : be2;
        k_khat<<<blks(kF1 * Fo * 64), TPB, 0, stream>>>(kk, khat, twf, kF1 * Fo * 64, SO3S);
        for (int zf0 = 0; zf0 < kB * kF1; zf0 += kFCH) {
            int nzf = kB * kF1 - zf0 < kFCH ? kB * kF1 - zf0 : kFCH;
            k_fft2<<<nzf * 64, TPB, 0, stream>>>(cube + (size_t)zf0 * kCube, xfc,
                                                 twf, stats, gp, bp, zf0);
            k_fh3<<<2048, TPB, 0, stream>>>(xfc, dqtw, fh + (size_t)zf0 * kNMN, nzf);
        }
        {
            int total = kB * kF1 * kNQ2;
            k_G4<<<blks(total), TPB, 0, stream>>>(fh, deTp, lmq, off4, Gb, total);
        }
        if (layer == 2) {
            int nOg = kF1 / 3;
            int CHb = (kCH2 * nOg + 7) / 8;
            k_zs_v4<60, 60><<<8 * CHb, TPB, 0, stream>>>(Gb, khat, lmn_l, lmn2, zsb);
        } else {
            int nOg = kF2 / 3;
            int CHb = (kCH2 * nOg + 7) / 8;
            k_zs_v4<60, 36><<<8 * CHb, TPB, 0, stream>>>(Gb, khat, lmn_l, lmn2, zsb);
        }
        synth(bi, Fo);
        if (layer == 3)
            k_final<<<blks(kB * kF2 * 4096), TPB, 0, stream>>>(cube, stats, g3, be3, (float*)d_out);
    }
}

// Round 14
// 1646.125 us; speedup vs baseline: 1.2141x; 1.1359x over previous
//
#include <hip/hip_runtime.h>
#include <cmath>
#include <cstring>
#include <cstdint>
#include <vector>

#define TPB 256
static constexpr int kLMAX = 32;
static constexpr int kNMN  = 43680;   // sum_{l<32} (2l+1)^2
static constexpr int kNMN2 = 22352;   // sum_{l<32} (l+1)(2l+1)  (m>=0 rows only)
static constexpr int kNM   = 1024;    // sum_{l<32} (2l+1)
static constexpr int kNQ2  = 5848;    // sum_{l<32} (l+1)*ceil((2l+1)/4)
static constexpr int kB    = 2;
static constexpr int kF0   = 3, kF1 = 60, kF2 = 36;
static constexpr int kCube = 262144;  // 64^3
static constexpr int kFCH  = 40;      // plane chunk (compact planes: 40 fit scratch)
static constexpr int kXfP  = 131072;  // xf plane: 64 beta x 32 mu x 64 nu float2
static constexpr int kTfP  = 135168;  // T plane: 33 mu x 64 j x 64 g float2
static constexpr int kCH2  = (kNMN2 + 255) / 256;   // 88 lmn2-chunks of 256

__host__ __device__ inline int off3i(int l) { return l * (4 * l * l - 1) / 3; }

// ---------------------------------------------------------------------------
// Host-side constant tables (~3.0 MB seeds; d_b = F_{b&7} * G_{b>>3}).
// Hermitian dead-code note: synA (mu<=32) only reads zs rows with m>=0, so
// the zs/G/fh chain is computed ONLY for mi>=l (lmn2/lmq tables below), and
// fh3/fft2 only produce the mu in [0,31] half of the spectrum. xf/T planes
// are stored COMPACT (32/33 rows) so kFCH=40 planes fit the scratch buffer.
// ---------------------------------------------------------------------------
static void h_matmul(const std::vector<double>& A, const std::vector<double>& B,
                     std::vector<double>& C, int n) {
    C.assign((size_t)n * n, 0.0);
    for (int i = 0; i < n; i++)
        for (int k = 0; k < n; k++) {
            double a = A[(size_t)i * n + k];
            if (a == 0.0) continue;
            const double* bp = &B[(size_t)k * n];
            double* cp = &C[(size_t)i * n];
            for (int j = 0; j < n; j++) cp[j] += a * bp[j];
        }
}

struct HostTables {
    std::vector<float> blob;
    size_t o_twf, o_twi, o_w, o_lmnl, o_lml, o_lmn2, o_lmq, o_off4, o_etab;
    size_t bytes;
    HostTables() {
        size_t n = 0;
        o_twf = n;  n += 128;
        o_twi = n;  n += 128;
        o_w = n;    n += 64;
        o_lmnl = n; n += kNMN;
        o_lml = n;  n += kNM;
        o_lmn2 = n; n += kNMN2;
        o_lmq = n;  n += kNQ2;
        o_off4 = n; n += 32;
        o_etab = n; n += (size_t)16 * kNMN;    // [F_0..F_7, G_0..G_7] per l
        blob.assign(n, 0.0f);
        bytes = n * 4;

        for (int k = 0; k < 64; k++) {
            double th = -2.0 * M_PI * k / 64.0;
            blob[o_twf + 2 * k]     = (float)cos(th);
            blob[o_twf + 2 * k + 1] = (float)sin(th);
            blob[o_twi + 2 * k]     = (float)cos(th);
            blob[o_twi + 2 * k + 1] = (float)(-sin(th));
        }
        for (int j = 0; j < 64; j++) {
            double s = 0;
            for (int k = 0; k < 32; k++)
                s += sin((2.0 * j + 1) * (2.0 * k + 1) * M_PI / 128.0) / (2.0 * k + 1);
            blob[o_w + j] = (float)(2.0 / 32.0 * sin(M_PI * (2.0 * j + 1) / 128.0) * s);
        }
        // lmn2: compact index of (l, mi>=l, ni) -> original lmn offset.
        {
            int qi = 0;
            for (int l = 0; l < kLMAX; l++) {
                int R = 2 * l + 1, o3 = off3i(l);
                for (int mi = l; mi < R; mi++)
                    for (int ni = 0; ni < R; ni++) {
                        int32_t v = o3 + mi * R + ni;
                        memcpy(&blob[o_lmn2 + qi], &v, 4);
                        qi++;
                    }
            }
        }
        // q -> (l, mi>=l, n0) table for n4-blocked k_G4, and padded-deT offsets.
        {
            int qi = 0, acc4 = 0;
            for (int l = 0; l < kLMAX; l++) {
                int R = 2 * l + 1, Rp = (R + 3) & ~3, C = Rp >> 2;
                int32_t o4 = acc4;
                memcpy(&blob[o_off4 + l], &o4, 4);
                for (int m = l; m < R; m++)
                    for (int c = 0; c < C; c++) {
                        int32_t pk = l | (m << 5) | ((4 * c) << 11);
                        memcpy(&blob[o_lmq + qi], &pk, 4);
                        qi++;
                    }
                acc4 += R * Rp;
            }
        }
        std::vector<double> A, Eh, E0, E08, F, G, term, tmp;
        for (int l = 0; l < kLMAX; l++) {
            int R = 2 * l + 1, o3 = off3i(l);
            A.assign((size_t)R * R, 0.0);
            for (int i = 0; i + 1 < R; i++) {
                double m = (double)i - l;
                double c = sqrt((double)l * (l + 1) - m * (m + 1));
                A[(size_t)(i + 1) * R + i] = -(M_PI / 128.0) * c * 0.5;
                A[(size_t)i * R + (i + 1)] =  (M_PI / 128.0) * c * 0.5;
            }
            Eh.assign((size_t)R * R, 0.0);
            for (int i = 0; i < R; i++) Eh[(size_t)i * R + i] = 1.0;
            term = Eh;
            for (int k = 1; k <= 30; k++) {
                h_matmul(term, A, tmp, R);
                for (auto& v : tmp) v /= k;
                term = tmp;
                for (size_t i = 0; i < (size_t)R * R; i++) Eh[i] += term[i];
            }
            h_matmul(Eh, Eh, E0, R);
            h_matmul(E0, E0, tmp, R);
            h_matmul(tmp, tmp, E08, R);
            h_matmul(E08, E08, tmp, R); E08 = tmp;  // E0^8
            F = Eh;
            for (int lo = 0; lo < 8; lo++) {
                for (int r = 0; r < R * R; r++)
                    blob[o_etab + (size_t)lo * kNMN + o3 + r] = (float)F[r];
                if (lo < 7) { h_matmul(F, E0, tmp, R); F = tmp; }
            }
            G.assign((size_t)R * R, 0.0);
            for (int i = 0; i < R; i++) G[(size_t)i * R + i] = 1.0;
            for (int hi = 0; hi < 8; hi++) {
                for (int r = 0; r < R * R; r++)
                    blob[o_etab + (size_t)(8 + hi) * kNMN + o3 + r] = (float)G[r];
                if (hi < 7) { h_matmul(G, E08, tmp, R); G = tmp; }
            }
            int32_t li = l;
            for (int r = 0; r < R * R; r++) memcpy(&blob[o_lmnl + o3 + r], &li, 4);
            for (int m = 0; m < R; m++)    memcpy(&blob[o_lml + (size_t)l * l + m], &li, 4);
        }
    }
};
static HostTables g_tab;

// ---------------------------------------------------------------------------
__global__ __launch_bounds__(TPB) void k_gendqA(const float* __restrict__ etab,
                                                float* __restrict__ dtmp) {
    __shared__ float Fm[3969];
    __shared__ float Gm[63 * 64];
    int l = blockIdx.x >> 6, b = blockIdx.x & 63;
    int lo = b & 7, hi = b >> 3;
    int R = 2 * l + 1, RR = R * R, o3 = off3i(l);
    int tid = threadIdx.x;
    const float* Fsrc = etab + (size_t)lo * kNMN + o3;
    const float* Gsrc = etab + (size_t)(8 + hi) * kNMN + o3;
    for (int i = tid; i < RR; i += TPB) Fm[i] = Fsrc[i];
    for (int i = tid; i < R * 64; i += TPB) {
        int k = i >> 6, c = i & 63;
        Gm[i] = (c < R) ? Gsrc[k * R + c] : 0.f;
    }
    __syncthreads();
    int Gc = (R + 15) >> 4;
    if (tid < R * Gc) {
        int row = tid / Gc, g = tid - row * Gc;
        float4 A0 = make_float4(0,0,0,0), A1 = A0, A2 = A0, A3 = A0;
        const float* fr = Fm + row * R;
        for (int k = 0; k < R; k++) {
            float a = fr[k];
            const float4* gp = (const float4*)(Gm + (k << 6) + (g << 4));
            float4 q0 = gp[0], q1 = gp[1], q2 = gp[2], q3 = gp[3];
            A0.x += a * q0.x; A0.y += a * q0.y; A0.z += a * q0.z; A0.w += a * q0.w;
            A1.x += a * q1.x; A1.y += a * q1.y; A1.z += a * q1.z; A1.w += a * q1.w;
            A2.x += a * q2.x; A2.y += a * q2.y; A2.z += a * q2.z; A2.w += a * q2.w;
            A3.x += a * q3.x; A3.y += a * q3.y; A3.z += a * q3.z; A3.w += a * q3.w;
        }
        float v[16] = {A0.x,A0.y,A0.z,A0.w, A1.x,A1.y,A1.z,A1.w,
                       A2.x,A2.y,A2.z,A2.w, A3.x,A3.y,A3.z,A3.w};
        float* dst = dtmp + (size_t)o3 * 64 + (size_t)b * RR + row * R;
        int c0 = g << 4;
        #pragma unroll
        for (int e = 0; e < 16; e++)
            if (c0 + e < R) dst[c0 + e] = v[e];
    }
}

__global__ __launch_bounds__(TPB) void k_scat(const float* __restrict__ dtmp,
                                              const float* __restrict__ w,
                                              float* __restrict__ dqz,
                                              float* __restrict__ dqtw) {
    __shared__ float S[64 * 65];
    int l = blockIdx.x / 63, tile = blockIdx.x % 63;
    int R = 2 * l + 1, RR = R * R, o3 = off3i(l);
    int i0 = tile * 64;
    if (i0 >= RR) return;
    int tid = threadIdx.x;
    const float* src = dtmp + (size_t)o3 * 64;
    #pragma unroll
    for (int s = 0; s < 16; s++) {
        int idx = tid + s * TPB;
        int b = idx >> 6, ii = idx & 63;
        int i = i0 + ii;
        S[ii * 65 + b] = (i < RR) ? src[(size_t)b * RR + i] : 0.f;
    }
    __syncthreads();
    float Rf = (float)R;
    #pragma unroll
    for (int s = 0; s < 16; s++) {
        int idx = tid + s * TPB;
        int ii = idx >> 6, b = idx & 63;
        int i = i0 + ii;
        if (i < RR) {
            float v = S[ii * 65 + b];
            dqtw[((size_t)o3 + i) * 64 + b] = w[b] * v;
            int mi = i / R, ni = i - mi * R;
            int nu = (ni - l) & 63;
            dqz[((size_t)(l * l + mi) * 64 + nu) * 64 + b] = Rf * v;
        }
    }
}

// Builds padded-row deTp: deTp[off4(l) + k*Rp + n] = dehalf[o3 + n*R + k],
// Rp = ceil(R/4)*4. Pad entries stay zero (memset upstream).
__global__ void k_transde_p(const float* __restrict__ dehalf, float* __restrict__ deTp,
                            const int* __restrict__ lmn_l, const int* __restrict__ off4) {
    int t = blockIdx.x * TPB + threadIdx.x;
    if (t >= kNMN) return;
    int l = lmn_l[t], o3 = off3i(l), r = t - o3, R = 2 * l + 1;
    int Rp = (R + 3) & ~3;
    int n = r / R, k = r - n * R;
    deTp[off4[l] + k * Rp + n] = dehalf[t];
}

__global__ void k_khat(const float* __restrict__ kern, float2* __restrict__ khat,
                       const float2* __restrict__ twf, int total, float scale) {
    int t = blockIdx.x * TPB + threadIdx.x;
    if (t >= total) return;
    int nu = t & 63, fo = t >> 6;
    const float* row = kern + (size_t)fo * 64;
    float re = 0, im = 0;
    for (int p = 0; p < 64; p++) {
        float2 w = twf[(p * nu) & 63];
        float v = row[p];
        re += v * w.x; im += v * w.y;
    }
    khat[t] = make_float2(re * scale, im * scale);
}

__global__ void k_fft1(const float* __restrict__ x, float2* __restrict__ xf1,
                       const float2* __restrict__ twf) {
    int t = blockIdx.x * TPB + threadIdx.x;
    if (t >= kB * kF0 * 64 * 64) return;
    int mu = t & 63, row = t >> 6;
    const float* p = x + (size_t)row * 64;
    float re = 0, im = 0;
    for (int a = 0; a < 64; a++) {
        float2 w = twf[(a * mu) & 63];
        float v = p[a];
        re += v * w.x; im += v * w.y;
    }
    xf1[t] = make_float2(re, im);
}

__global__ void k_fh1(const float2* __restrict__ xf1, const float* __restrict__ dqtw,
                      const int* __restrict__ lm_l, float2* __restrict__ fh1) {
    int t = blockIdx.x * TPB + threadIdx.x;
    if (t >= kNM * kB * kF0) return;
    int lm = t / 6, rem = t % 6, z = rem / 3, f = rem % 3;
    int l = lm_l[lm], m = lm - l * l, R = 2 * l + 1, o3 = off3i(l);
    int mu = (m - l) & 63;
    const float4* wq = (const float4*)(dqtw + (size_t)o3 * 64 + (size_t)(m * R + l) * 64);
    const float2* xr = xf1 + (size_t)((z * 3 + f) * 64) * 64 + mu;
    float re0 = 0, im0 = 0, re1 = 0, im1 = 0;
    #pragma unroll
    for (int b4 = 0; b4 < 16; b4++) {
        float4 w4 = wq[b4];
        float2 v0 = xr[(4 * b4 + 0) * 64];
        float2 v1 = xr[(4 * b4 + 1) * 64];
        float2 v2 = xr[(4 * b4 + 2) * 64];
        float2 v3 = xr[(4 * b4 + 3) * 64];
        re0 += w4.x * v0.x + w4.y * v1.x; im0 += w4.x * v0.y + w4.y * v1.y;
        re1 += w4.z * v2.x + w4.w * v3.x; im1 += w4.z * v2.y + w4.w * v3.y;
    }
    const float C2 = 1.0f / 128.0f;
    fh1[t] = make_float2((re0 + re1) * C2, (im0 + im1) * C2);
}

// Layer-1 zs restricted to lmn2 (mi>=l): synA never reads m<0 rows.
__global__ void k_zs1(const float2* __restrict__ fh1, const float2* __restrict__ khat,
                      const float* __restrict__ dehalf, const int* __restrict__ lmn_l,
                      const int* __restrict__ lmn2, float2* __restrict__ zs) {
    int nOg = kF1 / 6;                       // 10
    int t = blockIdx.x * TPB + threadIdx.x;  // og*NMN2 + i2
    if (t >= nOg * kNMN2) return;
    int i2 = t % kNMN2, og = t / kNMN2;
    int lmn = lmn2[i2];
    int l = lmn_l[lmn], o3 = off3i(l), r = lmn - o3, R = 2 * l + 1;
    int m = r / R, n = r - m * R;
    int nu = (n - l) & 63;
    float de1 = dehalf[o3 + n * R + l];
    int o0 = og * 6;
    const float2* fp = fh1 + (size_t)(l * l + m) * 6;
    const float2* kp = khat + (size_t)o0 * 64 + nu;
    float2 c0[6], c1[6];
    #pragma unroll
    for (int i = 0; i < 6; i++) {
        c0[i] = make_float2(0.f, 0.f);
        c1[i] = make_float2(0.f, 0.f);
    }
    #pragma unroll
    for (int f = 0; f < kF0; f++) {
        float2 a0 = fp[f];       // z = 0
        float2 a1 = fp[3 + f];   // z = 1
        const float2* kf = kp + (size_t)f * kF1 * 64;
        #pragma unroll
        for (int i = 0; i < 6; i++) {
            float2 b = kf[(size_t)i * 64];   // conj applied below
            c0[i].x += a0.x * b.x + a0.y * b.y;
            c0[i].y += a0.y * b.x - a0.x * b.y;
            c1[i].x += a1.x * b.x + a1.y * b.y;
            c1[i].y += a1.y * b.x - a1.x * b.y;
        }
    }
    float2* zp0 = zs + (size_t)o0 * kNMN + lmn;
    float2* zp1 = zs + ((size_t)kF1 + o0) * kNMN + lmn;
    #pragma unroll
    for (int i = 0; i < 6; i++) {
        zp0[(size_t)i * kNMN] = make_float2(c0[i].x * de1, c0[i].y * de1);
        zp1[(size_t)i * kNMN] = make_float2(c1[i].x * de1, c1[i].y * de1);
    }
}

// 2D forward DFT (radix-8 x2) with fused BN+ReLU; float4 staging.
// HERMITIAN DCE (output): k_fh3 reads only mu in [0,31] -> pass-2 computes
// only u<4, and xf planes are stored COMPACT (32 mu rows, kXfP float2/zf).
// HERMITIAN (input): rows are REAL, so pass-1 output satisfies
// F[64-nu] = conj(F[nu]); pass-1 stage-2 computes nu<=32 and mirrors 33..63
// in LDS (intra-wave lockstep, same reliance as the cross-lane stage reads).
__global__ __launch_bounds__(TPB) void k_fft2(const float* __restrict__ y,
                                              float2* __restrict__ xf,
                                              const float2* __restrict__ twf_g,
                                              const float* __restrict__ stats,
                                              const float* __restrict__ gamma,
                                              const float* __restrict__ beta,
                                              int zf0) {
    __shared__ float sIn[64 * 65];
    __shared__ float2 sMid[64 * 66];
    __shared__ float2 tw[64];
    int blk = blockIdx.x, tid = threadIdx.x;
    if (tid < 64) tw[tid] = twf_g[tid];
    int o = (zf0 + (blk >> 6)) % kF1;
    const float inv = 1.0f / 524288.0f;
    float mean = stats[o * 2] * inv;
    float var = stats[o * 2 + 1] * inv - mean * mean;
    float rstd = rsqrtf(var + 1e-5f);
    float ga = gamma[o], be = beta[o];
    const float4* src4 = (const float4*)(y + (size_t)blk * 4096);
    for (int i = tid; i < 1024; i += TPB) {
        float4 v4 = src4[i];
        int row = i >> 4, col = (i & 15) << 2;
        float* d = sIn + row * 65 + col;
        float a0 = (v4.x - mean) * rstd * ga + be;
        float a1 = (v4.y - mean) * rstd * ga + be;
        float a2 = (v4.z - mean) * rstd * ga + be;
        float a3 = (v4.w - mean) * rstd * ga + be;
        d[0] = a0 > 0.f ? a0 : 0.f;
        d[1] = a1 > 0.f ? a1 : 0.f;
        d[2] = a2 > 0.f ? a2 : 0.f;
        d[3] = a3 > 0.f ? a3 : 0.f;
    }
    __syncthreads();
    float2 w8[8];
    #pragma unroll
    for (int k = 0; k < 8; k++) w8[k] = tw[k * 8];
    int r2 = tid >> 2, q = tid & 3;
    {   // dim-1: g -> nu, REAL input
        const float* rowp = sIn + r2 * 65;
        float2* mrow = sMid + r2 * 66;
        #pragma unroll
        for (int half = 0; half < 2; half++) {
            int s = q + 4 * half;
            float f[8];
            #pragma unroll
            for (int p = 0; p < 8; p++) f[p] = rowp[8 * p + s];
            float2 ws = tw[s];
            float2 t = make_float2(1.f, 0.f);
            #pragma unroll
            for (int v = 0; v < 8; v++) {
                float re = 0, im = 0;
                #pragma unroll
                for (int p = 0; p < 8; p++) {
                    float2 w = w8[(v * p) & 7];
                    re += f[p] * w.x; im += f[p] * w.y;
                }
                mrow[v * 8 + s] = make_float2(re * t.x - im * t.y, re * t.y + im * t.x);
                float tx = t.x * ws.x - t.y * ws.y;
                t.y = t.x * ws.y + t.y * ws.x; t.x = tx;
            }
        }
        float2 a[2][8];
        #pragma unroll
        for (int half = 0; half < 2; half++) {
            int v = q + 4 * half;
            #pragma unroll
            for (int s = 0; s < 8; s++) a[half][s] = mrow[v * 8 + s];
        }
        #pragma unroll
        for (int half = 0; half < 2; half++) {
            int v = q + 4 * half;
            #pragma unroll
            for (int u = 0; u < 4; u++) {   // nu = 8u+v in [0,31]
                float re = 0, im = 0;
                #pragma unroll
                for (int s = 0; s < 8; s++) {
                    float2 w = w8[(u * s) & 7];
                    re += a[half][s].x * w.x - a[half][s].y * w.y;
                    im += a[half][s].x * w.y + a[half][s].y * w.x;
                }
                mrow[8 * u + v] = make_float2(re, im);
            }
        }
        if (q == 0) {   // nu = 32 (u=4, v=0): only the half=0, v=0 slot
            float re = 0, im = 0;
            #pragma unroll
            for (int s = 0; s < 8; s++) {
                float2 w = w8[(4 * s) & 7];
                re += a[0][s].x * w.x - a[0][s].y * w.y;
                im += a[0][s].x * w.y + a[0][s].y * w.x;
            }
            mrow[32] = make_float2(re, im);
        }
        // mirror nu = 33..63: F[nu] = conj(F[64-nu]) (real input rows).
        for (int nu = 33 + q; nu < 64; nu += 4) {
            float2 vv = mrow[64 - nu];
            mrow[nu] = make_float2(vv.x, -vv.y);
        }
    }
    __syncthreads();
    {   // dim-2: a -> mu per column c; only mu < 32 needed downstream
        int c = r2;
        float2* dst = xf + (size_t)blk * 2048;   // compact 32-row plane slice
        #pragma unroll
        for (int half = 0; half < 2; half++) {
            int s = q + 4 * half;
            float2 f[8];
            #pragma unroll
            for (int p = 0; p < 8; p++) f[p] = sMid[(8 * p + s) * 66 + c];
            float2 ws = tw[s];
            float2 t = make_float2(1.f, 0.f);
            #pragma unroll
            for (int v = 0; v < 8; v++) {
                float re = 0, im = 0;
                #pragma unroll
                for (int p = 0; p < 8; p++) {
                    float2 w = w8[(v * p) & 7];
                    re += f[p].x * w.x - f[p].y * w.y;
                    im += f[p].x * w.y + f[p].y * w.x;
                }
                sMid[(v * 8 + s) * 66 + c] = make_float2(re * t.x - im * t.y,
                                                         re * t.y + im * t.x);
                float tx = t.x * ws.x - t.y * ws.y;
                t.y = t.x * ws.y + t.y * ws.x; t.x = tx;
            }
        }
        float2 a[2][8];
        #pragma unroll
        for (int half = 0; half < 2; half++) {
            int v = q + 4 * half;
            #pragma unroll
            for (int s = 0; s < 8; s++) a[half][s] = sMid[(v * 8 + s) * 66 + c];
        }
        #pragma unroll
        for (int half = 0; half < 2; half++) {
            int v = q + 4 * half;
            #pragma unroll
            for (int u = 0; u < 4; u++) {   // mu = 8u+v in [0,31] only
                float re = 0, im = 0;
                #pragma unroll
                for (int s = 0; s < 8; s++) {
                    float2 w = w8[(u * s) & 7];
                    re += a[half][s].x * w.x - a[half][s].y * w.y;
                    im += a[half][s].x * w.y + a[half][s].y * w.x;
                }
                dst[(8 * u + v) * 64 + c] = make_float2(re, im);
            }
        }
    }
}

// fh3: one block per (mu,nu) column, mu in [0..31] ONLY (m>=0 rows; the m<0
// half of fh is dead code downstream). X and dqtw staged once in LDS.
// xf planes are compact (32 rows, kXfP float2/zf). nzf up to kFCH=40.
// XCD swizzle in 256-block chunks keeps nu-adjacent blocks on one L2.
__global__ __launch_bounds__(TPB) void k_fh3(const float2* __restrict__ xf,
                                             const float* __restrict__ dqtw,
                                             float2* __restrict__ fh_out, int nzf) {
    __shared__ float2 sX[kFCH * 66];  // [zf][b], row stride 66 float2
    __shared__ float  sD[32 * 68];    // [li][b], row stride 68 floats
    int v = blockIdx.x;               // 2048 blocks
    int wg = (v & 7) * 256 + (v >> 3);
    int nu = wg & 63, mu = wg >> 6;   // mu in [0,31] -> mt = mu >= 0
    int mt = mu;
    int nt = (nu <= 31) ? nu : nu - 64;
    int am = mu, an = nt < 0 ? -nt : nt;
    int lmin = am > an ? am : an;
    if (lmin >= kLMAX) return;
    int nl = kLMAX - lmin;
    int tid = threadIdx.x;
    for (int i = tid; i < nzf * 64; i += TPB) {
        int zf = i >> 6, b = i & 63;
        sX[zf * 66 + b] = xf[(size_t)zf * kXfP + (size_t)b * 2048 + mu * 64 + nu];
    }
    for (int i = tid; i < nl * 64; i += TPB) {
        int li = i >> 6, b = i & 63;
        int l = lmin + li, R = 2 * l + 1;
        int r = (mt + l) * R + (nt + l);
        sD[li * 68 + b] = dqtw[(size_t)(off3i(l) + r) * 64 + b];
    }
    __syncthreads();
    const float C3 = 1.0f / 8192.0f;
    int items = nzf * nl;
    for (int item = tid; item < items; item += TPB) {
        int zf = item / nl, li = item - zf * nl;
        const float4* D4 = (const float4*)(sD + li * 68);
        const float4* X4 = (const float4*)(sX + zf * 66);
        float re0 = 0, im0 = 0, re1 = 0, im1 = 0;
        #pragma unroll
        for (int b4 = 0; b4 < 16; b4++) {
            float4 d   = D4[b4];
            float4 x01 = X4[2 * b4];
            float4 x23 = X4[2 * b4 + 1];
            re0 += d.x * x01.x; im0 += d.x * x01.y;
            re0 += d.y * x01.z; im0 += d.y * x01.w;
            re1 += d.z * x23.x; im1 += d.z * x23.y;
            re1 += d.w * x23.z; im1 += d.w * x23.w;
        }
        int l = lmin + li, R = 2 * l + 1;
        int r = (mt + l) * R + (nt + l);
        fh_out[(size_t)zf * kNMN + off3i(l) + r] =
            make_float2((re0 + re1) * C3, (im0 + im1) * C3);
    }
}

// G (n4-blocked, mi>=l rows only): thread computes 4 consecutive n outputs.
// Per k: 1 float2 fh broadcast + 1 aligned float4 deTp row-load -> 16 lane-FMA.
__global__ void k_G4(const float2* __restrict__ fh, const float* __restrict__ deTp,
                     const int* __restrict__ lmq, const int* __restrict__ off4,
                     float2* __restrict__ G, int total) {
    int t = blockIdx.x * TPB + threadIdx.x;
    if (t >= total) return;
    int q = t % kNQ2, zf = t / kNQ2;
    int pk = lmq[q];
    int l = pk & 31, m = (pk >> 5) & 63, n0 = pk >> 11;
    int R = 2 * l + 1, o3 = off3i(l);
    int C4 = ((R + 3) & ~3) >> 2;            // Rp/4
    const float2* fr = fh + (size_t)zf * kNMN + o3 + m * R;
    const float4* dp = (const float4*)(deTp + off4[l] + n0);
    float4 re = make_float4(0.f, 0.f, 0.f, 0.f);
    float4 im = make_float4(0.f, 0.f, 0.f, 0.f);
    int k = 0;
    for (; k + 1 < R; k += 2) {
        float2 f0 = fr[k], f1 = fr[k + 1];
        float4 d0 = dp[(size_t)k * C4];
        float4 d1 = dp[(size_t)(k + 1) * C4];
        re.x += f0.x * d0.x + f1.x * d1.x; im.x += f0.y * d0.x + f1.y * d1.x;
        re.y += f0.x * d0.y + f1.x * d1.y; im.y += f0.y * d0.y + f1.y * d1.y;
        re.z += f0.x * d0.z + f1.x * d1.z; im.z += f0.y * d0.z + f1.y * d1.z;
        re.w += f0.x * d0.w + f1.x * d1.w; im.w += f0.y * d0.w + f1.y * d1.w;
    }
    {
        float2 f0 = fr[k];
        float4 d0 = dp[(size_t)k * C4];
        re.x += f0.x * d0.x; im.x += f0.y * d0.x;
        re.y += f0.x * d0.y; im.y += f0.y * d0.y;
        re.z += f0.x * d0.z; im.z += f0.y * d0.z;
        re.w += f0.x * d0.w; im.w += f0.y * d0.w;
    }
    float2* gp = G + (size_t)zf * kNMN + o3 + m * R + n0;
    int rem = R - n0;
    gp[0] = make_float2(re.x, im.x);
    if (rem > 1) gp[1] = make_float2(re.y, im.y);
    if (rem > 2) gp[2] = make_float2(re.z, im.z);
    if (rem > 3) gp[3] = make_float2(re.w, im.w);
}

// zs v4: og-tile 3; barrier-free body + og-fastest XCD-grouped decode +
// compile-time FIN/FO + unroll-4 f-loop; lmn2 (mi>=l) restricted.
template<int FIN, int FO>
__global__ __launch_bounds__(TPB) void k_zs_v4(const float2* __restrict__ G,
                                               const float2* __restrict__ khat,
                                               const int* __restrict__ lmn_l,
                                               const int* __restrict__ lmn2,
                                               float2* __restrict__ zs) {
    constexpr int NOG = FO / 3;
    int CHb = gridDim.x >> 3;
    int bid = blockIdx.x;
    int work = (bid & 7) * CHb + (bid >> 3);   // bijective; og-fastest
    if (work >= kCH2 * NOG) return;
    int x = work / NOG, og = work - x * NOG;
    int i2 = x * 256 + threadIdx.x;
    if (i2 >= kNMN2) return;
    int lmn = lmn2[i2];
    int l = lmn_l[lmn], r = lmn - off3i(l), R = 2 * l + 1;
    int n = r % R;
    int nu = (n - l) & 63;
    int o0 = og * 3;
    const float2* gp0 = G + lmn;
    const float2* gp1 = G + (size_t)FIN * kNMN + lmn;
    const float2* kp = khat + (size_t)o0 * 64 + nu;
    float2 c0[3], c1[3];
    #pragma unroll
    for (int i = 0; i < 3; i++) {
        c0[i] = make_float2(0.f, 0.f);
        c1[i] = make_float2(0.f, 0.f);
    }
    #pragma unroll 4
    for (int f = 0; f < FIN; f++) {
        float2 a0 = gp0[(size_t)f * kNMN];
        float2 a1 = gp1[(size_t)f * kNMN];
        const float2* kf = kp + (size_t)f * FO * 64;
        #pragma unroll
        for (int i = 0; i < 3; i++) {
            float2 b = kf[(size_t)i * 64];   // conj applied in the FMA signs
            c0[i].x += a0.x * b.x + a0.y * b.y;
            c0[i].y += a0.y * b.x - a0.x * b.y;
            c1[i].x += a1.x * b.x + a1.y * b.y;
            c1[i].y += a1.y * b.x - a1.x * b.y;
        }
    }
    float2* zp0 = zs + (size_t)o0 * kNMN + lmn;
    float2* zp1 = zs + ((size_t)FO + o0) * kNMN + lmn;
    #pragma unroll
    for (int i = 0; i < 3; i++) {
        zp0[(size_t)i * kNMN] = c0[i];
        zp1[(size_t)i * kNMN] = c1[i];
    }
}

// Synthesis stage A (1-plane blocks): grid = (33 mu) x (nzo planes); each
// block accumulates ONE zo plane into the COMPACT T plane (33 rows, kTfP
// float2/zo). Same per-output FMA order as before -> bitwise-same T.
// HERMITIAN: mu = 0..32 only; rows 33..63 derived in k_synB by conj-mirror.
__global__ __launch_bounds__(TPB) void k_synA(const float2* __restrict__ zs,
                                              const float* __restrict__ dqz,
                                              float2* __restrict__ T) {
    __shared__ float2 sZ[32 * 64];
    int mu = blockIdx.x, zo = blockIdx.y;
    int tid = threadIdx.x;
    int mt = (mu <= 31) ? mu : mu - 64;
    int am = mt < 0 ? -mt : mt;
    #pragma unroll
    for (int k = 0; k < 8; k++) {
        int i = tid + k * TPB;
        int nu = i & 63, l = i >> 6;
        int nt = (nu <= 31) ? nu : nu - 64;
        int an = nt < 0 ? -nt : nt;
        float2 v = make_float2(0.f, 0.f);
        if (l >= am && an <= l)
            v = zs[(size_t)zo * kNMN + off3i(l) +
                   (mt + l) * (2 * l + 1) + nt + l];
        sZ[i] = v;
    }
    __syncthreads();
    int j = tid & 63, s = tid >> 6;
    float2 c0[16];
    #pragma unroll
    for (int k = 0; k < 16; k++) c0[k] = make_float2(0.f, 0.f);
    for (int l = am; l < 32; l++) {
        const float* dp = dqz + ((size_t)(l * l + mt + l) * 64 + s * 16) * 64 + j;
        const float4* z04 = (const float4*)(sZ + (size_t)l * 64 + s * 16);
        #pragma unroll
        for (int h = 0; h < 8; h++) {
            float d0 = dp[(size_t)(2 * h) * 64];
            float d1 = dp[(size_t)(2 * h + 1) * 64];
            float4 za = z04[h];
            c0[2 * h].x     += d0 * za.x; c0[2 * h].y     += d0 * za.y;
            c0[2 * h + 1].x += d1 * za.z; c0[2 * h + 1].y += d1 * za.w;
        }
    }
    float2* t0 = T + (((size_t)zo * 33 + mu) * 64 + j) * 64 + s * 16;
    #pragma unroll
    for (int k = 0; k < 16; k++) t0[k] = c0[k];
}

// Synthesis stage B: radix-8 x2 IDFT; real + bias out; fused BN-stats atomics.
// Stages T rows mu=0..32 (compact kTfP planes); pass-1 (dim-nu) runs ONLY on
// those 33 rows with 8 threads/row; rows 33..63 derived by
// h[mu][g] = conj(h[64-mu][g]). Pass-2 unchanged.
__global__ __launch_bounds__(TPB) void k_synB(const float2* __restrict__ T,
                                              const float2* __restrict__ twi_g,
                                              const float* __restrict__ bias,
                                              float* __restrict__ yout,
                                              float* __restrict__ stats,
                                              int Fo, int zo0) {
    __shared__ float2 sF[64 * 66];
    __shared__ float2 tw[64];
    int blk = blockIdx.x;
    int zo_l = blk >> 6, j = blk & 63;
    int zo_g = zo0 + zo_l;
    int o = zo_g % Fo;
    int tid = threadIdx.x;
    if (tid < 64) tw[tid] = twi_g[tid];
    const float4* src4 = (const float4*)(T + (size_t)zo_l * kTfP + (size_t)j * 64);
    for (int i = tid; i < 1056; i += TPB) {      // mu = 0..32 direct
        int mu = i >> 5, half = i & 31;
        float4 v = src4[(size_t)mu * 2048 + half];
        sF[mu * 66 + 2 * half]     = make_float2(v.x, v.y);
        sF[mu * 66 + 2 * half + 1] = make_float2(v.z, v.w);
    }
    __syncthreads();
    float2 w8[8];
    #pragma unroll
    for (int k = 0; k < 8; k++) w8[k] = tw[k * 8];
    {   // pass 1 (dim-nu): rows 0..31 with 8 threads/row; row 32 on lanes 0..7
        int r8 = tid >> 3, q8 = tid & 7;
        float2* mrow = sF + r8 * 66;
        float2* mrow32 = sF + 32 * 66;
        {
            int s = q8;
            float2 f[8];
            #pragma unroll
            for (int p = 0; p < 8; p++) f[p] = mrow[8 * p + s];
            float2 ws = tw[s];
            float2 t = make_float2(1.f, 0.f);
            #pragma unroll
            for (int v = 0; v < 8; v++) {
                float re = 0, im = 0;
                #pragma unroll
                for (int p = 0; p < 8; p++) {
                    float2 w = w8[(v * p) & 7];
                    re += f[p].x * w.x - f[p].y * w.y;
                    im += f[p].x * w.y + f[p].y * w.x;
                }
                mrow[v * 8 + s] = make_float2(re * t.x - im * t.y, re * t.y + im * t.x);
                float tx = t.x * ws.x - t.y * ws.y;
                t.y = t.x * ws.y + t.y * ws.x; t.x = tx;
            }
        }
        if (tid < 8) {   // row 32 stage 1 (wave 0 lanes 0..7, lockstep)
            int s = tid;
            float2 f[8];
            #pragma unroll
            for (int p = 0; p < 8; p++) f[p] = mrow32[8 * p + s];
            float2 ws = tw[s];
            float2 t = make_float2(1.f, 0.f);
            #pragma unroll
            for (int v = 0; v < 8; v++) {
                float re = 0, im = 0;
                #pragma unroll
                for (int p = 0; p < 8; p++) {
                    float2 w = w8[(v * p) & 7];
                    re += f[p].x * w.x - f[p].y * w.y;
                    im += f[p].x * w.y + f[p].y * w.x;
                }
                mrow32[v * 8 + s] = make_float2(re * t.x - im * t.y, re * t.y + im * t.x);
                float tx = t.x * ws.x - t.y * ws.y;
                t.y = t.x * ws.y + t.y * ws.x; t.x = tx;
            }
        }
        {
            int v = q8;
            float2 a[8];
            #pragma unroll
            for (int s = 0; s < 8; s++) a[s] = mrow[v * 8 + s];
            #pragma unroll
            for (int u = 0; u < 8; u++) {
                float re = 0, im = 0;
                #pragma unroll
                for (int s = 0; s < 8; s++) {
                    float2 w = w8[(u * s) & 7];
                    re += a[s].x * w.x - a[s].y * w.y;
                    im += a[s].x * w.y + a[s].y * w.x;
                }
                mrow[8 * u + v] = make_float2(re, im);
            }
        }
        if (tid < 8) {   // row 32 stage 2
            int v = tid;
            float2 a[8];
            #pragma unroll
            for (int s = 0; s < 8; s++) a[s] = mrow32[v * 8 + s];
            #pragma unroll
            for (int u = 0; u < 8; u++) {
                float re = 0, im = 0;
                #pragma unroll
                for (int s = 0; s < 8; s++) {
                    float2 w = w8[(u * s) & 7];
                    re += a[s].x * w.x - a[s].y * w.y;
                    im += a[s].x * w.y + a[s].y * w.x;
                }
                mrow32[8 * u + v] = make_float2(re, im);
            }
        }
    }
    __syncthreads();
    for (int i = tid; i < 31 * 64; i += TPB) {   // rows 33..63: conj mirror in g
        int mu = 33 + (i >> 6), g = i & 63;
        float2 v = sF[(64 - mu) * 66 + g];
        sF[mu * 66 + g] = make_float2(v.x, -v.y);
    }
    __syncthreads();
    float s_acc = 0.f, q_acc = 0.f;
    int r2 = tid >> 2, q = tid & 3;
    {   // dim-mu, per column c; real + bias out
        int c = r2;
        float bo = bias[o];
        float* dst = yout + ((size_t)zo_g * 64 + j) * 4096;
        #pragma unroll
        for (int half = 0; half < 2; half++) {
            int s = q + 4 * half;
            float2 f[8];
            #pragma unroll
            for (int p = 0; p < 8; p++) f[p] = sF[(8 * p + s) * 66 + c];
            float2 ws = tw[s];
            float2 t = make_float2(1.f, 0.f);
            #pragma unroll
            for (int v = 0; v < 8; v++) {
                float re = 0, im = 0;
                #pragma unroll
                for (int p = 0; p < 8; p++) {
                    float2 w = w8[(v * p) & 7];
                    re += f[p].x * w.x - f[p].y * w.y;
                    im += f[p].x * w.y + f[p].y * w.x;
                }
                sF[(v * 8 + s) * 66 + c] = make_float2(re * t.x - im * t.y,
                                                       re * t.y + im * t.x);
                float tx = t.x * ws.x - t.y * ws.y;
                t.y = t.x * ws.y + t.y * ws.x; t.x = tx;
            }
        }
        float2 a[2][8];
        #pragma unroll
        for (int half = 0; half < 2; half++) {
            int v = q + 4 * half;
            #pragma unroll
            for (int s = 0; s < 8; s++) a[half][s] = sF[(v * 8 + s) * 66 + c];
        }
        #pragma unroll
        for (int half = 0; half < 2; half++) {
            int v = q + 4 * half;
            #pragma unroll
            for (int u = 0; u < 8; u++) {
                float re = 0;
                #pragma unroll
                for (int s = 0; s < 8; s++) {
                    float2 w = w8[(u * s) & 7];
                    re += a[half][s].x * w.x - a[half][s].y * w.y;
                }
                float val = re + bo;
                dst[(8 * u + v) * 64 + c] = val;
                s_acc += val;
                q_acc += val * val;
            }
        }
    }
    // fused BN stats: block reduce + 2 atomics (replaces k_bn_stats pass)
    __syncthreads();
    float* rs = (float*)sF;
    rs[tid] = s_acc;
    rs[TPB + tid] = q_acc;
    __syncthreads();
    for (int st = TPB / 2; st > 0; st >>= 1) {
        if (tid < st) { rs[tid] += rs[tid + st]; rs[TPB + tid] += rs[TPB + tid + st]; }
        __syncthreads();
    }
    if (tid == 0) {
        atomicAdd(&stats[o * 2], rs[0]);
        atomicAdd(&stats[o * 2 + 1], rs[TPB]);
    }
}

__global__ void k_final(const float* __restrict__ y, const float* __restrict__ stats,
                        const float* __restrict__ gamma, const float* __restrict__ beta,
                        float* __restrict__ out) {
    int t = blockIdx.x * TPB + threadIdx.x;
    if (t >= kB * kF2 * 4096) return;
    int zo = t >> 12, o = zo % kF2;
    const float inv = 1.0f / 524288.0f;
    float mean = stats[o * 2] * inv;
    float var = stats[o * 2 + 1] * inv - mean * mean;
    float rstd = rsqrtf(var + 1e-5f);
    float ga = gamma[o], be = beta[o];
    const float* p = y + (size_t)t * 64;
    float acc = 0;
    for (int g = 0; g < 64; g++) {
        float v = (p[g] - mean) * rstd * ga + be;
        acc += v > 0.f ? v : 0.f;
    }
    out[t] = acc * (1.0f / 64.0f);
}

// ---------------------------------------------------------------------------
extern "C" void kernel_launch(void* const* d_in, const int* in_sizes, int n_in,
                              void* d_out, int out_size, void* d_ws, size_t ws_size,
                              hipStream_t stream) {
    const float* x     = (const float*)d_in[0];
    const float* k1    = (const float*)d_in[1];
    const float* bias1 = (const float*)d_in[2];
    const float* g1    = (const float*)d_in[3];
    const float* be1   = (const float*)d_in[4];
    const float* k2    = (const float*)d_in[5];
    const float* bias2 = (const float*)d_in[6];
    const float* g2    = (const float*)d_in[7];
    const float* be2   = (const float*)d_in[8];
    const float* k3    = (const float*)d_in[9];
    const float* bias3 = (const float*)d_in[10];
    const float* g3    = (const float*)d_in[11];
    const float* be3   = (const float*)d_in[12];

    char* ws = (char*)d_ws;
    size_t off = 0;
    auto alloc = [&](size_t bytes) {
        size_t cur = off;
        off = (off + bytes + 255) & ~(size_t)255;
        return cur;
    };
    size_t o_const = alloc(g_tab.bytes);                       // 3.0 MB
    size_t o_dqz   = alloc((size_t)kNM * 64 * 64 * 4);         // 16.8 MB
    size_t o_dqtw  = alloc((size_t)64 * kNMN * 4);             // 11.2 MB
    size_t o_deTp  = alloc((size_t)4 * 11424 * 4);             // 0.18 MB (padded, full)
    size_t o_khat  = alloc((size_t)kF1 * kF1 * 64 * 8);        // 1.8 MB
    size_t o_xf1   = alloc((size_t)kB * kF0 * 64 * 64 * 8);    // 0.2 MB
    size_t o_fh1   = alloc((size_t)kNM * kB * kF0 * 8);        // 0.05 MB
    size_t o_stats = alloc(2 * 64 * 4);
    size_t o_fh    = alloc((size_t)kB * kF1 * kNMN * 8);       // 42 MB (fh, then zs)
    size_t o_scr   = alloc((size_t)kFCH * kTfP * 8);           // 43.3 MB (dtmp/xf/G/T)
    size_t o_cube  = alloc((size_t)kB * kF1 * kCube * 4);      // 126 MB
    if (off > ws_size) return;

    const float* cb = (const float*)(ws + o_const);
    const float2* twf = (const float2*)(cb + g_tab.o_twf);
    const float2* twi = (const float2*)(cb + g_tab.o_twi);
    const float* w_t = cb + g_tab.o_w;
    const float* etab = cb + g_tab.o_etab;
    const float* dehalf = etab + (size_t)(8 + 4) * kNMN;  // G_4 = E0^32 = d(pi/2)
    const int* lmn_l = (const int*)(cb + g_tab.o_lmnl);
    const int* lm_l = (const int*)(cb + g_tab.o_lml);
    const int* lmn2 = (const int*)(cb + g_tab.o_lmn2);
    const int* lmq = (const int*)(cb + g_tab.o_lmq);
    const int* off4 = (const int*)(cb + g_tab.o_off4);

    float* dqz = (float*)(ws + o_dqz);
    float* dqtw = (float*)(ws + o_dqtw);
    float* deTp = (float*)(ws + o_deTp);
    float2* khat = (float2*)(ws + o_khat);
    float2* xf1 = (float2*)(ws + o_xf1);
    float2* fh1 = (float2*)(ws + o_fh1);
    float* stats = (float*)(ws + o_stats);
    float2* fh = (float2*)(ws + o_fh);
    float2* zsb = (float2*)(ws + o_fh);
    float* dtmp = (float*)(ws + o_scr);
    float2* Gb = (float2*)(ws + o_scr);
    float2* xfc = (float2*)(ws + o_scr);
    float2* Tb = (float2*)(ws + o_scr);
    float* cube = (float*)(ws + o_cube);

    hipMemcpyAsync(ws + o_const, g_tab.blob.data(), g_tab.bytes,
                   hipMemcpyHostToDevice, stream);
    hipMemsetAsync(dqz, 0, (size_t)kNM * 64 * 64 * 4, stream);
    hipMemsetAsync(deTp, 0, (size_t)4 * 11424 * 4, stream);
    k_gendqA<<<kLMAX * 64, TPB, 0, stream>>>(etab, dtmp);
    k_scat<<<kLMAX * 63, TPB, 0, stream>>>(dtmp, w_t, dqz, dqtw);
    k_transde_p<<<(kNMN + TPB - 1) / TPB, TPB, 0, stream>>>(dehalf, deTp, lmn_l, off4);

    const float S2S = 1.0f / sqrtf(64.0f * 3.0f * 1024.0f);
    const float SO3S = 1.0f / sqrtf(64.0f * 60.0f);
    auto blks = [](size_t n) { return (int)((n + TPB - 1) / TPB); };

    auto synth = [&](const float* bi, int Fo) {
        hipMemsetAsync(stats, 0, 2 * 64 * 4, stream);
        int planes = kB * Fo;
        for (int zo0 = 0; zo0 < planes; zo0 += kFCH) {
            int nzo = planes - zo0 < kFCH ? planes - zo0 : kFCH;
            k_synA<<<dim3(33, nzo), TPB, 0, stream>>>(
                zsb + (size_t)zo0 * kNMN, dqz, Tb);
            k_synB<<<nzo * 64, TPB, 0, stream>>>(Tb, twi, bi, cube, stats, Fo, zo0);
        }
    };

    // ---- Layer 1: S2 conv -> cube ----
    k_khat<<<blks(kF0 * kF1 * 64), TPB, 0, stream>>>(k1, khat, twf, kF0 * kF1 * 64, S2S);
    k_fft1<<<blks(kB * kF0 * 64 * 64), TPB, 0, stream>>>(x, xf1, twf);
    k_fh1<<<blks(kNM * kB * kF0), TPB, 0, stream>>>(xf1, dqtw, lm_l, fh1);
    k_zs1<<<blks((size_t)(kF1 / 6) * kNMN2), TPB, 0, stream>>>(fh1, khat, dehalf,
                                                               lmn_l, lmn2, zsb);
    synth(bias1, kF1);

    // ---- Layers 2 & 3: SO3 conv; fft2 applies previous layer's BN+ReLU ----
    for (int layer = 2; layer <= 3; layer++) {
        int Fo = (layer == 2) ? kF1 : kF2;
        const float* kk = (layer == 2) ? k2 : k3;
        const float* bi = (layer == 2) ? bias2 : bias3;
        const float* gp = (layer == 2) ? g1 : g2;
        const float* bp = (layer == 2) ? be1 : be2;
        k_khat<<<blks(kF1 * Fo * 64), TPB, 0, stream>>>(kk, khat, twf, kF1 * Fo * 64, SO3S);
        for (int zf0 = 0; zf0 < kB * kF1; zf0 += kFCH) {
            int nzf = kB * kF1 - zf0 < kFCH ? kB * kF1 - zf0 : kFCH;
            k_fft2<<<nzf * 64, TPB, 0, stream>>>(cube + (size_t)zf0 * kCube, xfc,
                                                 twf, stats, gp, bp, zf0);
            k_fh3<<<2048, TPB, 0, stream>>>(xfc, dqtw, fh + (size_t)zf0 * kNMN, nzf);
        }
        {
            int total = kB * kF1 * kNQ2;
            k_G4<<<blks(total), TPB, 0, stream>>>(fh, deTp, lmq, off4, Gb, total);
        }
        if (layer == 2) {
            int nOg = kF1 / 3;
            int CHb = (kCH2 * nOg + 7) / 8;
            k_zs_v4<60, 60><<<8 * CHb, TPB, 0, stream>>>(Gb, khat, lmn_l, lmn2, zsb);
        } else {
            int nOg = kF2 / 3;
            int CHb = (kCH2 * nOg + 7) / 8;
            k_zs_v4<60, 36><<<8 * CHb, TPB, 0, stream>>>(Gb, khat, lmn_l, lmn2, zsb);
        }
        synth(bi, Fo);
        if (layer == 3)
            k_final<<<blks(kB * kF2 * 4096), TPB, 0, stream>>>(cube, stats, g3, be3, (float*)d_out);
    }
}

// Round 16
// 1534.167 us; speedup vs baseline: 1.3027x; 1.0730x over previous
//
#include <hip/hip_runtime.h>
#include <cmath>
#include <cstring>
#include <cstdint>
#include <vector>

#define TPB 256
static constexpr int kLMAX = 32;
static constexpr int kNMN  = 43680;   // sum_{l<32} (2l+1)^2
static constexpr int kNMN2 = 22352;   // sum_{l<32} (l+1)(2l+1)  (m>=0 rows only)
static constexpr int kNM   = 1024;    // sum_{l<32} (2l+1)
static constexpr int kNQ2  = 5848;    // sum_{l<32} (l+1)*ceil((2l+1)/4)
static constexpr int kB    = 2;
static constexpr int kF0   = 3, kF1 = 60, kF2 = 36;
static constexpr int kCube = 262144;  // 64^3
static constexpr int kFCHMAX = 60;    // max plane chunk (adaptive: 60 or 40)
static constexpr int kXfP  = 131072;  // xf plane: 64 beta x 32 mu x 64 nu float2
static constexpr int kTfP  = 135168;  // T plane: 33 mu x 64 j x 64 g float2
static constexpr int kCH2  = (kNMN2 + 255) / 256;   // 88 lmn2-chunks of 256

__host__ __device__ inline int off3i(int l) { return l * (4 * l * l - 1) / 3; }

// ---------------------------------------------------------------------------
// Host-side constant tables (~3.0 MB seeds; d_b = F_{b&7} * G_{b>>3}).
// Hermitian dead-code note: synA (mu<=32) only reads zs rows with m>=0, so
// the zs/G/fh chain is computed ONLY for mi>=l (lmn2/lmq tables below), and
// fh3/fft2 only produce the mu in [0,31] half of the spectrum. xf/T planes
// are stored COMPACT (32/33 rows); chunk size adapts to the workspace.
// ---------------------------------------------------------------------------
static void h_matmul(const std::vector<double>& A, const std::vector<double>& B,
                     std::vector<double>& C, int n) {
    C.assign((size_t)n * n, 0.0);
    for (int i = 0; i < n; i++)
        for (int k = 0; k < n; k++) {
            double a = A[(size_t)i * n + k];
            if (a == 0.0) continue;
            const double* bp = &B[(size_t)k * n];
            double* cp = &C[(size_t)i * n];
            for (int j = 0; j < n; j++) cp[j] += a * bp[j];
        }
}

struct HostTables {
    std::vector<float> blob;
    size_t o_twf, o_twi, o_w, o_lmnl, o_lml, o_lmn2, o_lmq, o_off4, o_etab;
    size_t bytes;
    HostTables() {
        size_t n = 0;
        o_twf = n;  n += 128;
        o_twi = n;  n += 128;
        o_w = n;    n += 64;
        o_lmnl = n; n += kNMN;
        o_lml = n;  n += kNM;
        o_lmn2 = n; n += kNMN2;
        o_lmq = n;  n += kNQ2;
        o_off4 = n; n += 32;
        o_etab = n; n += (size_t)16 * kNMN;    // [F_0..F_7, G_0..G_7] per l
        blob.assign(n, 0.0f);
        bytes = n * 4;

        for (int k = 0; k < 64; k++) {
            double th = -2.0 * M_PI * k / 64.0;
            blob[o_twf + 2 * k]     = (float)cos(th);
            blob[o_twf + 2 * k + 1] = (float)sin(th);
            blob[o_twi + 2 * k]     = (float)cos(th);
            blob[o_twi + 2 * k + 1] = (float)(-sin(th));
        }
        for (int j = 0; j < 64; j++) {
            double s = 0;
            for (int k = 0; k < 32; k++)
                s += sin((2.0 * j + 1) * (2.0 * k + 1) * M_PI / 128.0) / (2.0 * k + 1);
            blob[o_w + j] = (float)(2.0 / 32.0 * sin(M_PI * (2.0 * j + 1) / 128.0) * s);
        }
        // lmn2: compact index of (l, mi>=l, ni) -> original lmn offset.
        {
            int qi = 0;
            for (int l = 0; l < kLMAX; l++) {
                int R = 2 * l + 1, o3 = off3i(l);
                for (int mi = l; mi < R; mi++)
                    for (int ni = 0; ni < R; ni++) {
                        int32_t v = o3 + mi * R + ni;
                        memcpy(&blob[o_lmn2 + qi], &v, 4);
                        qi++;
                    }
            }
        }
        // q -> (l, mi>=l, n0) table for n4-blocked k_G4, and padded-deT offsets.
        {
            int qi = 0, acc4 = 0;
            for (int l = 0; l < kLMAX; l++) {
                int R = 2 * l + 1, Rp = (R + 3) & ~3, C = Rp >> 2;
                int32_t o4 = acc4;
                memcpy(&blob[o_off4 + l], &o4, 4);
                for (int m = l; m < R; m++)
                    for (int c = 0; c < C; c++) {
                        int32_t pk = l | (m << 5) | ((4 * c) << 11);
                        memcpy(&blob[o_lmq + qi], &pk, 4);
                        qi++;
                    }
                acc4 += R * Rp;
            }
        }
        std::vector<double> A, Eh, E0, E08, F, G, term, tmp;
        for (int l = 0; l < kLMAX; l++) {
            int R = 2 * l + 1, o3 = off3i(l);
            A.assign((size_t)R * R, 0.0);
            for (int i = 0; i + 1 < R; i++) {
                double m = (double)i - l;
                double c = sqrt((double)l * (l + 1) - m * (m + 1));
                A[(size_t)(i + 1) * R + i] = -(M_PI / 128.0) * c * 0.5;
                A[(size_t)i * R + (i + 1)] =  (M_PI / 128.0) * c * 0.5;
            }
            Eh.assign((size_t)R * R, 0.0);
            for (int i = 0; i < R; i++) Eh[(size_t)i * R + i] = 1.0;
            term = Eh;
            for (int k = 1; k <= 30; k++) {
                h_matmul(term, A, tmp, R);
                for (auto& v : tmp) v /= k;
                term = tmp;
                for (size_t i = 0; i < (size_t)R * R; i++) Eh[i] += term[i];
            }
            h_matmul(Eh, Eh, E0, R);
            h_matmul(E0, E0, tmp, R);
            h_matmul(tmp, tmp, E08, R);
            h_matmul(E08, E08, tmp, R); E08 = tmp;  // E0^8
            F = Eh;
            for (int lo = 0; lo < 8; lo++) {
                for (int r = 0; r < R * R; r++)
                    blob[o_etab + (size_t)lo * kNMN + o3 + r] = (float)F[r];
                if (lo < 7) { h_matmul(F, E0, tmp, R); F = tmp; }
            }
            G.assign((size_t)R * R, 0.0);
            for (int i = 0; i < R; i++) G[(size_t)i * R + i] = 1.0;
            for (int hi = 0; hi < 8; hi++) {
                for (int r = 0; r < R * R; r++)
                    blob[o_etab + (size_t)(8 + hi) * kNMN + o3 + r] = (float)G[r];
                if (hi < 7) { h_matmul(G, E08, tmp, R); G = tmp; }
            }
            int32_t li = l;
            for (int r = 0; r < R * R; r++) memcpy(&blob[o_lmnl + o3 + r], &li, 4);
            for (int m = 0; m < R; m++)    memcpy(&blob[o_lml + (size_t)l * l + m], &li, 4);
        }
    }
};
static HostTables g_tab;

// ---------------------------------------------------------------------------
__global__ __launch_bounds__(TPB) void k_gendqA(const float* __restrict__ etab,
                                                float* __restrict__ dtmp) {
    __shared__ float Fm[3969];
    __shared__ float Gm[63 * 64];
    int l = blockIdx.x >> 6, b = blockIdx.x & 63;
    int lo = b & 7, hi = b >> 3;
    int R = 2 * l + 1, RR = R * R, o3 = off3i(l);
    int tid = threadIdx.x;
    const float* Fsrc = etab + (size_t)lo * kNMN + o3;
    const float* Gsrc = etab + (size_t)(8 + hi) * kNMN + o3;
    for (int i = tid; i < RR; i += TPB) Fm[i] = Fsrc[i];
    for (int i = tid; i < R * 64; i += TPB) {
        int k = i >> 6, c = i & 63;
        Gm[i] = (c < R) ? Gsrc[k * R + c] : 0.f;
    }
    __syncthreads();
    int Gc = (R + 15) >> 4;
    if (tid < R * Gc) {
        int row = tid / Gc, g = tid - row * Gc;
        float4 A0 = make_float4(0,0,0,0), A1 = A0, A2 = A0, A3 = A0;
        const float* fr = Fm + row * R;
        for (int k = 0; k < R; k++) {
            float a = fr[k];
            const float4* gp = (const float4*)(Gm + (k << 6) + (g << 4));
            float4 q0 = gp[0], q1 = gp[1], q2 = gp[2], q3 = gp[3];
            A0.x += a * q0.x; A0.y += a * q0.y; A0.z += a * q0.z; A0.w += a * q0.w;
            A1.x += a * q1.x; A1.y += a * q1.y; A1.z += a * q1.z; A1.w += a * q1.w;
            A2.x += a * q2.x; A2.y += a * q2.y; A2.z += a * q2.z; A2.w += a * q2.w;
            A3.x += a * q3.x; A3.y += a * q3.y; A3.z += a * q3.z; A3.w += a * q3.w;
        }
        float v[16] = {A0.x,A0.y,A0.z,A0.w, A1.x,A1.y,A1.z,A1.w,
                       A2.x,A2.y,A2.z,A2.w, A3.x,A3.y,A3.z,A3.w};
        float* dst = dtmp + (size_t)o3 * 64 + (size_t)b * RR + row * R;
        int c0 = g << 4;
        #pragma unroll
        for (int e = 0; e < 16; e++)
            if (c0 + e < R) dst[c0 + e] = v[e];
    }
}

__global__ __launch_bounds__(TPB) void k_scat(const float* __restrict__ dtmp,
                                              const float* __restrict__ w,
                                              float* __restrict__ dqz,
                                              float* __restrict__ dqtw) {
    __shared__ float S[64 * 65];
    int l = blockIdx.x / 63, tile = blockIdx.x % 63;
    int R = 2 * l + 1, RR = R * R, o3 = off3i(l);
    int i0 = tile * 64;
    if (i0 >= RR) return;
    int tid = threadIdx.x;
    const float* src = dtmp + (size_t)o3 * 64;
    #pragma unroll
    for (int s = 0; s < 16; s++) {
        int idx = tid + s * TPB;
        int b = idx >> 6, ii = idx & 63;
        int i = i0 + ii;
        S[ii * 65 + b] = (i < RR) ? src[(size_t)b * RR + i] : 0.f;
    }
    __syncthreads();
    float Rf = (float)R;
    #pragma unroll
    for (int s = 0; s < 16; s++) {
        int idx = tid + s * TPB;
        int ii = idx >> 6, b = idx & 63;
        int i = i0 + ii;
        if (i < RR) {
            float v = S[ii * 65 + b];
            dqtw[((size_t)o3 + i) * 64 + b] = w[b] * v;
            int mi = i / R, ni = i - mi * R;
            int nu = (ni - l) & 63;
            dqz[((size_t)(l * l + mi) * 64 + nu) * 64 + b] = Rf * v;
        }
    }
}

// Builds padded-row deTp: deTp[off4(l) + k*Rp + n] = dehalf[o3 + n*R + k],
// Rp = ceil(R/4)*4. Pad entries stay zero (memset upstream).
__global__ void k_transde_p(const float* __restrict__ dehalf, float* __restrict__ deTp,
                            const int* __restrict__ lmn_l, const int* __restrict__ off4) {
    int t = blockIdx.x * TPB + threadIdx.x;
    if (t >= kNMN) return;
    int l = lmn_l[t], o3 = off3i(l), r = t - o3, R = 2 * l + 1;
    int Rp = (R + 3) & ~3;
    int n = r / R, k = r - n * R;
    deTp[off4[l] + k * Rp + n] = dehalf[t];
}

__global__ void k_khat(const float* __restrict__ kern, float2* __restrict__ khat,
                       const float2* __restrict__ twf, int total, float scale) {
    int t = blockIdx.x * TPB + threadIdx.x;
    if (t >= total) return;
    int nu = t & 63, fo = t >> 6;
    const float* row = kern + (size_t)fo * 64;
    float re = 0, im = 0;
    for (int p = 0; p < 64; p++) {
        float2 w = twf[(p * nu) & 63];
        float v = row[p];
        re += v * w.x; im += v * w.y;
    }
    khat[t] = make_float2(re * scale, im * scale);
}

__global__ void k_fft1(const float* __restrict__ x, float2* __restrict__ xf1,
                       const float2* __restrict__ twf) {
    int t = blockIdx.x * TPB + threadIdx.x;
    if (t >= kB * kF0 * 64 * 64) return;
    int mu = t & 63, row = t >> 6;
    const float* p = x + (size_t)row * 64;
    float re = 0, im = 0;
    for (int a = 0; a < 64; a++) {
        float2 w = twf[(a * mu) & 63];
        float v = p[a];
        re += v * w.x; im += v * w.y;
    }
    xf1[t] = make_float2(re, im);
}

__global__ void k_fh1(const float2* __restrict__ xf1, const float* __restrict__ dqtw,
                      const int* __restrict__ lm_l, float2* __restrict__ fh1) {
    int t = blockIdx.x * TPB + threadIdx.x;
    if (t >= kNM * kB * kF0) return;
    int lm = t / 6, rem = t % 6, z = rem / 3, f = rem % 3;
    int l = lm_l[lm], m = lm - l * l, R = 2 * l + 1, o3 = off3i(l);
    int mu = (m - l) & 63;
    const float4* wq = (const float4*)(dqtw + (size_t)o3 * 64 + (size_t)(m * R + l) * 64);
    const float2* xr = xf1 + (size_t)((z * 3 + f) * 64) * 64 + mu;
    float re0 = 0, im0 = 0, re1 = 0, im1 = 0;
    #pragma unroll
    for (int b4 = 0; b4 < 16; b4++) {
        float4 w4 = wq[b4];
        float2 v0 = xr[(4 * b4 + 0) * 64];
        float2 v1 = xr[(4 * b4 + 1) * 64];
        float2 v2 = xr[(4 * b4 + 2) * 64];
        float2 v3 = xr[(4 * b4 + 3) * 64];
        re0 += w4.x * v0.x + w4.y * v1.x; im0 += w4.x * v0.y + w4.y * v1.y;
        re1 += w4.z * v2.x + w4.w * v3.x; im1 += w4.z * v2.y + w4.w * v3.y;
    }
    const float C2 = 1.0f / 128.0f;
    fh1[t] = make_float2((re0 + re1) * C2, (im0 + im1) * C2);
}

// Layer-1 zs restricted to lmn2 (mi>=l): synA never reads m<0 rows.
__global__ void k_zs1(const float2* __restrict__ fh1, const float2* __restrict__ khat,
                      const float* __restrict__ dehalf, const int* __restrict__ lmn_l,
                      const int* __restrict__ lmn2, float2* __restrict__ zs) {
    int nOg = kF1 / 6;                       // 10
    int t = blockIdx.x * TPB + threadIdx.x;  // og*NMN2 + i2
    if (t >= nOg * kNMN2) return;
    int i2 = t % kNMN2, og = t / kNMN2;
    int lmn = lmn2[i2];
    int l = lmn_l[lmn], o3 = off3i(l), r = lmn - o3, R = 2 * l + 1;
    int m = r / R, n = r - m * R;
    int nu = (n - l) & 63;
    float de1 = dehalf[o3 + n * R + l];
    int o0 = og * 6;
    const float2* fp = fh1 + (size_t)(l * l + m) * 6;
    const float2* kp = khat + (size_t)o0 * 64 + nu;
    float2 c0[6], c1[6];
    #pragma unroll
    for (int i = 0; i < 6; i++) {
        c0[i] = make_float2(0.f, 0.f);
        c1[i] = make_float2(0.f, 0.f);
    }
    #pragma unroll
    for (int f = 0; f < kF0; f++) {
        float2 a0 = fp[f];       // z = 0
        float2 a1 = fp[3 + f];   // z = 1
        const float2* kf = kp + (size_t)f * kF1 * 64;
        #pragma unroll
        for (int i = 0; i < 6; i++) {
            float2 b = kf[(size_t)i * 64];   // conj applied below
            c0[i].x += a0.x * b.x + a0.y * b.y;
            c0[i].y += a0.y * b.x - a0.x * b.y;
            c1[i].x += a1.x * b.x + a1.y * b.y;
            c1[i].y += a1.y * b.x - a1.x * b.y;
        }
    }
    float2* zp0 = zs + (size_t)o0 * kNMN + lmn;
    float2* zp1 = zs + ((size_t)kF1 + o0) * kNMN + lmn;
    #pragma unroll
    for (int i = 0; i < 6; i++) {
        zp0[(size_t)i * kNMN] = make_float2(c0[i].x * de1, c0[i].y * de1);
        zp1[(size_t)i * kNMN] = make_float2(c1[i].x * de1, c1[i].y * de1);
    }
}

// 2D forward DFT (radix-8 x2) with fused BN+ReLU; float4 staging.
// HERMITIAN DCE (output): k_fh3 reads only mu in [0,31] -> pass-2 computes
// only u<4, and xf planes are stored COMPACT (32 mu rows, kXfP float2/zf).
// HERMITIAN (input): rows are REAL, so pass-1 output satisfies
// F[64-nu] = conj(F[nu]); pass-1 stage-2 computes nu<=32 and mirrors 33..63
// in LDS (intra-wave lockstep, same reliance as the cross-lane stage reads).
__global__ __launch_bounds__(TPB) void k_fft2(const float* __restrict__ y,
                                              float2* __restrict__ xf,
                                              const float2* __restrict__ twf_g,
                                              const float* __restrict__ stats,
                                              const float* __restrict__ gamma,
                                              const float* __restrict__ beta,
                                              int zf0) {
    __shared__ float sIn[64 * 65];
    __shared__ float2 sMid[64 * 66];
    __shared__ float2 tw[64];
    int blk = blockIdx.x, tid = threadIdx.x;
    if (tid < 64) tw[tid] = twf_g[tid];
    int o = (zf0 + (blk >> 6)) % kF1;
    const float inv = 1.0f / 524288.0f;
    float mean = stats[o * 2] * inv;
    float var = stats[o * 2 + 1] * inv - mean * mean;
    float rstd = rsqrtf(var + 1e-5f);
    float ga = gamma[o], be = beta[o];
    const float4* src4 = (const float4*)(y + (size_t)blk * 4096);
    for (int i = tid; i < 1024; i += TPB) {
        float4 v4 = src4[i];
        int row = i >> 4, col = (i & 15) << 2;
        float* d = sIn + row * 65 + col;
        float a0 = (v4.x - mean) * rstd * ga + be;
        float a1 = (v4.y - mean) * rstd * ga + be;
        float a2 = (v4.z - mean) * rstd * ga + be;
        float a3 = (v4.w - mean) * rstd * ga + be;
        d[0] = a0 > 0.f ? a0 : 0.f;
        d[1] = a1 > 0.f ? a1 : 0.f;
        d[2] = a2 > 0.f ? a2 : 0.f;
        d[3] = a3 > 0.f ? a3 : 0.f;
    }
    __syncthreads();
    float2 w8[8];
    #pragma unroll
    for (int k = 0; k < 8; k++) w8[k] = tw[k * 8];
    int r2 = tid >> 2, q = tid & 3;
    {   // dim-1: g -> nu, REAL input
        const float* rowp = sIn + r2 * 65;
        float2* mrow = sMid + r2 * 66;
        #pragma unroll
        for (int half = 0; half < 2; half++) {
            int s = q + 4 * half;
            float f[8];
            #pragma unroll
            for (int p = 0; p < 8; p++) f[p] = rowp[8 * p + s];
            float2 ws = tw[s];
            float2 t = make_float2(1.f, 0.f);
            #pragma unroll
            for (int v = 0; v < 8; v++) {
                float re = 0, im = 0;
                #pragma unroll
                for (int p = 0; p < 8; p++) {
                    float2 w = w8[(v * p) & 7];
                    re += f[p] * w.x; im += f[p] * w.y;
                }
                mrow[v * 8 + s] = make_float2(re * t.x - im * t.y, re * t.y + im * t.x);
                float tx = t.x * ws.x - t.y * ws.y;
                t.y = t.x * ws.y + t.y * ws.x; t.x = tx;
            }
        }
        float2 a[2][8];
        #pragma unroll
        for (int half = 0; half < 2; half++) {
            int v = q + 4 * half;
            #pragma unroll
            for (int s = 0; s < 8; s++) a[half][s] = mrow[v * 8 + s];
        }
        #pragma unroll
        for (int half = 0; half < 2; half++) {
            int v = q + 4 * half;
            #pragma unroll
            for (int u = 0; u < 4; u++) {   // nu = 8u+v in [0,31]
                float re = 0, im = 0;
                #pragma unroll
                for (int s = 0; s < 8; s++) {
                    float2 w = w8[(u * s) & 7];
                    re += a[half][s].x * w.x - a[half][s].y * w.y;
                    im += a[half][s].x * w.y + a[half][s].y * w.x;
                }
                mrow[8 * u + v] = make_float2(re, im);
            }
        }
        if (q == 0) {   // nu = 32 (u=4, v=0): only the half=0, v=0 slot
            float re = 0, im = 0;
            #pragma unroll
            for (int s = 0; s < 8; s++) {
                float2 w = w8[(4 * s) & 7];
                re += a[0][s].x * w.x - a[0][s].y * w.y;
                im += a[0][s].x * w.y + a[0][s].y * w.x;
            }
            mrow[32] = make_float2(re, im);
        }
        // mirror nu = 33..63: F[nu] = conj(F[64-nu]) (real input rows).
        for (int nu = 33 + q; nu < 64; nu += 4) {
            float2 vv = mrow[64 - nu];
            mrow[nu] = make_float2(vv.x, -vv.y);
        }
    }
    __syncthreads();
    {   // dim-2: a -> mu per column c; only mu < 32 needed downstream
        int c = r2;
        float2* dst = xf + (size_t)blk * 2048;   // compact 32-row plane slice
        #pragma unroll
        for (int half = 0; half < 2; half++) {
            int s = q + 4 * half;
            float2 f[8];
            #pragma unroll
            for (int p = 0; p < 8; p++) f[p] = sMid[(8 * p + s) * 66 + c];
            float2 ws = tw[s];
            float2 t = make_float2(1.f, 0.f);
            #pragma unroll
            for (int v = 0; v < 8; v++) {
                float re = 0, im = 0;
                #pragma unroll
                for (int p = 0; p < 8; p++) {
                    float2 w = w8[(v * p) & 7];
                    re += f[p].x * w.x - f[p].y * w.y;
                    im += f[p].x * w.y + f[p].y * w.x;
                }
                sMid[(v * 8 + s) * 66 + c] = make_float2(re * t.x - im * t.y,
                                                         re * t.y + im * t.x);
                float tx = t.x * ws.x - t.y * ws.y;
                t.y = t.x * ws.y + t.y * ws.x; t.x = tx;
            }
        }
        float2 a[2][8];
        #pragma unroll
        for (int half = 0; half < 2; half++) {
            int v = q + 4 * half;
            #pragma unroll
            for (int s = 0; s < 8; s++) a[half][s] = sMid[(v * 8 + s) * 66 + c];
        }
        #pragma unroll
        for (int half = 0; half < 2; half++) {
            int v = q + 4 * half;
            #pragma unroll
            for (int u = 0; u < 4; u++) {   // mu = 8u+v in [0,31] only
                float re = 0, im = 0;
                #pragma unroll
                for (int s = 0; s < 8; s++) {
                    float2 w = w8[(u * s) & 7];
                    re += a[half][s].x * w.x - a[half][s].y * w.y;
                    im += a[half][s].x * w.y + a[half][s].y * w.x;
                }
                dst[(8 * u + v) * 64 + c] = make_float2(re, im);
            }
        }
    }
}

// fh3: one block per (mu,nu) column, mu in [0..31] ONLY (m>=0 rows; the m<0
// half of fh is dead code downstream). X and dqtw staged once in LDS.
// xf planes are compact (32 rows, kXfP float2/zf). nzf up to kFCHMAX=60.
// XCD swizzle in 256-block chunks keeps nu-adjacent blocks on one L2.
__global__ __launch_bounds__(TPB) void k_fh3(const float2* __restrict__ xf,
                                             const float* __restrict__ dqtw,
                                             float2* __restrict__ fh_out, int nzf) {
    __shared__ float2 sX[kFCHMAX * 66];  // [zf][b], row stride 66 float2
    __shared__ float  sD[32 * 68];       // [li][b], row stride 68 floats
    int v = blockIdx.x;                  // 2048 blocks
    int wg = (v & 7) * 256 + (v >> 3);
    int nu = wg & 63, mu = wg >> 6;      // mu in [0,31] -> mt = mu >= 0
    int mt = mu;
    int nt = (nu <= 31) ? nu : nu - 64;
    int am = mu, an = nt < 0 ? -nt : nt;
    int lmin = am > an ? am : an;
    if (lmin >= kLMAX) return;
    int nl = kLMAX - lmin;
    int tid = threadIdx.x;
    for (int i = tid; i < nzf * 64; i += TPB) {
        int zf = i >> 6, b = i & 63;
        sX[zf * 66 + b] = xf[(size_t)zf * kXfP + (size_t)b * 2048 + mu * 64 + nu];
    }
    for (int i = tid; i < nl * 64; i += TPB) {
        int li = i >> 6, b = i & 63;
        int l = lmin + li, R = 2 * l + 1;
        int r = (mt + l) * R + (nt + l);
        sD[li * 68 + b] = dqtw[(size_t)(off3i(l) + r) * 64 + b];
    }
    __syncthreads();
    const float C3 = 1.0f / 8192.0f;
    int items = nzf * nl;
    for (int item = tid; item < items; item += TPB) {
        int zf = item / nl, li = item - zf * nl;
        const float4* D4 = (const float4*)(sD + li * 68);
        const float4* X4 = (const float4*)(sX + zf * 66);
        float re0 = 0, im0 = 0, re1 = 0, im1 = 0;
        #pragma unroll
        for (int b4 = 0; b4 < 16; b4++) {
            float4 d   = D4[b4];
            float4 x01 = X4[2 * b4];
            float4 x23 = X4[2 * b4 + 1];
            re0 += d.x * x01.x; im0 += d.x * x01.y;
            re0 += d.y * x01.z; im0 += d.y * x01.w;
            re1 += d.z * x23.x; im1 += d.z * x23.y;
            re1 += d.w * x23.z; im1 += d.w * x23.w;
        }
        int l = lmin + li, R = 2 * l + 1;
        int r = (mt + l) * R + (nt + l);
        fh_out[(size_t)zf * kNMN + off3i(l) + r] =
            make_float2((re0 + re1) * C3, (im0 + im1) * C3);
    }
}

// G (n4-blocked, mi>=l rows only): thread computes 4 consecutive n outputs.
// Per k: 1 float2 fh broadcast + 1 aligned float4 deTp row-load -> 16 lane-FMA.
__global__ void k_G4(const float2* __restrict__ fh, const float* __restrict__ deTp,
                     const int* __restrict__ lmq, const int* __restrict__ off4,
                     float2* __restrict__ G, int total) {
    int t = blockIdx.x * TPB + threadIdx.x;
    if (t >= total) return;
    int q = t % kNQ2, zf = t / kNQ2;
    int pk = lmq[q];
    int l = pk & 31, m = (pk >> 5) & 63, n0 = pk >> 11;
    int R = 2 * l + 1, o3 = off3i(l);
    int C4 = ((R + 3) & ~3) >> 2;            // Rp/4
    const float2* fr = fh + (size_t)zf * kNMN + o3 + m * R;
    const float4* dp = (const float4*)(deTp + off4[l] + n0);
    float4 re = make_float4(0.f, 0.f, 0.f, 0.f);
    float4 im = make_float4(0.f, 0.f, 0.f, 0.f);
    int k = 0;
    for (; k + 1 < R; k += 2) {
        float2 f0 = fr[k], f1 = fr[k + 1];
        float4 d0 = dp[(size_t)k * C4];
        float4 d1 = dp[(size_t)(k + 1) * C4];
        re.x += f0.x * d0.x + f1.x * d1.x; im.x += f0.y * d0.x + f1.y * d1.x;
        re.y += f0.x * d0.y + f1.x * d1.y; im.y += f0.y * d0.y + f1.y * d1.y;
        re.z += f0.x * d0.z + f1.x * d1.z; im.z += f0.y * d0.z + f1.y * d1.z;
        re.w += f0.x * d0.w + f1.x * d1.w; im.w += f0.y * d0.w + f1.y * d1.w;
    }
    {
        float2 f0 = fr[k];
        float4 d0 = dp[(size_t)k * C4];
        re.x += f0.x * d0.x; im.x += f0.y * d0.x;
        re.y += f0.x * d0.y; im.y += f0.y * d0.y;
        re.z += f0.x * d0.z; im.z += f0.y * d0.z;
        re.w += f0.x * d0.w; im.w += f0.y * d0.w;
    }
    float2* gp = G + (size_t)zf * kNMN + o3 + m * R + n0;
    int rem = R - n0;
    gp[0] = make_float2(re.x, im.x);
    if (rem > 1) gp[1] = make_float2(re.y, im.y);
    if (rem > 2) gp[2] = make_float2(re.z, im.z);
    if (rem > 3) gp[3] = make_float2(re.w, im.w);
}

// zs v4: og-tile 3; barrier-free body + og-fastest XCD-grouped decode +
// compile-time FIN/FO + unroll-4 f-loop; lmn2 (mi>=l) restricted.
template<int FIN, int FO>
__global__ __launch_bounds__(TPB) void k_zs_v4(const float2* __restrict__ G,
                                               const float2* __restrict__ khat,
                                               const int* __restrict__ lmn_l,
                                               const int* __restrict__ lmn2,
                                               float2* __restrict__ zs) {
    constexpr int NOG = FO / 3;
    int CHb = gridDim.x >> 3;
    int bid = blockIdx.x;
    int work = (bid & 7) * CHb + (bid >> 3);   // bijective; og-fastest
    if (work >= kCH2 * NOG) return;
    int x = work / NOG, og = work - x * NOG;
    int i2 = x * 256 + threadIdx.x;
    if (i2 >= kNMN2) return;
    int lmn = lmn2[i2];
    int l = lmn_l[lmn], r = lmn - off3i(l), R = 2 * l + 1;
    int n = r % R;
    int nu = (n - l) & 63;
    int o0 = og * 3;
    const float2* gp0 = G + lmn;
    const float2* gp1 = G + (size_t)FIN * kNMN + lmn;
    const float2* kp = khat + (size_t)o0 * 64 + nu;
    float2 c0[3], c1[3];
    #pragma unroll
    for (int i = 0; i < 3; i++) {
        c0[i] = make_float2(0.f, 0.f);
        c1[i] = make_float2(0.f, 0.f);
    }
    #pragma unroll 4
    for (int f = 0; f < FIN; f++) {
        float2 a0 = gp0[(size_t)f * kNMN];
        float2 a1 = gp1[(size_t)f * kNMN];
        const float2* kf = kp + (size_t)f * FO * 64;
        #pragma unroll
        for (int i = 0; i < 3; i++) {
            float2 b = kf[(size_t)i * 64];   // conj applied in the FMA signs
            c0[i].x += a0.x * b.x + a0.y * b.y;
            c0[i].y += a0.y * b.x - a0.x * b.y;
            c1[i].x += a1.x * b.x + a1.y * b.y;
            c1[i].y += a1.y * b.x - a1.x * b.y;
        }
    }
    float2* zp0 = zs + (size_t)o0 * kNMN + lmn;
    float2* zp1 = zs + ((size_t)FO + o0) * kNMN + lmn;
    #pragma unroll
    for (int i = 0; i < 3; i++) {
        zp0[(size_t)i * kNMN] = c0[i];
        zp1[(size_t)i * kNMN] = c1[i];
    }
}

// Synthesis stage A (1-plane blocks): grid = (33 mu) x (nzo planes); each
// block accumulates ONE zo plane into the COMPACT T plane (33 rows, kTfP
// float2/zo). Same per-output FMA order as before -> bitwise-same T.
// HERMITIAN: mu = 0..32 only; rows 33..63 derived in k_synB by conj-mirror.
__global__ __launch_bounds__(TPB) void k_synA(const float2* __restrict__ zs,
                                              const float* __restrict__ dqz,
                                              float2* __restrict__ T) {
    __shared__ float2 sZ[32 * 64];
    int mu = blockIdx.x, zo = blockIdx.y;
    int tid = threadIdx.x;
    int mt = (mu <= 31) ? mu : mu - 64;
    int am = mt < 0 ? -mt : mt;
    #pragma unroll
    for (int k = 0; k < 8; k++) {
        int i = tid + k * TPB;
        int nu = i & 63, l = i >> 6;
        int nt = (nu <= 31) ? nu : nu - 64;
        int an = nt < 0 ? -nt : nt;
        float2 v = make_float2(0.f, 0.f);
        if (l >= am && an <= l)
            v = zs[(size_t)zo * kNMN + off3i(l) +
                   (mt + l) * (2 * l + 1) + nt + l];
        sZ[i] = v;
    }
    __syncthreads();
    int j = tid & 63, s = tid >> 6;
    float2 c0[16];
    #pragma unroll
    for (int k = 0; k < 16; k++) c0[k] = make_float2(0.f, 0.f);
    for (int l = am; l < 32; l++) {
        const float* dp = dqz + ((size_t)(l * l + mt + l) * 64 + s * 16) * 64 + j;
        const float4* z04 = (const float4*)(sZ + (size_t)l * 64 + s * 16);
        #pragma unroll
        for (int h = 0; h < 8; h++) {
            float d0 = dp[(size_t)(2 * h) * 64];
            float d1 = dp[(size_t)(2 * h + 1) * 64];
            float4 za = z04[h];
            c0[2 * h].x     += d0 * za.x; c0[2 * h].y     += d0 * za.y;
            c0[2 * h + 1].x += d1 * za.z; c0[2 * h + 1].y += d1 * za.w;
        }
    }
    float2* t0 = T + (((size_t)zo * 33 + mu) * 64 + j) * 64 + s * 16;
    #pragma unroll
    for (int k = 0; k < 16; k++) t0[k] = c0[k];
}

// Synthesis stage B: radix-8 x2 IDFT; real + bias out; fused BN-stats atomics.
// Stages T rows mu=0..32 (compact kTfP planes); pass-1 (dim-nu) runs ONLY on
// those 33 rows with 8 threads/row; rows 33..63 derived by
// h[mu][g] = conj(h[64-mu][g]). Pass-2 unchanged.
__global__ __launch_bounds__(TPB) void k_synB(const float2* __restrict__ T,
                                              const float2* __restrict__ twi_g,
                                              const float* __restrict__ bias,
                                              float* __restrict__ yout,
                                              float* __restrict__ stats,
                                              int Fo, int zo0) {
    __shared__ float2 sF[64 * 66];
    __shared__ float2 tw[64];
    int blk = blockIdx.x;
    int zo_l = blk >> 6, j = blk & 63;
    int zo_g = zo0 + zo_l;
    int o = zo_g % Fo;
    int tid = threadIdx.x;
    if (tid < 64) tw[tid] = twi_g[tid];
    const float4* src4 = (const float4*)(T + (size_t)zo_l * kTfP + (size_t)j * 64);
    for (int i = tid; i < 1056; i += TPB) {      // mu = 0..32 direct
        int mu = i >> 5, half = i & 31;
        float4 v = src4[(size_t)mu * 2048 + half];
        sF[mu * 66 + 2 * half]     = make_float2(v.x, v.y);
        sF[mu * 66 + 2 * half + 1] = make_float2(v.z, v.w);
    }
    __syncthreads();
    float2 w8[8];
    #pragma unroll
    for (int k = 0; k < 8; k++) w8[k] = tw[k * 8];
    {   // pass 1 (dim-nu): rows 0..31 with 8 threads/row; row 32 on lanes 0..7
        int r8 = tid >> 3, q8 = tid & 7;
        float2* mrow = sF + r8 * 66;
        float2* mrow32 = sF + 32 * 66;
        {
            int s = q8;
            float2 f[8];
            #pragma unroll
            for (int p = 0; p < 8; p++) f[p] = mrow[8 * p + s];
            float2 ws = tw[s];
            float2 t = make_float2(1.f, 0.f);
            #pragma unroll
            for (int v = 0; v < 8; v++) {
                float re = 0, im = 0;
                #pragma unroll
                for (int p = 0; p < 8; p++) {
                    float2 w = w8[(v * p) & 7];
                    re += f[p].x * w.x - f[p].y * w.y;
                    im += f[p].x * w.y + f[p].y * w.x;
                }
                mrow[v * 8 + s] = make_float2(re * t.x - im * t.y, re * t.y + im * t.x);
                float tx = t.x * ws.x - t.y * ws.y;
                t.y = t.x * ws.y + t.y * ws.x; t.x = tx;
            }
        }
        if (tid < 8) {   // row 32 stage 1 (wave 0 lanes 0..7, lockstep)
            int s = tid;
            float2 f[8];
            #pragma unroll
            for (int p = 0; p < 8; p++) f[p] = mrow32[8 * p + s];
            float2 ws = tw[s];
            float2 t = make_float2(1.f, 0.f);
            #pragma unroll
            for (int v = 0; v < 8; v++) {
                float re = 0, im = 0;
                #pragma unroll
                for (int p = 0; p < 8; p++) {
                    float2 w = w8[(v * p) & 7];
                    re += f[p].x * w.x - f[p].y * w.y;
                    im += f[p].x * w.y + f[p].y * w.x;
                }
                mrow32[v * 8 + s] = make_float2(re * t.x - im * t.y, re * t.y + im * t.x);
                float tx = t.x * ws.x - t.y * ws.y;
                t.y = t.x * ws.y + t.y * ws.x; t.x = tx;
            }
        }
        {
            int v = q8;
            float2 a[8];
            #pragma unroll
            for (int s = 0; s < 8; s++) a[s] = mrow[v * 8 + s];
            #pragma unroll
            for (int u = 0; u < 8; u++) {
                float re = 0, im = 0;
                #pragma unroll
                for (int s = 0; s < 8; s++) {
                    float2 w = w8[(u * s) & 7];
                    re += a[s].x * w.x - a[s].y * w.y;
                    im += a[s].x * w.y + a[s].y * w.x;
                }
                mrow[8 * u + v] = make_float2(re, im);
            }
        }
        if (tid < 8) {   // row 32 stage 2
            int v = tid;
            float2 a[8];
            #pragma unroll
            for (int s = 0; s < 8; s++) a[s] = mrow32[v * 8 + s];
            #pragma unroll
            for (int u = 0; u < 8; u++) {
                float re = 0, im = 0;
                #pragma unroll
                for (int s = 0; s < 8; s++) {
                    float2 w = w8[(u * s) & 7];
                    re += a[s].x * w.x - a[s].y * w.y;
                    im += a[s].x * w.y + a[s].y * w.x;
                }
                mrow32[8 * u + v] = make_float2(re, im);
            }
        }
    }
    __syncthreads();
    for (int i = tid; i < 31 * 64; i += TPB) {   // rows 33..63: conj mirror in g
        int mu = 33 + (i >> 6), g = i & 63;
        float2 v = sF[(64 - mu) * 66 + g];
        sF[mu * 66 + g] = make_float2(v.x, -v.y);
    }
    __syncthreads();
    float s_acc = 0.f, q_acc = 0.f;
    int r2 = tid >> 2, q = tid & 3;
    {   // dim-mu, per column c; real + bias out
        int c = r2;
        float bo = bias[o];
        float* dst = yout + ((size_t)zo_g * 64 + j) * 4096;
        #pragma unroll
        for (int half = 0; half < 2; half++) {
            int s = q + 4 * half;
            float2 f[8];
            #pragma unroll
            for (int p = 0; p < 8; p++) f[p] = sF[(8 * p + s) * 66 + c];
            float2 ws = tw[s];
            float2 t = make_float2(1.f, 0.f);
            #pragma unroll
            for (int v = 0; v < 8; v++) {
                float re = 0, im = 0;
                #pragma unroll
                for (int p = 0; p < 8; p++) {
                    float2 w = w8[(v * p) & 7];
                    re += f[p].x * w.x - f[p].y * w.y;
                    im += f[p].x * w.y + f[p].y * w.x;
                }
                sF[(v * 8 + s) * 66 + c] = make_float2(re * t.x - im * t.y,
                                                       re * t.y + im * t.x);
                float tx = t.x * ws.x - t.y * ws.y;
                t.y = t.x * ws.y + t.y * ws.x; t.x = tx;
            }
        }
        float2 a[2][8];
        #pragma unroll
        for (int half = 0; half < 2; half++) {
            int v = q + 4 * half;
            #pragma unroll
            for (int s = 0; s < 8; s++) a[half][s] = sF[(v * 8 + s) * 66 + c];
        }
        #pragma unroll
        for (int half = 0; half < 2; half++) {
            int v = q + 4 * half;
            #pragma unroll
            for (int u = 0; u < 8; u++) {
                float re = 0;
                #pragma unroll
                for (int s = 0; s < 8; s++) {
                    float2 w = w8[(u * s) & 7];
                    re += a[half][s].x * w.x - a[half][s].y * w.y;
                }
                float val = re + bo;
                dst[(8 * u + v) * 64 + c] = val;
                s_acc += val;
                q_acc += val * val;
            }
        }
    }
    // fused BN stats: block reduce + 2 atomics (replaces k_bn_stats pass)
    __syncthreads();
    float* rs = (float*)sF;
    rs[tid] = s_acc;
    rs[TPB + tid] = q_acc;
    __syncthreads();
    for (int st = TPB / 2; st > 0; st >>= 1) {
        if (tid < st) { rs[tid] += rs[tid + st]; rs[TPB + tid] += rs[TPB + tid + st]; }
        __syncthreads();
    }
    if (tid == 0) {
        atomicAdd(&stats[o * 2], rs[0]);
        atomicAdd(&stats[o * 2 + 1], rs[TPB]);
    }
}

__global__ void k_final(const float* __restrict__ y, const float* __restrict__ stats,
                        const float* __restrict__ gamma, const float* __restrict__ beta,
                        float* __restrict__ out) {
    int t = blockIdx.x * TPB + threadIdx.x;
    if (t >= kB * kF2 * 4096) return;
    int zo = t >> 12, o = zo % kF2;
    const float inv = 1.0f / 524288.0f;
    float mean = stats[o * 2] * inv;
    float var = stats[o * 2 + 1] * inv - mean * mean;
    float rstd = rsqrtf(var + 1e-5f);
    float ga = gamma[o], be = beta[o];
    const float* p = y + (size_t)t * 64;
    float acc = 0;
    for (int g = 0; g < 64; g++) {
        float v = (p[g] - mean) * rstd * ga + be;
        acc += v > 0.f ? v : 0.f;
    }
    out[t] = acc * (1.0f / 64.0f);
}

// ---------------------------------------------------------------------------
extern "C" void kernel_launch(void* const* d_in, const int* in_sizes, int n_in,
                              void* d_out, int out_size, void* d_ws, size_t ws_size,
                              hipStream_t stream) {
    const float* x     = (const float*)d_in[0];
    const float* k1    = (const float*)d_in[1];
    const float* bias1 = (const float*)d_in[2];
    const float* g1    = (const float*)d_in[3];
    const float* be1   = (const float*)d_in[4];
    const float* k2    = (const float*)d_in[5];
    const float* bias2 = (const float*)d_in[6];
    const float* g2    = (const float*)d_in[7];
    const float* be2   = (const float*)d_in[8];
    const float* k3    = (const float*)d_in[9];
    const float* bias3 = (const float*)d_in[10];
    const float* g3    = (const float*)d_in[11];
    const float* be3   = (const float*)d_in[12];

    char* ws = (char*)d_ws;
    size_t off = 0;
    auto alloc = [&](size_t bytes) {
        size_t cur = off;
        off = (off + bytes + 255) & ~(size_t)255;
        return cur;
    };
    size_t o_const = alloc(g_tab.bytes);                       // 3.0 MB
    size_t o_dqz   = alloc((size_t)kNM * 64 * 64 * 4);         // 16.8 MB
    size_t o_dqtw  = alloc((size_t)64 * kNMN * 4);             // 11.2 MB
    size_t o_deTp  = alloc((size_t)4 * 11424 * 4);             // 0.18 MB (padded, full)
    size_t o_khat  = alloc((size_t)kF1 * kF1 * 64 * 8);        // 1.8 MB
    size_t o_xf1   = alloc((size_t)kB * kF0 * 64 * 64 * 8);    // 0.2 MB
    size_t o_fh1   = alloc((size_t)kNM * kB * kF0 * 8);        // 0.05 MB
    size_t o_stats = alloc(2 * 64 * 4);
    size_t o_fh    = alloc((size_t)kB * kF1 * kNMN * 8);       // 42 MB (fh, then zs)
    // Adaptive chunk: try CH=60 scratch (64.9 MB); fall back to proven 40.
    size_t off_save = off;
    int CH = 60;
    size_t o_scr  = alloc((size_t)CH * kTfP * 8);
    size_t o_cube = alloc((size_t)kB * kF1 * kCube * 4);       // 126 MB
    if (off > ws_size) {
        off = off_save;
        CH = 40;
        o_scr  = alloc((size_t)CH * kTfP * 8);                 // 43.3 MB
        o_cube = alloc((size_t)kB * kF1 * kCube * 4);
        if (off > ws_size) return;
    }

    const float* cb = (const float*)(ws + o_const);
    const float2* twf = (const float2*)(cb + g_tab.o_twf);
    const float2* twi = (const float2*)(cb + g_tab.o_twi);
    const float* w_t = cb + g_tab.o_w;
    const float* etab = cb + g_tab.o_etab;
    const float* dehalf = etab + (size_t)(8 + 4) * kNMN;  // G_4 = E0^32 = d(pi/2)
    const int* lmn_l = (const int*)(cb + g_tab.o_lmnl);
    const int* lm_l = (const int*)(cb + g_tab.o_lml);
    const int* lmn2 = (const int*)(cb + g_tab.o_lmn2);
    const int* lmq = (const int*)(cb + g_tab.o_lmq);
    const int* off4 = (const int*)(cb + g_tab.o_off4);

    float* dqz = (float*)(ws + o_dqz);
    float* dqtw = (float*)(ws + o_dqtw);
    float* deTp = (float*)(ws + o_deTp);
    float2* khat = (float2*)(ws + o_khat);
    float2* xf1 = (float2*)(ws + o_xf1);
    float2* fh1 = (float2*)(ws + o_fh1);
    float* stats = (float*)(ws + o_stats);
    float2* fh = (float2*)(ws + o_fh);
    float2* zsb = (float2*)(ws + o_fh);
    float* dtmp = (float*)(ws + o_scr);
    float2* Gb = (float2*)(ws + o_scr);
    float2* xfc = (float2*)(ws + o_scr);
    float2* Tb = (float2*)(ws + o_scr);
    float* cube = (float*)(ws + o_cube);

    hipMemcpyAsync(ws + o_const, g_tab.blob.data(), g_tab.bytes,
                   hipMemcpyHostToDevice, stream);
    hipMemsetAsync(dqz, 0, (size_t)kNM * 64 * 64 * 4, stream);
    hipMemsetAsync(deTp, 0, (size_t)4 * 11424 * 4, stream);
    k_gendqA<<<kLMAX * 64, TPB, 0, stream>>>(etab, dtmp);
    k_scat<<<kLMAX * 63, TPB, 0, stream>>>(dtmp, w_t, dqz, dqtw);
    k_transde_p<<<(kNMN + TPB - 1) / TPB, TPB, 0, stream>>>(dehalf, deTp, lmn_l, off4);

    const float S2S = 1.0f / sqrtf(64.0f * 3.0f * 1024.0f);
    const float SO3S = 1.0f / sqrtf(64.0f * 60.0f);
    auto blks = [](size_t n) { return (int)((n + TPB - 1) / TPB); };

    auto synth = [&](const float* bi, int Fo) {
        hipMemsetAsync(stats, 0, 2 * 64 * 4, stream);
        int planes = kB * Fo;
        for (int zo0 = 0; zo0 < planes; zo0 += CH) {
            int nzo = planes - zo0 < CH ? planes - zo0 : CH;
            k_synA<<<dim3(33, nzo), TPB, 0, stream>>>(
                zsb + (size_t)zo0 * kNMN, dqz, Tb);
            k_synB<<<nzo * 64, TPB, 0, stream>>>(Tb, twi, bi, cube, stats, Fo, zo0);
        }
    };

    // ---- Layer 1: S2 conv -> cube ----
    k_khat<<<blks(kF0 * kF1 * 64), TPB, 0, stream>>>(k1, khat, twf, kF0 * kF1 * 64, S2S);
    k_fft1<<<blks(kB * kF0 * 64 * 64), TPB, 0, stream>>>(x, xf1, twf);
    k_fh1<<<blks(kNM * kB * kF0), TPB, 0, stream>>>(xf1, dqtw, lm_l, fh1);
    k_zs1<<<blks((size_t)(kF1 / 6) * kNMN2), TPB, 0, stream>>>(fh1, khat, dehalf,
                                                               lmn_l, lmn2, zsb);
    synth(bias1, kF1);

    // ---- Layers 2 & 3: SO3 conv; fft2 applies previous layer's BN+ReLU ----
    for (int layer = 2; layer <= 3; layer++) {
        int Fo = (layer == 2) ? kF1 : kF2;
        const float* kk = (layer == 2) ? k2 : k3;
        const float* bi = (layer == 2) ? bias2 : bias3;
        const float* gp = (layer == 2) ? g1 : g2;
        const float* bp = (layer == 2) ? be1 : be2;
        k_khat<<<blks(kF1 * Fo * 64), TPB, 0, stream>>>(kk, khat, twf, kF1 * Fo * 64, SO3S);
        for (int zf0 = 0; zf0 < kB * kF1; zf0 += CH) {
            int nzf = kB * kF1 - zf0 < CH ? kB * kF1 - zf0 : CH;
            k_fft2<<<nzf * 64, TPB, 0, stream>>>(cube + (size_t)zf0 * kCube, xfc,
                                                 twf, stats, gp, bp, zf0);
            k_fh3<<<2048, TPB, 0, stream>>>(xfc, dqtw, fh + (size_t)zf0 * kNMN, nzf);
        }
        {
            int total = kB * kF1 * kNQ2;
            k_G4<<<blks(total), TPB, 0, stream>>>(fh, deTp, lmq, off4, Gb, total);
        }
        if (layer == 2) {
            int nOg = kF1 / 3;
            int CHb = (kCH2 * nOg + 7) / 8;
            k_zs_v4<60, 60><<<8 * CHb, TPB, 0, stream>>>(Gb, khat, lmn_l, lmn2, zsb);
        } else {
            int nOg = kF2 / 3;
            int CHb = (kCH2 * nOg + 7) / 8;
            k_zs_v4<60, 36><<<8 * CHb, TPB, 0, stream>>>(Gb, khat, lmn_l, lmn2, zsb);
        }
        synth(bi, Fo);
        if (layer == 3)
            k_final<<<blks(kB * kF2 * 4096), TPB, 0, stream>>>(cube, stats, g3, be3, (float*)d_out);
    }
}

// Round 17
// 1531.337 us; speedup vs baseline: 1.3051x; 1.0018x over previous
//
#include <hip/hip_runtime.h>
#include <cmath>
#include <cstring>
#include <cstdint>
#include <vector>

#define TPB 256
static constexpr int kLMAX = 32;
static constexpr int kNMN  = 43680;   // sum_{l<32} (2l+1)^2
static constexpr int kNMN2 = 22352;   // sum_{l<32} (l+1)(2l+1)  (m>=0 rows only)
static constexpr int kNM   = 1024;    // sum_{l<32} (2l+1)
static constexpr int kNQ2  = 5848;    // sum_{l<32} (l+1)*ceil((2l+1)/4)
static constexpr int kB    = 2;
static constexpr int kF0   = 3, kF1 = 60, kF2 = 36;
static constexpr int kCube = 262144;  // 64^3
static constexpr int kFh3Ch = 60;     // fh3 LDS sub-chunk (fits 64KB LDS)
static constexpr int kXfP  = 131072;  // xf plane: 64 beta x 32 mu x 64 nu float2
static constexpr int kTfP  = 135168;  // T plane: 33 mu x 64 j x 64 g float2
static constexpr int kCH2  = (kNMN2 + 255) / 256;   // 88 lmn2-chunks of 256

__host__ __device__ inline int off3i(int l) { return l * (4 * l * l - 1) / 3; }

// ---------------------------------------------------------------------------
// Host-side constant tables (~3.0 MB seeds; d_b = F_{b&7} * G_{b>>3}).
// Hermitian dead-code note: synA (mu<=32) only reads zs rows with m>=0, so
// the zs/G/fh chain is computed ONLY for mi>=l (lmn2/lmq tables below), and
// fh3/fft2 only produce the mu in [0,31] half of the spectrum. xf/T planes
// are stored COMPACT (32/33 rows); chunk size adapts to the workspace
// (CH in {120, 60, 40}); fh3 loops internally over 60-plane LDS tiles.
// ---------------------------------------------------------------------------
static void h_matmul(const std::vector<double>& A, const std::vector<double>& B,
                     std::vector<double>& C, int n) {
    C.assign((size_t)n * n, 0.0);
    for (int i = 0; i < n; i++)
        for (int k = 0; k < n; k++) {
            double a = A[(size_t)i * n + k];
            if (a == 0.0) continue;
            const double* bp = &B[(size_t)k * n];
            double* cp = &C[(size_t)i * n];
            for (int j = 0; j < n; j++) cp[j] += a * bp[j];
        }
}

struct HostTables {
    std::vector<float> blob;
    size_t o_twf, o_twi, o_w, o_lmnl, o_lml, o_lmn2, o_lmq, o_off4, o_etab;
    size_t bytes;
    HostTables() {
        size_t n = 0;
        o_twf = n;  n += 128;
        o_twi = n;  n += 128;
        o_w = n;    n += 64;
        o_lmnl = n; n += kNMN;
        o_lml = n;  n += kNM;
        o_lmn2 = n; n += kNMN2;
        o_lmq = n;  n += kNQ2;
        o_off4 = n; n += 32;
        o_etab = n; n += (size_t)16 * kNMN;    // [F_0..F_7, G_0..G_7] per l
        blob.assign(n, 0.0f);
        bytes = n * 4;

        for (int k = 0; k < 64; k++) {
            double th = -2.0 * M_PI * k / 64.0;
            blob[o_twf + 2 * k]     = (float)cos(th);
            blob[o_twf + 2 * k + 1] = (float)sin(th);
            blob[o_twi + 2 * k]     = (float)cos(th);
            blob[o_twi + 2 * k + 1] = (float)(-sin(th));
        }
        for (int j = 0; j < 64; j++) {
            double s = 0;
            for (int k = 0; k < 32; k++)
                s += sin((2.0 * j + 1) * (2.0 * k + 1) * M_PI / 128.0) / (2.0 * k + 1);
            blob[o_w + j] = (float)(2.0 / 32.0 * sin(M_PI * (2.0 * j + 1) / 128.0) * s);
        }
        // lmn2: compact index of (l, mi>=l, ni) -> original lmn offset.
        {
            int qi = 0;
            for (int l = 0; l < kLMAX; l++) {
                int R = 2 * l + 1, o3 = off3i(l);
                for (int mi = l; mi < R; mi++)
                    for (int ni = 0; ni < R; ni++) {
                        int32_t v = o3 + mi * R + ni;
                        memcpy(&blob[o_lmn2 + qi], &v, 4);
                        qi++;
                    }
            }
        }
        // q -> (l, mi>=l, n0) table for n4-blocked k_G4, and padded-deT offsets.
        {
            int qi = 0, acc4 = 0;
            for (int l = 0; l < kLMAX; l++) {
                int R = 2 * l + 1, Rp = (R + 3) & ~3, C = Rp >> 2;
                int32_t o4 = acc4;
                memcpy(&blob[o_off4 + l], &o4, 4);
                for (int m = l; m < R; m++)
                    for (int c = 0; c < C; c++) {
                        int32_t pk = l | (m << 5) | ((4 * c) << 11);
                        memcpy(&blob[o_lmq + qi], &pk, 4);
                        qi++;
                    }
                acc4 += R * Rp;
            }
        }
        std::vector<double> A, Eh, E0, E08, F, G, term, tmp;
        for (int l = 0; l < kLMAX; l++) {
            int R = 2 * l + 1, o3 = off3i(l);
            A.assign((size_t)R * R, 0.0);
            for (int i = 0; i + 1 < R; i++) {
                double m = (double)i - l;
                double c = sqrt((double)l * (l + 1) - m * (m + 1));
                A[(size_t)(i + 1) * R + i] = -(M_PI / 128.0) * c * 0.5;
                A[(size_t)i * R + (i + 1)] =  (M_PI / 128.0) * c * 0.5;
            }
            Eh.assign((size_t)R * R, 0.0);
            for (int i = 0; i < R; i++) Eh[(size_t)i * R + i] = 1.0;
            term = Eh;
            for (int k = 1; k <= 30; k++) {
                h_matmul(term, A, tmp, R);
                for (auto& v : tmp) v /= k;
                term = tmp;
                for (size_t i = 0; i < (size_t)R * R; i++) Eh[i] += term[i];
            }
            h_matmul(Eh, Eh, E0, R);
            h_matmul(E0, E0, tmp, R);
            h_matmul(tmp, tmp, E08, R);
            h_matmul(E08, E08, tmp, R); E08 = tmp;  // E0^8
            F = Eh;
            for (int lo = 0; lo < 8; lo++) {
                for (int r = 0; r < R * R; r++)
                    blob[o_etab + (size_t)lo * kNMN + o3 + r] = (float)F[r];
                if (lo < 7) { h_matmul(F, E0, tmp, R); F = tmp; }
            }
            G.assign((size_t)R * R, 0.0);
            for (int i = 0; i < R; i++) G[(size_t)i * R + i] = 1.0;
            for (int hi = 0; hi < 8; hi++) {
                for (int r = 0; r < R * R; r++)
                    blob[o_etab + (size_t)(8 + hi) * kNMN + o3 + r] = (float)G[r];
                if (hi < 7) { h_matmul(G, E08, tmp, R); G = tmp; }
            }
            int32_t li = l;
            for (int r = 0; r < R * R; r++) memcpy(&blob[o_lmnl + o3 + r], &li, 4);
            for (int m = 0; m < R; m++)    memcpy(&blob[o_lml + (size_t)l * l + m], &li, 4);
        }
    }
};
static HostTables g_tab;

// ---------------------------------------------------------------------------
__global__ __launch_bounds__(TPB) void k_gendqA(const float* __restrict__ etab,
                                                float* __restrict__ dtmp) {
    __shared__ float Fm[3969];
    __shared__ float Gm[63 * 64];
    int l = blockIdx.x >> 6, b = blockIdx.x & 63;
    int lo = b & 7, hi = b >> 3;
    int R = 2 * l + 1, RR = R * R, o3 = off3i(l);
    int tid = threadIdx.x;
    const float* Fsrc = etab + (size_t)lo * kNMN + o3;
    const float* Gsrc = etab + (size_t)(8 + hi) * kNMN + o3;
    for (int i = tid; i < RR; i += TPB) Fm[i] = Fsrc[i];
    for (int i = tid; i < R * 64; i += TPB) {
        int k = i >> 6, c = i & 63;
        Gm[i] = (c < R) ? Gsrc[k * R + c] : 0.f;
    }
    __syncthreads();
    int Gc = (R + 15) >> 4;
    if (tid < R * Gc) {
        int row = tid / Gc, g = tid - row * Gc;
        float4 A0 = make_float4(0,0,0,0), A1 = A0, A2 = A0, A3 = A0;
        const float* fr = Fm + row * R;
        for (int k = 0; k < R; k++) {
            float a = fr[k];
            const float4* gp = (const float4*)(Gm + (k << 6) + (g << 4));
            float4 q0 = gp[0], q1 = gp[1], q2 = gp[2], q3 = gp[3];
            A0.x += a * q0.x; A0.y += a * q0.y; A0.z += a * q0.z; A0.w += a * q0.w;
            A1.x += a * q1.x; A1.y += a * q1.y; A1.z += a * q1.z; A1.w += a * q1.w;
            A2.x += a * q2.x; A2.y += a * q2.y; A2.z += a * q2.z; A2.w += a * q2.w;
            A3.x += a * q3.x; A3.y += a * q3.y; A3.z += a * q3.z; A3.w += a * q3.w;
        }
        float v[16] = {A0.x,A0.y,A0.z,A0.w, A1.x,A1.y,A1.z,A1.w,
                       A2.x,A2.y,A2.z,A2.w, A3.x,A3.y,A3.z,A3.w};
        float* dst = dtmp + (size_t)o3 * 64 + (size_t)b * RR + row * R;
        int c0 = g << 4;
        #pragma unroll
        for (int e = 0; e < 16; e++)
            if (c0 + e < R) dst[c0 + e] = v[e];
    }
}

__global__ __launch_bounds__(TPB) void k_scat(const float* __restrict__ dtmp,
                                              const float* __restrict__ w,
                                              float* __restrict__ dqz,
                                              float* __restrict__ dqtw) {
    __shared__ float S[64 * 65];
    int l = blockIdx.x / 63, tile = blockIdx.x % 63;
    int R = 2 * l + 1, RR = R * R, o3 = off3i(l);
    int i0 = tile * 64;
    if (i0 >= RR) return;
    int tid = threadIdx.x;
    const float* src = dtmp + (size_t)o3 * 64;
    #pragma unroll
    for (int s = 0; s < 16; s++) {
        int idx = tid + s * TPB;
        int b = idx >> 6, ii = idx & 63;
        int i = i0 + ii;
        S[ii * 65 + b] = (i < RR) ? src[(size_t)b * RR + i] : 0.f;
    }
    __syncthreads();
    float Rf = (float)R;
    #pragma unroll
    for (int s = 0; s < 16; s++) {
        int idx = tid + s * TPB;
        int ii = idx >> 6, b = idx & 63;
        int i = i0 + ii;
        if (i < RR) {
            float v = S[ii * 65 + b];
            dqtw[((size_t)o3 + i) * 64 + b] = w[b] * v;
            int mi = i / R, ni = i - mi * R;
            int nu = (ni - l) & 63;
            dqz[((size_t)(l * l + mi) * 64 + nu) * 64 + b] = Rf * v;
        }
    }
}

// Builds padded-row deTp: deTp[off4(l) + k*Rp + n] = dehalf[o3 + n*R + k],
// Rp = ceil(R/4)*4. Pad entries stay zero (memset upstream).
__global__ void k_transde_p(const float* __restrict__ dehalf, float* __restrict__ deTp,
                            const int* __restrict__ lmn_l, const int* __restrict__ off4) {
    int t = blockIdx.x * TPB + threadIdx.x;
    if (t >= kNMN) return;
    int l = lmn_l[t], o3 = off3i(l), r = t - o3, R = 2 * l + 1;
    int Rp = (R + 3) & ~3;
    int n = r / R, k = r - n * R;
    deTp[off4[l] + k * Rp + n] = dehalf[t];
}

__global__ void k_khat(const float* __restrict__ kern, float2* __restrict__ khat,
                       const float2* __restrict__ twf, int total, float scale) {
    int t = blockIdx.x * TPB + threadIdx.x;
    if (t >= total) return;
    int nu = t & 63, fo = t >> 6;
    const float* row = kern + (size_t)fo * 64;
    float re = 0, im = 0;
    for (int p = 0; p < 64; p++) {
        float2 w = twf[(p * nu) & 63];
        float v = row[p];
        re += v * w.x; im += v * w.y;
    }
    khat[t] = make_float2(re * scale, im * scale);
}

__global__ void k_fft1(const float* __restrict__ x, float2* __restrict__ xf1,
                       const float2* __restrict__ twf) {
    int t = blockIdx.x * TPB + threadIdx.x;
    if (t >= kB * kF0 * 64 * 64) return;
    int mu = t & 63, row = t >> 6;
    const float* p = x + (size_t)row * 64;
    float re = 0, im = 0;
    for (int a = 0; a < 64; a++) {
        float2 w = twf[(a * mu) & 63];
        float v = p[a];
        re += v * w.x; im += v * w.y;
    }
    xf1[t] = make_float2(re, im);
}

__global__ void k_fh1(const float2* __restrict__ xf1, const float* __restrict__ dqtw,
                      const int* __restrict__ lm_l, float2* __restrict__ fh1) {
    int t = blockIdx.x * TPB + threadIdx.x;
    if (t >= kNM * kB * kF0) return;
    int lm = t / 6, rem = t % 6, z = rem / 3, f = rem % 3;
    int l = lm_l[lm], m = lm - l * l, R = 2 * l + 1, o3 = off3i(l);
    int mu = (m - l) & 63;
    const float4* wq = (const float4*)(dqtw + (size_t)o3 * 64 + (size_t)(m * R + l) * 64);
    const float2* xr = xf1 + (size_t)((z * 3 + f) * 64) * 64 + mu;
    float re0 = 0, im0 = 0, re1 = 0, im1 = 0;
    #pragma unroll
    for (int b4 = 0; b4 < 16; b4++) {
        float4 w4 = wq[b4];
        float2 v0 = xr[(4 * b4 + 0) * 64];
        float2 v1 = xr[(4 * b4 + 1) * 64];
        float2 v2 = xr[(4 * b4 + 2) * 64];
        float2 v3 = xr[(4 * b4 + 3) * 64];
        re0 += w4.x * v0.x + w4.y * v1.x; im0 += w4.x * v0.y + w4.y * v1.y;
        re1 += w4.z * v2.x + w4.w * v3.x; im1 += w4.z * v2.y + w4.w * v3.y;
    }
    const float C2 = 1.0f / 128.0f;
    fh1[t] = make_float2((re0 + re1) * C2, (im0 + im1) * C2);
}

// Layer-1 zs restricted to lmn2 (mi>=l): synA never reads m<0 rows.
__global__ void k_zs1(const float2* __restrict__ fh1, const float2* __restrict__ khat,
                      const float* __restrict__ dehalf, const int* __restrict__ lmn_l,
                      const int* __restrict__ lmn2, float2* __restrict__ zs) {
    int nOg = kF1 / 6;                       // 10
    int t = blockIdx.x * TPB + threadIdx.x;  // og*NMN2 + i2
    if (t >= nOg * kNMN2) return;
    int i2 = t % kNMN2, og = t / kNMN2;
    int lmn = lmn2[i2];
    int l = lmn_l[lmn], o3 = off3i(l), r = lmn - o3, R = 2 * l + 1;
    int m = r / R, n = r - m * R;
    int nu = (n - l) & 63;
    float de1 = dehalf[o3 + n * R + l];
    int o0 = og * 6;
    const float2* fp = fh1 + (size_t)(l * l + m) * 6;
    const float2* kp = khat + (size_t)o0 * 64 + nu;
    float2 c0[6], c1[6];
    #pragma unroll
    for (int i = 0; i < 6; i++) {
        c0[i] = make_float2(0.f, 0.f);
        c1[i] = make_float2(0.f, 0.f);
    }
    #pragma unroll
    for (int f = 0; f < kF0; f++) {
        float2 a0 = fp[f];       // z = 0
        float2 a1 = fp[3 + f];   // z = 1
        const float2* kf = kp + (size_t)f * kF1 * 64;
        #pragma unroll
        for (int i = 0; i < 6; i++) {
            float2 b = kf[(size_t)i * 64];   // conj applied below
            c0[i].x += a0.x * b.x + a0.y * b.y;
            c0[i].y += a0.y * b.x - a0.x * b.y;
            c1[i].x += a1.x * b.x + a1.y * b.y;
            c1[i].y += a1.y * b.x - a1.x * b.y;
        }
    }
    float2* zp0 = zs + (size_t)o0 * kNMN + lmn;
    float2* zp1 = zs + ((size_t)kF1 + o0) * kNMN + lmn;
    #pragma unroll
    for (int i = 0; i < 6; i++) {
        zp0[(size_t)i * kNMN] = make_float2(c0[i].x * de1, c0[i].y * de1);
        zp1[(size_t)i * kNMN] = make_float2(c1[i].x * de1, c1[i].y * de1);
    }
}

// 2D forward DFT (radix-8 x2) with fused BN+ReLU; float4 staging.
// HERMITIAN DCE (output): k_fh3 reads only mu in [0,31] -> pass-2 computes
// only u<4, and xf planes are stored COMPACT (32 mu rows, kXfP float2/zf).
// HERMITIAN (input): rows are REAL, so pass-1 output satisfies
// F[64-nu] = conj(F[nu]); pass-1 stage-2 computes nu<=32 and mirrors 33..63
// in LDS (intra-wave lockstep, same reliance as the cross-lane stage reads).
__global__ __launch_bounds__(TPB) void k_fft2(const float* __restrict__ y,
                                              float2* __restrict__ xf,
                                              const float2* __restrict__ twf_g,
                                              const float* __restrict__ stats,
                                              const float* __restrict__ gamma,
                                              const float* __restrict__ beta,
                                              int zf0) {
    __shared__ float sIn[64 * 65];
    __shared__ float2 sMid[64 * 66];
    __shared__ float2 tw[64];
    int blk = blockIdx.x, tid = threadIdx.x;
    if (tid < 64) tw[tid] = twf_g[tid];
    int o = (zf0 + (blk >> 6)) % kF1;
    const float inv = 1.0f / 524288.0f;
    float mean = stats[o * 2] * inv;
    float var = stats[o * 2 + 1] * inv - mean * mean;
    float rstd = rsqrtf(var + 1e-5f);
    float ga = gamma[o], be = beta[o];
    const float4* src4 = (const float4*)(y + (size_t)blk * 4096);
    for (int i = tid; i < 1024; i += TPB) {
        float4 v4 = src4[i];
        int row = i >> 4, col = (i & 15) << 2;
        float* d = sIn + row * 65 + col;
        float a0 = (v4.x - mean) * rstd * ga + be;
        float a1 = (v4.y - mean) * rstd * ga + be;
        float a2 = (v4.z - mean) * rstd * ga + be;
        float a3 = (v4.w - mean) * rstd * ga + be;
        d[0] = a0 > 0.f ? a0 : 0.f;
        d[1] = a1 > 0.f ? a1 : 0.f;
        d[2] = a2 > 0.f ? a2 : 0.f;
        d[3] = a3 > 0.f ? a3 : 0.f;
    }
    __syncthreads();
    float2 w8[8];
    #pragma unroll
    for (int k = 0; k < 8; k++) w8[k] = tw[k * 8];
    int r2 = tid >> 2, q = tid & 3;
    {   // dim-1: g -> nu, REAL input
        const float* rowp = sIn + r2 * 65;
        float2* mrow = sMid + r2 * 66;
        #pragma unroll
        for (int half = 0; half < 2; half++) {
            int s = q + 4 * half;
            float f[8];
            #pragma unroll
            for (int p = 0; p < 8; p++) f[p] = rowp[8 * p + s];
            float2 ws = tw[s];
            float2 t = make_float2(1.f, 0.f);
            #pragma unroll
            for (int v = 0; v < 8; v++) {
                float re = 0, im = 0;
                #pragma unroll
                for (int p = 0; p < 8; p++) {
                    float2 w = w8[(v * p) & 7];
                    re += f[p] * w.x; im += f[p] * w.y;
                }
                mrow[v * 8 + s] = make_float2(re * t.x - im * t.y, re * t.y + im * t.x);
                float tx = t.x * ws.x - t.y * ws.y;
                t.y = t.x * ws.y + t.y * ws.x; t.x = tx;
            }
        }
        float2 a[2][8];
        #pragma unroll
        for (int half = 0; half < 2; half++) {
            int v = q + 4 * half;
            #pragma unroll
            for (int s = 0; s < 8; s++) a[half][s] = mrow[v * 8 + s];
        }
        #pragma unroll
        for (int half = 0; half < 2; half++) {
            int v = q + 4 * half;
            #pragma unroll
            for (int u = 0; u < 4; u++) {   // nu = 8u+v in [0,31]
                float re = 0, im = 0;
                #pragma unroll
                for (int s = 0; s < 8; s++) {
                    float2 w = w8[(u * s) & 7];
                    re += a[half][s].x * w.x - a[half][s].y * w.y;
                    im += a[half][s].x * w.y + a[half][s].y * w.x;
                }
                mrow[8 * u + v] = make_float2(re, im);
            }
        }
        if (q == 0) {   // nu = 32 (u=4, v=0): only the half=0, v=0 slot
            float re = 0, im = 0;
            #pragma unroll
            for (int s = 0; s < 8; s++) {
                float2 w = w8[(4 * s) & 7];
                re += a[0][s].x * w.x - a[0][s].y * w.y;
                im += a[0][s].x * w.y + a[0][s].y * w.x;
            }
            mrow[32] = make_float2(re, im);
        }
        // mirror nu = 33..63: F[nu] = conj(F[64-nu]) (real input rows).
        for (int nu = 33 + q; nu < 64; nu += 4) {
            float2 vv = mrow[64 - nu];
            mrow[nu] = make_float2(vv.x, -vv.y);
        }
    }
    __syncthreads();
    {   // dim-2: a -> mu per column c; only mu < 32 needed downstream
        int c = r2;
        float2* dst = xf + (size_t)blk * 2048;   // compact 32-row plane slice
        #pragma unroll
        for (int half = 0; half < 2; half++) {
            int s = q + 4 * half;
            float2 f[8];
            #pragma unroll
            for (int p = 0; p < 8; p++) f[p] = sMid[(8 * p + s) * 66 + c];
            float2 ws = tw[s];
            float2 t = make_float2(1.f, 0.f);
            #pragma unroll
            for (int v = 0; v < 8; v++) {
                float re = 0, im = 0;
                #pragma unroll
                for (int p = 0; p < 8; p++) {
                    float2 w = w8[(v * p) & 7];
                    re += f[p].x * w.x - f[p].y * w.y;
                    im += f[p].x * w.y + f[p].y * w.x;
                }
                sMid[(v * 8 + s) * 66 + c] = make_float2(re * t.x - im * t.y,
                                                         re * t.y + im * t.x);
                float tx = t.x * ws.x - t.y * ws.y;
                t.y = t.x * ws.y + t.y * ws.x; t.x = tx;
            }
        }
        float2 a[2][8];
        #pragma unroll
        for (int half = 0; half < 2; half++) {
            int v = q + 4 * half;
            #pragma unroll
            for (int s = 0; s < 8; s++) a[half][s] = sMid[(v * 8 + s) * 66 + c];
        }
        #pragma unroll
        for (int half = 0; half < 2; half++) {
            int v = q + 4 * half;
            #pragma unroll
            for (int u = 0; u < 4; u++) {   // mu = 8u+v in [0,31] only
                float re = 0, im = 0;
                #pragma unroll
                for (int s = 0; s < 8; s++) {
                    float2 w = w8[(u * s) & 7];
                    re += a[half][s].x * w.x - a[half][s].y * w.y;
                    im += a[half][s].x * w.y + a[half][s].y * w.x;
                }
                dst[(8 * u + v) * 64 + c] = make_float2(re, im);
            }
        }
    }
}

// fh3: one block per (mu,nu) column, mu in [0..31] ONLY (m>=0 rows; the m<0
// half of fh is dead code downstream). X and dqtw staged in LDS; X is staged
// in 60-plane sub-chunks (internal loop) so nzf can be up to 120.
// XCD swizzle in 256-block chunks keeps nu-adjacent blocks on one L2.
__global__ __launch_bounds__(TPB) void k_fh3(const float2* __restrict__ xf,
                                             const float* __restrict__ dqtw,
                                             float2* __restrict__ fh_out, int nzf) {
    __shared__ float2 sX[kFh3Ch * 66];   // [zf][b], row stride 66 float2
    __shared__ float  sD[32 * 68];       // [li][b], row stride 68 floats
    int v = blockIdx.x;                  // 2048 blocks
    int wg = (v & 7) * 256 + (v >> 3);
    int nu = wg & 63, mu = wg >> 6;      // mu in [0,31] -> mt = mu >= 0
    int mt = mu;
    int nt = (nu <= 31) ? nu : nu - 64;
    int am = mu, an = nt < 0 ? -nt : nt;
    int lmin = am > an ? am : an;
    if (lmin >= kLMAX) return;
    int nl = kLMAX - lmin;
    int tid = threadIdx.x;
    for (int i = tid; i < nl * 64; i += TPB) {
        int li = i >> 6, b = i & 63;
        int l = lmin + li, R = 2 * l + 1;
        int r = (mt + l) * R + (nt + l);
        sD[li * 68 + b] = dqtw[(size_t)(off3i(l) + r) * 64 + b];
    }
    const float C3 = 1.0f / 8192.0f;
    for (int z0 = 0; z0 < nzf; z0 += kFh3Ch) {
        int nz = nzf - z0 < kFh3Ch ? nzf - z0 : kFh3Ch;
        __syncthreads();   // previous compute done (and sD ready on iter 0)
        for (int i = tid; i < nz * 64; i += TPB) {
            int zf = i >> 6, b = i & 63;
            sX[zf * 66 + b] =
                xf[(size_t)(z0 + zf) * kXfP + (size_t)b * 2048 + mu * 64 + nu];
        }
        __syncthreads();
        int items = nz * nl;
        for (int item = tid; item < items; item += TPB) {
            int zf = item / nl, li = item - zf * nl;
            const float4* D4 = (const float4*)(sD + li * 68);
            const float4* X4 = (const float4*)(sX + zf * 66);
            float re0 = 0, im0 = 0, re1 = 0, im1 = 0;
            #pragma unroll
            for (int b4 = 0; b4 < 16; b4++) {
                float4 d   = D4[b4];
                float4 x01 = X4[2 * b4];
                float4 x23 = X4[2 * b4 + 1];
                re0 += d.x * x01.x; im0 += d.x * x01.y;
                re0 += d.y * x01.z; im0 += d.y * x01.w;
                re1 += d.z * x23.x; im1 += d.z * x23.y;
                re1 += d.w * x23.z; im1 += d.w * x23.w;
            }
            int l = lmin + li, R = 2 * l + 1;
            int r = (mt + l) * R + (nt + l);
            fh_out[(size_t)(z0 + zf) * kNMN + off3i(l) + r] =
                make_float2((re0 + re1) * C3, (im0 + im1) * C3);
        }
    }
}

// G (n4-blocked, mi>=l rows only): thread computes 4 consecutive n outputs.
// Per k: 1 float2 fh broadcast + 1 aligned float4 deTp row-load -> 16 lane-FMA.
__global__ void k_G4(const float2* __restrict__ fh, const float* __restrict__ deTp,
                     const int* __restrict__ lmq, const int* __restrict__ off4,
                     float2* __restrict__ G, int total) {
    int t = blockIdx.x * TPB + threadIdx.x;
    if (t >= total) return;
    int q = t % kNQ2, zf = t / kNQ2;
    int pk = lmq[q];
    int l = pk & 31, m = (pk >> 5) & 63, n0 = pk >> 11;
    int R = 2 * l + 1, o3 = off3i(l);
    int C4 = ((R + 3) & ~3) >> 2;            // Rp/4
    const float2* fr = fh + (size_t)zf * kNMN + o3 + m * R;
    const float4* dp = (const float4*)(deTp + off4[l] + n0);
    float4 re = make_float4(0.f, 0.f, 0.f, 0.f);
    float4 im = make_float4(0.f, 0.f, 0.f, 0.f);
    int k = 0;
    for (; k + 1 < R; k += 2) {
        float2 f0 = fr[k], f1 = fr[k + 1];
        float4 d0 = dp[(size_t)k * C4];
        float4 d1 = dp[(size_t)(k + 1) * C4];
        re.x += f0.x * d0.x + f1.x * d1.x; im.x += f0.y * d0.x + f1.y * d1.x;
        re.y += f0.x * d0.y + f1.x * d1.y; im.y += f0.y * d0.y + f1.y * d1.y;
        re.z += f0.x * d0.z + f1.x * d1.z; im.z += f0.y * d0.z + f1.y * d1.z;
        re.w += f0.x * d0.w + f1.x * d1.w; im.w += f0.y * d0.w + f1.y * d1.w;
    }
    {
        float2 f0 = fr[k];
        float4 d0 = dp[(size_t)k * C4];
        re.x += f0.x * d0.x; im.x += f0.y * d0.x;
        re.y += f0.x * d0.y; im.y += f0.y * d0.y;
        re.z += f0.x * d0.z; im.z += f0.y * d0.z;
        re.w += f0.x * d0.w; im.w += f0.y * d0.w;
    }
    float2* gp = G + (size_t)zf * kNMN + o3 + m * R + n0;
    int rem = R - n0;
    gp[0] = make_float2(re.x, im.x);
    if (rem > 1) gp[1] = make_float2(re.y, im.y);
    if (rem > 2) gp[2] = make_float2(re.z, im.z);
    if (rem > 3) gp[3] = make_float2(re.w, im.w);
}

// zs v4: og-tile 3; barrier-free body + og-fastest XCD-grouped decode +
// compile-time FIN/FO + unroll-4 f-loop; lmn2 (mi>=l) restricted.
template<int FIN, int FO>
__global__ __launch_bounds__(TPB) void k_zs_v4(const float2* __restrict__ G,
                                               const float2* __restrict__ khat,
                                               const int* __restrict__ lmn_l,
                                               const int* __restrict__ lmn2,
                                               float2* __restrict__ zs) {
    constexpr int NOG = FO / 3;
    int CHb = gridDim.x >> 3;
    int bid = blockIdx.x;
    int work = (bid & 7) * CHb + (bid >> 3);   // bijective; og-fastest
    if (work >= kCH2 * NOG) return;
    int x = work / NOG, og = work - x * NOG;
    int i2 = x * 256 + threadIdx.x;
    if (i2 >= kNMN2) return;
    int lmn = lmn2[i2];
    int l = lmn_l[lmn], r = lmn - off3i(l), R = 2 * l + 1;
    int n = r % R;
    int nu = (n - l) & 63;
    int o0 = og * 3;
    const float2* gp0 = G + lmn;
    const float2* gp1 = G + (size_t)FIN * kNMN + lmn;
    const float2* kp = khat + (size_t)o0 * 64 + nu;
    float2 c0[3], c1[3];
    #pragma unroll
    for (int i = 0; i < 3; i++) {
        c0[i] = make_float2(0.f, 0.f);
        c1[i] = make_float2(0.f, 0.f);
    }
    #pragma unroll 4
    for (int f = 0; f < FIN; f++) {
        float2 a0 = gp0[(size_t)f * kNMN];
        float2 a1 = gp1[(size_t)f * kNMN];
        const float2* kf = kp + (size_t)f * FO * 64;
        #pragma unroll
        for (int i = 0; i < 3; i++) {
            float2 b = kf[(size_t)i * 64];   // conj applied in the FMA signs
            c0[i].x += a0.x * b.x + a0.y * b.y;
            c0[i].y += a0.y * b.x - a0.x * b.y;
            c1[i].x += a1.x * b.x + a1.y * b.y;
            c1[i].y += a1.y * b.x - a1.x * b.y;
        }
    }
    float2* zp0 = zs + (size_t)o0 * kNMN + lmn;
    float2* zp1 = zs + ((size_t)FO + o0) * kNMN + lmn;
    #pragma unroll
    for (int i = 0; i < 3; i++) {
        zp0[(size_t)i * kNMN] = c0[i];
        zp1[(size_t)i * kNMN] = c1[i];
    }
}

// Synthesis stage A (1-plane blocks): grid = (33 mu) x (nzo planes); each
// block accumulates ONE zo plane into the COMPACT T plane (33 rows, kTfP
// float2/zo). Same per-output FMA order as before -> bitwise-same T.
// HERMITIAN: mu = 0..32 only; rows 33..63 derived in k_synB by conj-mirror.
__global__ __launch_bounds__(TPB) void k_synA(const float2* __restrict__ zs,
                                              const float* __restrict__ dqz,
                                              float2* __restrict__ T) {
    __shared__ float2 sZ[32 * 64];
    int mu = blockIdx.x, zo = blockIdx.y;
    int tid = threadIdx.x;
    int mt = (mu <= 31) ? mu : mu - 64;
    int am = mt < 0 ? -mt : mt;
    #pragma unroll
    for (int k = 0; k < 8; k++) {
        int i = tid + k * TPB;
        int nu = i & 63, l = i >> 6;
        int nt = (nu <= 31) ? nu : nu - 64;
        int an = nt < 0 ? -nt : nt;
        float2 v = make_float2(0.f, 0.f);
        if (l >= am && an <= l)
            v = zs[(size_t)zo * kNMN + off3i(l) +
                   (mt + l) * (2 * l + 1) + nt + l];
        sZ[i] = v;
    }
    __syncthreads();
    int j = tid & 63, s = tid >> 6;
    float2 c0[16];
    #pragma unroll
    for (int k = 0; k < 16; k++) c0[k] = make_float2(0.f, 0.f);
    for (int l = am; l < 32; l++) {
        const float* dp = dqz + ((size_t)(l * l + mt + l) * 64 + s * 16) * 64 + j;
        const float4* z04 = (const float4*)(sZ + (size_t)l * 64 + s * 16);
        #pragma unroll
        for (int h = 0; h < 8; h++) {
            float d0 = dp[(size_t)(2 * h) * 64];
            float d1 = dp[(size_t)(2 * h + 1) * 64];
            float4 za = z04[h];
            c0[2 * h].x     += d0 * za.x; c0[2 * h].y     += d0 * za.y;
            c0[2 * h + 1].x += d1 * za.z; c0[2 * h + 1].y += d1 * za.w;
        }
    }
    float2* t0 = T + (((size_t)zo * 33 + mu) * 64 + j) * 64 + s * 16;
    #pragma unroll
    for (int k = 0; k < 16; k++) t0[k] = c0[k];
}

// Synthesis stage B: radix-8 x2 IDFT; real + bias out; fused BN-stats atomics.
// Stages T rows mu=0..32 (compact kTfP planes); pass-1 (dim-nu) runs ONLY on
// those 33 rows with 8 threads/row; rows 33..63 derived by
// h[mu][g] = conj(h[64-mu][g]). Pass-2 unchanged.
__global__ __launch_bounds__(TPB) void k_synB(const float2* __restrict__ T,
                                              const float2* __restrict__ twi_g,
                                              const float* __restrict__ bias,
                                              float* __restrict__ yout,
                                              float* __restrict__ stats,
                                              int Fo, int zo0) {
    __shared__ float2 sF[64 * 66];
    __shared__ float2 tw[64];
    int blk = blockIdx.x;
    int zo_l = blk >> 6, j = blk & 63;
    int zo_g = zo0 + zo_l;
    int o = zo_g % Fo;
    int tid = threadIdx.x;
    if (tid < 64) tw[tid] = twi_g[tid];
    const float4* src4 = (const float4*)(T + (size_t)zo_l * kTfP + (size_t)j * 64);
    for (int i = tid; i < 1056; i += TPB) {      // mu = 0..32 direct
        int mu = i >> 5, half = i & 31;
        float4 v = src4[(size_t)mu * 2048 + half];
        sF[mu * 66 + 2 * half]     = make_float2(v.x, v.y);
        sF[mu * 66 + 2 * half + 1] = make_float2(v.z, v.w);
    }
    __syncthreads();
    float2 w8[8];
    #pragma unroll
    for (int k = 0; k < 8; k++) w8[k] = tw[k * 8];
    {   // pass 1 (dim-nu): rows 0..31 with 8 threads/row; row 32 on lanes 0..7
        int r8 = tid >> 3, q8 = tid & 7;
        float2* mrow = sF + r8 * 66;
        float2* mrow32 = sF + 32 * 66;
        {
            int s = q8;
            float2 f[8];
            #pragma unroll
            for (int p = 0; p < 8; p++) f[p] = mrow[8 * p + s];
            float2 ws = tw[s];
            float2 t = make_float2(1.f, 0.f);
            #pragma unroll
            for (int v = 0; v < 8; v++) {
                float re = 0, im = 0;
                #pragma unroll
                for (int p = 0; p < 8; p++) {
                    float2 w = w8[(v * p) & 7];
                    re += f[p].x * w.x - f[p].y * w.y;
                    im += f[p].x * w.y + f[p].y * w.x;
                }
                mrow[v * 8 + s] = make_float2(re * t.x - im * t.y, re * t.y + im * t.x);
                float tx = t.x * ws.x - t.y * ws.y;
                t.y = t.x * ws.y + t.y * ws.x; t.x = tx;
            }
        }
        if (tid < 8) {   // row 32 stage 1 (wave 0 lanes 0..7, lockstep)
            int s = tid;
            float2 f[8];
            #pragma unroll
            for (int p = 0; p < 8; p++) f[p] = mrow32[8 * p + s];
            float2 ws = tw[s];
            float2 t = make_float2(1.f, 0.f);
            #pragma unroll
            for (int v = 0; v < 8; v++) {
                float re = 0, im = 0;
                #pragma unroll
                for (int p = 0; p < 8; p++) {
                    float2 w = w8[(v * p) & 7];
                    re += f[p].x * w.x - f[p].y * w.y;
                    im += f[p].x * w.y + f[p].y * w.x;
                }
                mrow32[v * 8 + s] = make_float2(re * t.x - im * t.y, re * t.y + im * t.x);
                float tx = t.x * ws.x - t.y * ws.y;
                t.y = t.x * ws.y + t.y * ws.x; t.x = tx;
            }
        }
        {
            int v = q8;
            float2 a[8];
            #pragma unroll
            for (int s = 0; s < 8; s++) a[s] = mrow[v * 8 + s];
            #pragma unroll
            for (int u = 0; u < 8; u++) {
                float re = 0, im = 0;
                #pragma unroll
                for (int s = 0; s < 8; s++) {
                    float2 w = w8[(u * s) & 7];
                    re += a[s].x * w.x - a[s].y * w.y;
                    im += a[s].x * w.y + a[s].y * w.x;
                }
                mrow[8 * u + v] = make_float2(re, im);
            }
        }
        if (tid < 8) {   // row 32 stage 2
            int v = tid;
            float2 a[8];
            #pragma unroll
            for (int s = 0; s < 8; s++) a[s] = mrow32[v * 8 + s];
            #pragma unroll
            for (int u = 0; u < 8; u++) {
                float re = 0, im = 0;
                #pragma unroll
                for (int s = 0; s < 8; s++) {
                    float2 w = w8[(u * s) & 7];
                    re += a[s].x * w.x - a[s].y * w.y;
                    im += a[s].x * w.y + a[s].y * w.x;
                }
                mrow32[8 * u + v] = make_float2(re, im);
            }
        }
    }
    __syncthreads();
    for (int i = tid; i < 31 * 64; i += TPB) {   // rows 33..63: conj mirror in g
        int mu = 33 + (i >> 6), g = i & 63;
        float2 v = sF[(64 - mu) * 66 + g];
        sF[mu * 66 + g] = make_float2(v.x, -v.y);
    }
    __syncthreads();
    float s_acc = 0.f, q_acc = 0.f;
    int r2 = tid >> 2, q = tid & 3;
    {   // dim-mu, per column c; real + bias out
        int c = r2;
        float bo = bias[o];
        float* dst = yout + ((size_t)zo_g * 64 + j) * 4096;
        #pragma unroll
        for (int half = 0; half < 2; half++) {
            int s = q + 4 * half;
            float2 f[8];
            #pragma unroll
            for (int p = 0; p < 8; p++) f[p] = sF[(8 * p + s) * 66 + c];
            float2 ws = tw[s];
            float2 t = make_float2(1.f, 0.f);
            #pragma unroll
            for (int v = 0; v < 8; v++) {
                float re = 0, im = 0;
                #pragma unroll
                for (int p = 0; p < 8; p++) {
                    float2 w = w8[(v * p) & 7];
                    re += f[p].x * w.x - f[p].y * w.y;
                    im += f[p].x * w.y + f[p].y * w.x;
                }
                sF[(v * 8 + s) * 66 + c] = make_float2(re * t.x - im * t.y,
                                                       re * t.y + im * t.x);
                float tx = t.x * ws.x - t.y * ws.y;
                t.y = t.x * ws.y + t.y * ws.x; t.x = tx;
            }
        }
        float2 a[2][8];
        #pragma unroll
        for (int half = 0; half < 2; half++) {
            int v = q + 4 * half;
            #pragma unroll
            for (int s = 0; s < 8; s++) a[half][s] = sF[(v * 8 + s) * 66 + c];
        }
        #pragma unroll
        for (int half = 0; half < 2; half++) {
            int v = q + 4 * half;
            #pragma unroll
            for (int u = 0; u < 8; u++) {
                float re = 0;
                #pragma unroll
                for (int s = 0; s < 8; s++) {
                    float2 w = w8[(u * s) & 7];
                    re += a[half][s].x * w.x - a[half][s].y * w.y;
                }
                float val = re + bo;
                dst[(8 * u + v) * 64 + c] = val;
                s_acc += val;
                q_acc += val * val;
            }
        }
    }
    // fused BN stats: block reduce + 2 atomics (replaces k_bn_stats pass)
    __syncthreads();
    float* rs = (float*)sF;
    rs[tid] = s_acc;
    rs[TPB + tid] = q_acc;
    __syncthreads();
    for (int st = TPB / 2; st > 0; st >>= 1) {
        if (tid < st) { rs[tid] += rs[tid + st]; rs[TPB + tid] += rs[TPB + tid + st]; }
        __syncthreads();
    }
    if (tid == 0) {
        atomicAdd(&stats[o * 2], rs[0]);
        atomicAdd(&stats[o * 2 + 1], rs[TPB]);
    }
}

__global__ void k_final(const float* __restrict__ y, const float* __restrict__ stats,
                        const float* __restrict__ gamma, const float* __restrict__ beta,
                        float* __restrict__ out) {
    int t = blockIdx.x * TPB + threadIdx.x;
    if (t >= kB * kF2 * 4096) return;
    int zo = t >> 12, o = zo % kF2;
    const float inv = 1.0f / 524288.0f;
    float mean = stats[o * 2] * inv;
    float var = stats[o * 2 + 1] * inv - mean * mean;
    float rstd = rsqrtf(var + 1e-5f);
    float ga = gamma[o], be = beta[o];
    const float* p = y + (size_t)t * 64;
    float acc = 0;
    for (int g = 0; g < 64; g++) {
        float v = (p[g] - mean) * rstd * ga + be;
        acc += v > 0.f ? v : 0.f;
    }
    out[t] = acc * (1.0f / 64.0f);
}

// ---------------------------------------------------------------------------
extern "C" void kernel_launch(void* const* d_in, const int* in_sizes, int n_in,
                              void* d_out, int out_size, void* d_ws, size_t ws_size,
                              hipStream_t stream) {
    const float* x     = (const float*)d_in[0];
    const float* k1    = (const float*)d_in[1];
    const float* bias1 = (const float*)d_in[2];
    const float* g1    = (const float*)d_in[3];
    const float* be1   = (const float*)d_in[4];
    const float* k2    = (const float*)d_in[5];
    const float* bias2 = (const float*)d_in[6];
    const float* g2    = (const float*)d_in[7];
    const float* be2   = (const float*)d_in[8];
    const float* k3    = (const float*)d_in[9];
    const float* bias3 = (const float*)d_in[10];
    const float* g3    = (const float*)d_in[11];
    const float* be3   = (const float*)d_in[12];

    char* ws = (char*)d_ws;
    size_t off = 0;
    auto alloc = [&](size_t bytes) {
        size_t cur = off;
        off = (off + bytes + 255) & ~(size_t)255;
        return cur;
    };
    size_t o_const = alloc(g_tab.bytes);                       // 3.0 MB
    size_t o_dqz   = alloc((size_t)kNM * 64 * 64 * 4);         // 16.8 MB
    size_t o_dqtw  = alloc((size_t)64 * kNMN * 4);             // 11.2 MB
    size_t o_deTp  = alloc((size_t)4 * 11424 * 4);             // 0.18 MB (padded, full)
    size_t o_khat  = alloc((size_t)kF1 * kF1 * 64 * 8);        // 1.8 MB
    size_t o_xf1   = alloc((size_t)kB * kF0 * 64 * 64 * 8);    // 0.2 MB
    size_t o_fh1   = alloc((size_t)kNM * kB * kF0 * 8);        // 0.05 MB
    size_t o_stats = alloc(2 * 64 * 4);
    size_t o_fh    = alloc((size_t)kB * kF1 * kNMN * 8);       // 42 MB (fh, then zs)
    // Adaptive chunk: try CH=120 (129.7 MB scratch), then 60, then 40.
    size_t off_save = off;
    int CH = 120;
    size_t o_scr  = alloc((size_t)CH * kTfP * 8);
    size_t o_cube = alloc((size_t)kB * kF1 * kCube * 4);       // 126 MB
    if (off > ws_size) {
        off = off_save;
        CH = 60;
        o_scr  = alloc((size_t)CH * kTfP * 8);                 // 64.9 MB
        o_cube = alloc((size_t)kB * kF1 * kCube * 4);
        if (off > ws_size) {
            off = off_save;
            CH = 40;
            o_scr  = alloc((size_t)CH * kTfP * 8);             // 43.3 MB
            o_cube = alloc((size_t)kB * kF1 * kCube * 4);
            if (off > ws_size) return;
        }
    }

    const float* cb = (const float*)(ws + o_const);
    const float2* twf = (const float2*)(cb + g_tab.o_twf);
    const float2* twi = (const float2*)(cb + g_tab.o_twi);
    const float* w_t = cb + g_tab.o_w;
    const float* etab = cb + g_tab.o_etab;
    const float* dehalf = etab + (size_t)(8 + 4) * kNMN;  // G_4 = E0^32 = d(pi/2)
    const int* lmn_l = (const int*)(cb + g_tab.o_lmnl);
    const int* lm_l = (const int*)(cb + g_tab.o_lml);
    const int* lmn2 = (const int*)(cb + g_tab.o_lmn2);
    const int* lmq = (const int*)(cb + g_tab.o_lmq);
    const int* off4 = (const int*)(cb + g_tab.o_off4);

    float* dqz = (float*)(ws + o_dqz);
    float* dqtw = (float*)(ws + o_dqtw);
    float* deTp = (float*)(ws + o_deTp);
    float2* khat = (float2*)(ws + o_khat);
    float2* xf1 = (float2*)(ws + o_xf1);
    float2* fh1 = (float2*)(ws + o_fh1);
    float* stats = (float*)(ws + o_stats);
    float2* fh = (float2*)(ws + o_fh);
    float2* zsb = (float2*)(ws + o_fh);
    float* dtmp = (float*)(ws + o_scr);
    float2* Gb = (float2*)(ws + o_scr);
    float2* xfc = (float2*)(ws + o_scr);
    float2* Tb = (float2*)(ws + o_scr);
    float* cube = (float*)(ws + o_cube);

    hipMemcpyAsync(ws + o_const, g_tab.blob.data(), g_tab.bytes,
                   hipMemcpyHostToDevice, stream);
    hipMemsetAsync(dqz, 0, (size_t)kNM * 64 * 64 * 4, stream);
    hipMemsetAsync(deTp, 0, (size_t)4 * 11424 * 4, stream);
    k_gendqA<<<kLMAX * 64, TPB, 0, stream>>>(etab, dtmp);
    k_scat<<<kLMAX * 63, TPB, 0, stream>>>(dtmp, w_t, dqz, dqtw);
    k_transde_p<<<(kNMN + TPB - 1) / TPB, TPB, 0, stream>>>(dehalf, deTp, lmn_l, off4);

    const float S2S = 1.0f / sqrtf(64.0f * 3.0f * 1024.0f);
    const float SO3S = 1.0f / sqrtf(64.0f * 60.0f);
    auto blks = [](size_t n) { return (int)((n + TPB - 1) / TPB); };

    auto synth = [&](const float* bi, int Fo) {
        hipMemsetAsync(stats, 0, 2 * 64 * 4, stream);
        int planes = kB * Fo;
        for (int zo0 = 0; zo0 < planes; zo0 += CH) {
            int nzo = planes - zo0 < CH ? planes - zo0 : CH;
            k_synA<<<dim3(33, nzo), TPB, 0, stream>>>(
                zsb + (size_t)zo0 * kNMN, dqz, Tb);
            k_synB<<<nzo * 64, TPB, 0, stream>>>(Tb, twi, bi, cube, stats, Fo, zo0);
        }
    };

    // ---- Layer 1: S2 conv -> cube ----
    k_khat<<<blks(kF0 * kF1 * 64), TPB, 0, stream>>>(k1, khat, twf, kF0 * kF1 * 64, S2S);
    k_fft1<<<blks(kB * kF0 * 64 * 64), TPB, 0, stream>>>(x, xf1, twf);
    k_fh1<<<blks(kNM * kB * kF0), TPB, 0, stream>>>(xf1, dqtw, lm_l, fh1);
    k_zs1<<<blks((size_t)(kF1 / 6) * kNMN2), TPB, 0, stream>>>(fh1, khat, dehalf,
                                                               lmn_l, lmn2, zsb);
    synth(bias1, kF1);

    // ---- Layers 2 & 3: SO3 conv; fft2 applies previous layer's BN+ReLU ----
    for (int layer = 2; layer <= 3; layer++) {
        int Fo = (layer == 2) ? kF1 : kF2;
        const float* kk = (layer == 2) ? k2 : k3;
        const float* bi = (layer == 2) ? bias2 : bias3;
        const float* gp = (layer == 2) ? g1 : g2;
        const float* bp = (layer == 2) ? be1 : be2;
        k_khat<<<blks(kF1 * Fo * 64), TPB, 0, stream>>>(kk, khat, twf, kF1 * Fo * 64, SO3S);
        for (int zf0 = 0; zf0 < kB * kF1; zf0 += CH) {
            int nzf = kB * kF1 - zf0 < CH ? kB * kF1 - zf0 : CH;
            k_fft2<<<nzf * 64, TPB, 0, stream>>>(cube + (size_t)zf0 * kCube, xfc,
                                                 twf, stats, gp, bp, zf0);
            k_fh3<<<2048, TPB, 0, stream>>>(xfc, dqtw, fh + (size_t)zf0 * kNMN, nzf);
        }
        {
            int total = kB * kF1 * kNQ2;
            k_G4<<<blks(total), TPB, 0, stream>>>(fh, deTp, lmq, off4, Gb, total);
        }
        if (layer == 2) {
            int nOg = kF1 / 3;
            int CHb = (kCH2 * nOg + 7) / 8;
            k_zs_v4<60, 60><<<8 * CHb, TPB, 0, stream>>>(Gb, khat, lmn_l, lmn2, zsb);
        } else {
            int nOg = kF2 / 3;
            int CHb = (kCH2 * nOg + 7) / 8;
            k_zs_v4<60, 36><<<8 * CHb, TPB, 0, stream>>>(Gb, khat, lmn_l, lmn2, zsb);
        }
        synth(bi, Fo);
        if (layer == 3)
            k_final<<<blks(kB * kF2 * 4096), TPB, 0, stream>>>(cube, stats, g3, be3, (float*)d_out);
    }
}